// Round 1
// baseline (6075.878 us; speedup 1.0000x reference)
//
#include <hip/hip_runtime.h>
#include <cmath>

#define D_MODEL 768
#define SEQ 2048
#define BATCH 8
#define FC_PAD 96            // 90 conv channels padded to 96
#define NTAP 7
#define KCOMB (NTAP * D_MODEL)   // 5376

// ---------------- combined conv weight build ----------------
// Wcomb[k=t*768+d][o] : conv7 occupies taps 0..6, conv5 taps 1..5, conv3 taps 2..4.
__global__ void build_wcomb(const float* __restrict__ w7, const float* __restrict__ b7,
                            const float* __restrict__ w5, const float* __restrict__ b5,
                            const float* __restrict__ w3, const float* __restrict__ b3,
                            float* __restrict__ Wcomb, float* __restrict__ bcat) {
    int idx = blockIdx.x * blockDim.x + threadIdx.x;
    const int total = KCOMB * FC_PAD;
    if (idx < total) {
        int o = idx % FC_PAD;
        int k = idx / FC_PAD;      // t*768 + d
        int t = k / D_MODEL;
        int d = k - t * D_MODEL;
        float v = 0.f;
        if (o < 40) {
            v = w7[(size_t)o * (D_MODEL * 7) + d * 7 + t];
        } else if (o < 70) {
            int t5 = t - 1;
            if (t5 >= 0 && t5 < 5) v = w5[(size_t)(o - 40) * (D_MODEL * 5) + d * 5 + t5];
        } else if (o < 90) {
            int t3 = t - 2;
            if (t3 >= 0 && t3 < 3) v = w3[(size_t)(o - 70) * (D_MODEL * 3) + d * 3 + t3];
        }
        Wcomb[idx] = v;
    }
    if (idx < FC_PAD) {
        float bv = 0.f;
        if (idx < 40) bv = b7[idx];
        else if (idx < 70) bv = b5[idx - 40];
        else if (idx < 90) bv = b3[idx - 70];
        bcat[idx] = bv;
    }
}

// ---------------- rowbias[b,t] = x2[b,t,:] . bias_v ----------------
__global__ void rowbias_kernel(const float* __restrict__ x2, const float* __restrict__ bias_v,
                               float* __restrict__ rowbias) {
    int row = blockIdx.x;                       // 0..16383
    const float* xr = x2 + (size_t)row * D_MODEL;
    float s = 0.f;
    for (int c = threadIdx.x; c < D_MODEL; c += 256) s += xr[c] * bias_v[c];
    for (int off = 32; off > 0; off >>= 1) s += __shfl_down(s, off);
    __shared__ float red[4];
    int lane = threadIdx.x & 63, w = threadIdx.x >> 6;
    if (lane == 0) red[w] = s;
    __syncthreads();
    if (threadIdx.x == 0) rowbias[row] = red[0] + red[1] + red[2] + red[3];
}

// ---------------- in-place row softmax over [nrows x 2048] ----------------
__global__ void softmax_kernel(float* __restrict__ attn) {
    __shared__ float ls[SEQ];
    __shared__ float red[4];
    __shared__ float bc;
    int row = blockIdx.x;
    float* p = attn + (size_t)row * SEQ;
    int lane = threadIdx.x & 63, w = threadIdx.x >> 6;

    float mx = -1e30f;
    for (int c = threadIdx.x; c < SEQ; c += 256) { float v = p[c]; ls[c] = v; mx = fmaxf(mx, v); }
    for (int off = 32; off > 0; off >>= 1) mx = fmaxf(mx, __shfl_down(mx, off));
    if (lane == 0) red[w] = mx;
    __syncthreads();
    if (threadIdx.x == 0) bc = fmaxf(fmaxf(red[0], red[1]), fmaxf(red[2], red[3]));
    __syncthreads();
    mx = bc;
    float s = 0.f;
    for (int c = threadIdx.x; c < SEQ; c += 256) { float e = __expf(ls[c] - mx); ls[c] = e; s += e; }
    for (int off = 32; off > 0; off >>= 1) s += __shfl_down(s, off);
    if (lane == 0) red[w] = s;
    __syncthreads();
    if (threadIdx.x == 0) bc = 1.f / (red[0] + red[1] + red[2] + red[3]);
    __syncthreads();
    float inv = bc;
    for (int c = threadIdx.x; c < SEQ; c += 256) p[c] = ls[c] * inv;
}

// ---------------- generic fp32 tiled GEMM ----------------
// C[M,N] = act( A' @ B' + bias ) (+ addsrc)
// AMODE: 0 = A[m,k] row-major (stride lda)
//        1 = im2col of x2: A'[m, t*768+d] = x2[b, s+t-3, d], m=b*2048+s
//        2 = virtual concat: k<768 -> A[m,k], else A2[m,k-768]
// BTRANS: 0 -> B[k*ldb+n], 1 -> B[n*ldb+k]; k >= Kreal reads 0 (zero-pad)
// ACT: 0 none, 1 relu, 2 tanh ; HASBIAS: per-n bias ; HASADD: C = addsrc + act(...)
template<int AMODE, int BTRANS, int ACT, int HASBIAS, int HASADD>
__global__ __launch_bounds__(256)
void gemm_kernel(const float* __restrict__ A, const float* __restrict__ A2,
                 const float* __restrict__ B, const float* __restrict__ bias,
                 const float* __restrict__ addsrc, float* __restrict__ C,
                 int M, int N, int K, int Kreal, int lda, int ldb, int ldc) {
    __shared__ float As[32][68];
    __shared__ float Bs[32][68];
    const int m0 = blockIdx.x * 64;
    const int n0 = blockIdx.y * 64;
    const int tid = threadIdx.x;
    const int tx = tid & 15, ty = tid >> 4;
    float acc[4][4] = {};

    for (int k0 = 0; k0 < K; k0 += 32) {
        // stage A tile [64 m x 32 k] -> As[k][m]
        #pragma unroll
        for (int i = tid; i < 64 * 32; i += 256) {
            int m = i >> 5, k = i & 31;
            int gm = m0 + m, gk = k0 + k;
            float v;
            if (AMODE == 1) {
                int t = gk / D_MODEL;               // uniform within chunk (32 | 768)
                int d = gk - t * D_MODEL;
                int s = (gm & (SEQ - 1)) + t - 3;
                int b = gm >> 11;
                v = (s >= 0 && s < SEQ) ? A[((size_t)(b * SEQ + s)) * D_MODEL + d] : 0.f;
            } else if (AMODE == 2) {
                v = (gk < D_MODEL) ? A[(size_t)gm * D_MODEL + gk]
                                   : A2[(size_t)gm * D_MODEL + (gk - D_MODEL)];
            } else {
                v = A[(size_t)gm * lda + gk];
            }
            As[k][m] = v;
        }
        // stage B tile [32 k x 64 n] -> Bs[k][n]
        #pragma unroll
        for (int i = tid; i < 64 * 32; i += 256) {
            int k, n;
            if (BTRANS) { n = i >> 5; k = i & 31; }
            else        { k = i >> 6; n = i & 63; }
            int gk = k0 + k, gn = n0 + n;
            float v = 0.f;
            if (gk < Kreal && gn < N)
                v = BTRANS ? B[(size_t)gn * ldb + gk] : B[(size_t)gk * ldb + gn];
            Bs[k][n] = v;
        }
        __syncthreads();
        #pragma unroll
        for (int kk = 0; kk < 32; ++kk) {
            float4 a = *(const float4*)&As[kk][ty * 4];
            float4 b = *(const float4*)&Bs[kk][tx * 4];
            float av[4] = {a.x, a.y, a.z, a.w};
            float bv[4] = {b.x, b.y, b.z, b.w};
            #pragma unroll
            for (int i = 0; i < 4; ++i)
                #pragma unroll
                for (int j = 0; j < 4; ++j)
                    acc[i][j] = fmaf(av[i], bv[j], acc[i][j]);
        }
        __syncthreads();
    }

    #pragma unroll
    for (int i = 0; i < 4; ++i) {
        int gm = m0 + ty * 4 + i;
        #pragma unroll
        for (int j = 0; j < 4; ++j) {
            int gn = n0 + tx * 4 + j;
            if (gn >= N) continue;
            float v = acc[i][j];
            if (HASBIAS) v += bias[gn];
            if (ACT == 1) v = fmaxf(v, 0.f);
            else if (ACT == 2) v = tanhf(v);
            if (HASADD) v += addsrc[(size_t)gm * ldc + gn];
            C[(size_t)gm * ldc + gn] = v;
        }
    }
}

extern "C" void kernel_launch(void* const* d_in, const int* in_sizes, int n_in,
                              void* d_out, int out_size, void* d_ws, size_t ws_size,
                              hipStream_t stream) {
    const float* x1     = (const float*)d_in[0];
    const float* x2     = (const float*)d_in[1];
    const float* w7     = (const float*)d_in[2];
    const float* b7     = (const float*)d_in[3];
    const float* w5     = (const float*)d_in[4];
    const float* b5     = (const float*)d_in[5];
    const float* w3     = (const float*)d_in[6];
    const float* b3     = (const float*)d_in[7];
    const float* U      = (const float*)d_in[8];
    const float* bias_v = (const float*)d_in[9];
    const float* fc_w   = (const float*)d_in[10];
    const float* fc_b   = (const float*)d_in[11];
    const float* fcx_w  = (const float*)d_in[12];
    const float* fcx_b  = (const float*)d_in[13];
    float* out = (float*)d_out;
    float* ws  = (float*)d_ws;

    const size_t MTOT = (size_t)BATCH * SEQ;     // 16384

    // workspace layout (floats): total ~18.9M floats = 75.5 MB
    float* xbuf  = ws;                            // [16384][768] x_cnn, then x (in-place)
    float* feats = xbuf + MTOT * D_MODEL;         // [16384][96]
    float* Wcomb = feats + MTOT * FC_PAD;         // [5376][96]
    float* bcat  = Wcomb + (size_t)KCOMB * FC_PAD;// [96] (padded to 128)
    float* rbias = bcat + 128;                    // [16384]
    float* attnb = rbias + MTOT;                  // [2048][2048] per-batch scores

    build_wcomb<<<dim3((KCOMB * FC_PAD + 255) / 256), dim3(256), 0, stream>>>(
        w7, b7, w5, b5, w3, b3, Wcomb, bcat);

    rowbias_kernel<<<dim3((int)MTOT), dim3(256), 0, stream>>>(x2, bias_v, rbias);

    // conv (im2col GEMM): feats = relu(im2col(x2) @ Wcomb + bcat)   [16384 x 96]
    gemm_kernel<1, 0, 1, 1, 0><<<dim3((int)MTOT / 64, 2), dim3(256), 0, stream>>>(
        x2, nullptr, Wcomb, bcat, nullptr, feats,
        (int)MTOT, FC_PAD, KCOMB, KCOMB, 0, FC_PAD, FC_PAD);

    // fc: x_cnn = tanh(feats @ fc_w^T + fc_b)   [16384 x 768]
    gemm_kernel<0, 1, 2, 1, 0><<<dim3((int)MTOT / 64, 12), dim3(256), 0, stream>>>(
        feats, nullptr, fc_w, fc_b, nullptr, xbuf,
        (int)MTOT, D_MODEL, FC_PAD, 90, FC_PAD, 90, D_MODEL);

    // y1 = x1 @ U  -> stored temporarily in d_out
    gemm_kernel<0, 0, 0, 0, 0><<<dim3((int)MTOT / 64, 12), dim3(256), 0, stream>>>(
        x1, nullptr, U, nullptr, nullptr, out,
        (int)MTOT, D_MODEL, D_MODEL, D_MODEL, D_MODEL, D_MODEL, D_MODEL);

    // attention, one batch at a time (bounded scratch)
    for (int b = 0; b < BATCH; ++b) {
        const float* x2b = x2 + (size_t)b * SEQ * D_MODEL;
        const float* y1b = out + (size_t)b * SEQ * D_MODEL;
        float* xb = xbuf + (size_t)b * SEQ * D_MODEL;

        // scores = y1b @ x2b^T + rowbias[b,:]   [2048 x 2048]
        gemm_kernel<0, 1, 0, 1, 0><<<dim3(SEQ / 64, SEQ / 64), dim3(256), 0, stream>>>(
            y1b, nullptr, x2b, rbias + (size_t)b * SEQ, nullptr, attnb,
            SEQ, SEQ, D_MODEL, D_MODEL, D_MODEL, D_MODEL, SEQ);

        softmax_kernel<<<dim3(SEQ), dim3(256), 0, stream>>>(attnb);

        // x = x_cnn + tanh(attn @ x2b)  (in-place on xbuf)
        gemm_kernel<0, 0, 2, 0, 1><<<dim3(SEQ / 64, 12), dim3(256), 0, stream>>>(
            attnb, nullptr, x2b, nullptr, xb, xb,
            SEQ, D_MODEL, SEQ, SEQ, SEQ, D_MODEL, D_MODEL);
    }

    // final: out = concat(x1, x) @ fcx_w^T + fcx_b
    gemm_kernel<2, 1, 0, 1, 0><<<dim3((int)MTOT / 64, 12), dim3(256), 0, stream>>>(
        x1, xbuf, fcx_w, fcx_b, nullptr, out,
        (int)MTOT, D_MODEL, 2 * D_MODEL, 2 * D_MODEL, 0, 2 * D_MODEL, D_MODEL);
}

// Round 2
// 1628.106 us; speedup vs baseline: 3.7319x; 3.7319x over previous
//
#include <hip/hip_runtime.h>
#include <cmath>

#define D_MODEL 768
#define SEQ 2048
#define BATCH 8
#define FC_PAD 96
#define KCOMB (7 * D_MODEL)   // 5376

typedef unsigned short ushort_t;
typedef __attribute__((ext_vector_type(8))) unsigned short u16x8;
typedef __attribute__((ext_vector_type(8))) short bf16x8;
typedef __attribute__((ext_vector_type(4))) float f32x4;

__device__ __forceinline__ ushort_t f2bf(float x) {
    unsigned u = __builtin_bit_cast(unsigned, x);
    unsigned r = (u + 0x7FFFu + ((u >> 16) & 1u)) >> 16;
    return (ushort_t)r;
}
__device__ __forceinline__ float bf2f(ushort_t h) {
    return __builtin_bit_cast(float, (unsigned)h << 16);
}

// ---------------- conversion / split kernels ----------------
__global__ void split_f32_kernel(const float* __restrict__ src,
                                 ushort_t* __restrict__ hi, ushort_t* __restrict__ lo,
                                 size_t n) {
    size_t i = (size_t)blockIdx.x * 256 + threadIdx.x;
    if (i >= n) return;
    float x = src[i];
    ushort_t h = f2bf(x);
    hi[i] = h;
    lo[i] = f2bf(x - bf2f(h));
}

__global__ void convert_fcx_kernel(const float* __restrict__ src, ushort_t* __restrict__ dst, size_t n) {
    size_t i = (size_t)blockIdx.x * 256 + threadIdx.x;
    if (i < n) dst[i] = f2bf(src[i]);
}

// fc_w [768][90] -> fc_wt bf16 [768][96] zero-padded
__global__ void convert_fc_kernel(const float* __restrict__ src, ushort_t* __restrict__ dst) {
    int i = blockIdx.x * 256 + threadIdx.x;
    if (i >= D_MODEL * FC_PAD) return;
    int o = i / FC_PAD, j = i - o * FC_PAD;
    dst[i] = (j < 90) ? f2bf(src[o * 90 + j]) : 0;
}

// U [768][768] -> Ut_hi/lo [n][k] = split(U[k][n])
__global__ void split_ut_kernel(const float* __restrict__ U,
                                ushort_t* __restrict__ hi, ushort_t* __restrict__ lo) {
    int i = blockIdx.x * 256 + threadIdx.x;
    if (i >= D_MODEL * D_MODEL) return;
    int n = i / D_MODEL, k = i - n * D_MODEL;
    float x = U[(size_t)k * D_MODEL + n];
    ushort_t h = f2bf(x);
    hi[i] = h;
    lo[i] = f2bf(x - bf2f(h));
}

// combined conv weight, bf16, [96][5376] layout; rows 90..95 zero
__global__ void build_wcomb_kernel(const float* __restrict__ w7, const float* __restrict__ b7,
                                   const float* __restrict__ w5, const float* __restrict__ b5,
                                   const float* __restrict__ w3, const float* __restrict__ b3,
                                   ushort_t* __restrict__ Wt, float* __restrict__ bcat) {
    int idx = blockIdx.x * 256 + threadIdx.x;
    const int total = FC_PAD * KCOMB;
    if (idx < total) {
        int o = idx / KCOMB, k = idx - o * KCOMB;
        int t = k / D_MODEL, d = k - t * D_MODEL;
        float v = 0.f;
        if (o < 40) {
            v = w7[(size_t)o * (D_MODEL * 7) + d * 7 + t];
        } else if (o < 70) {
            int t5 = t - 1;
            if (t5 >= 0 && t5 < 5) v = w5[(size_t)(o - 40) * (D_MODEL * 5) + d * 5 + t5];
        } else if (o < 90) {
            int t3 = t - 2;
            if (t3 >= 0 && t3 < 3) v = w3[(size_t)(o - 70) * (D_MODEL * 3) + d * 3 + t3];
        }
        Wt[idx] = f2bf(v);
    }
    if (idx < FC_PAD) {
        float bv = 0.f;
        if (idx < 40) bv = b7[idx];
        else if (idx < 70) bv = b5[idx - 40];
        else if (idx < 90) bv = b3[idx - 70];
        bcat[idx] = bv;
    }
}

// x2_hi [8][2048][768] -> x2t [8][768][2048]
__global__ void transpose_bf16_kernel(const ushort_t* __restrict__ in, ushort_t* __restrict__ out) {
    __shared__ ushort_t tile[32][40];
    int b = blockIdx.z;
    int s0 = blockIdx.x * 32, d0 = blockIdx.y * 32;
    int tx = threadIdx.x & 31, ty = threadIdx.x >> 5;   // 32 x 8
    const ushort_t* inb = in + (size_t)b * SEQ * D_MODEL;
    ushort_t* outb = out + (size_t)b * D_MODEL * SEQ;
    #pragma unroll
    for (int i = 0; i < 4; ++i)
        tile[ty + i * 8][tx] = inb[(size_t)(s0 + ty + i * 8) * D_MODEL + d0 + tx];
    __syncthreads();
    #pragma unroll
    for (int i = 0; i < 4; ++i)
        outb[(size_t)(d0 + ty + i * 8) * SEQ + s0 + tx] = tile[tx][ty + i * 8];
}

// rowbias[b,t] = x2[b,t,:] . bias_v   (fp32)
__global__ void rowbias_kernel(const float* __restrict__ x2, const float* __restrict__ bias_v,
                               float* __restrict__ rowbias) {
    int row = blockIdx.x;
    const float* xr = x2 + (size_t)row * D_MODEL;
    float s = 0.f;
    for (int c = threadIdx.x; c < D_MODEL; c += 256) s += xr[c] * bias_v[c];
    for (int off = 32; off > 0; off >>= 1) s += __shfl_down(s, off);
    __shared__ float red[4];
    int lane = threadIdx.x & 63, w = threadIdx.x >> 6;
    if (lane == 0) red[w] = s;
    __syncthreads();
    if (threadIdx.x == 0) rowbias[row] = red[0] + red[1] + red[2] + red[3];
}

// row softmax: fp32 in [2048], bf16 out
__global__ void softmax_kernel(const float* __restrict__ in, ushort_t* __restrict__ outb) {
    __shared__ float ls[SEQ];
    __shared__ float red[4];
    __shared__ float bc;
    int row = blockIdx.x;
    const float* p = in + (size_t)row * SEQ;
    ushort_t* q = outb + (size_t)row * SEQ;
    int lane = threadIdx.x & 63, w = threadIdx.x >> 6;

    float mx = -1e30f;
    for (int c = threadIdx.x; c < SEQ; c += 256) { float v = p[c]; ls[c] = v; mx = fmaxf(mx, v); }
    for (int off = 32; off > 0; off >>= 1) mx = fmaxf(mx, __shfl_down(mx, off));
    if (lane == 0) red[w] = mx;
    __syncthreads();
    if (threadIdx.x == 0) bc = fmaxf(fmaxf(red[0], red[1]), fmaxf(red[2], red[3]));
    __syncthreads();
    mx = bc;
    float s = 0.f;
    for (int c = threadIdx.x; c < SEQ; c += 256) { float e = __expf(ls[c] - mx); ls[c] = e; s += e; }
    for (int off = 32; off > 0; off >>= 1) s += __shfl_down(s, off);
    if (lane == 0) red[w] = s;
    __syncthreads();
    if (threadIdx.x == 0) bc = 1.f / (red[0] + red[1] + red[2] + red[3]);
    __syncthreads();
    float inv = bc;
    for (int c = threadIdx.x; c < SEQ; c += 256) q[c] = f2bf(ls[c] * inv);
}

// ---------------- bf16 MFMA GEMM ----------------
// C[M,N] = epilogue( A' @ B'^T )  with A' [M][K] bf16, B' [N][K] bf16 (N-major).
// AMODE: 0 plain, 1 im2col(x2_hi), 2 concat(A | A2)
// SPLIT: A/Al and B/Bl hi/lo pairs, 3 MFMA per fragment (drop lo*lo)
// ACT: 0 none, 1 relu, 2 tanh; HASBIAS: +bias[n] (before ACT);
// HASADD: += bf16 addsrc[m][n] (after ACT); OUTBF16: write bf16 to Cb else f32 to Cf.
template<int AMODE, int SPLIT, int ACT, int HASBIAS, int HASADD, int OUTBF16>
__global__ __launch_bounds__(256)
void mfma_gemm(const ushort_t* __restrict__ A, const ushort_t* __restrict__ A2,
               const ushort_t* __restrict__ Al, const ushort_t* __restrict__ B,
               const ushort_t* __restrict__ Bl, const float* __restrict__ bias,
               const ushort_t* addsrc, float* Cf, ushort_t* Cb,
               int M, int N, int K, int lda, int ldb, int ldc) {
    __shared__ __align__(16) ushort_t smem[(SPLIT ? 4 : 2) * 128 * 40];
    ushort_t* As_ = smem;
    ushort_t* Bs_ = smem + 128 * 40;
    ushort_t* Als_ = smem + 2 * 128 * 40;   // SPLIT only
    ushort_t* Bls_ = smem + 3 * 128 * 40;

    const int m0 = blockIdx.x * 128;
    const int n0 = blockIdx.y * 128;
    const int tid = threadIdx.x;
    const int lane = tid & 63;
    const int wave = tid >> 6;
    const int wm = (wave >> 1) * 64, wn = (wave & 1) * 64;
    const int r16 = lane & 15, kq = lane >> 4;
    const int srow = tid >> 2;
    const int sseg = (tid & 3) * 8;

    f32x4 acc[4][4];
    #pragma unroll
    for (int i = 0; i < 4; ++i)
        #pragma unroll
        for (int j = 0; j < 4; ++j) acc[i][j] = (f32x4){0.f, 0.f, 0.f, 0.f};

    const u16x8 zv = {0, 0, 0, 0, 0, 0, 0, 0};

    for (int k0 = 0; k0 < K; k0 += 32) {
        #pragma unroll
        for (int i = 0; i < 2; ++i) {
            int m = srow + i * 64;
            int gm = m0 + m;
            int gk = k0 + sseg;
            // A tile
            u16x8 va;
            if (AMODE == 1) {
                int t = gk / D_MODEL;
                int d = gk - t * D_MODEL;
                int s = (gm & (SEQ - 1)) + t - 3;
                int bb = gm >> 11;
                va = (s >= 0 && s < SEQ) ? *(const u16x8*)(A + ((size_t)(bb * SEQ + s)) * D_MODEL + d) : zv;
            } else if (AMODE == 2) {
                va = (gk < D_MODEL) ? *(const u16x8*)(A + (size_t)gm * D_MODEL + gk)
                                    : *(const u16x8*)(A2 + (size_t)gm * D_MODEL + (gk - D_MODEL));
            } else {
                va = *(const u16x8*)(A + (size_t)gm * lda + gk);
            }
            *(u16x8*)&As_[(size_t)m * 40 + sseg] = va;
            if (SPLIT)
                *(u16x8*)&Als_[(size_t)m * 40 + sseg] = *(const u16x8*)(Al + (size_t)gm * lda + gk);
            // B tile (N-major)
            int gn = n0 + m;
            u16x8 vb = (gn < N) ? *(const u16x8*)(B + (size_t)gn * ldb + gk) : zv;
            *(u16x8*)&Bs_[(size_t)m * 40 + sseg] = vb;
            if (SPLIT) {
                u16x8 vbl = (gn < N) ? *(const u16x8*)(Bl + (size_t)gn * ldb + gk) : zv;
                *(u16x8*)&Bls_[(size_t)m * 40 + sseg] = vbl;
            }
        }
        __syncthreads();

        bf16x8 ah[4], bh[4], al_[4], bl_[4];
        #pragma unroll
        for (int mi = 0; mi < 4; ++mi)
            ah[mi] = *(const bf16x8*)&As_[(size_t)(wm + mi * 16 + r16) * 40 + kq * 8];
        #pragma unroll
        for (int ni = 0; ni < 4; ++ni)
            bh[ni] = *(const bf16x8*)&Bs_[(size_t)(wn + ni * 16 + r16) * 40 + kq * 8];
        if (SPLIT) {
            #pragma unroll
            for (int mi = 0; mi < 4; ++mi)
                al_[mi] = *(const bf16x8*)&Als_[(size_t)(wm + mi * 16 + r16) * 40 + kq * 8];
            #pragma unroll
            for (int ni = 0; ni < 4; ++ni)
                bl_[ni] = *(const bf16x8*)&Bls_[(size_t)(wn + ni * 16 + r16) * 40 + kq * 8];
        }
        #pragma unroll
        for (int mi = 0; mi < 4; ++mi)
            #pragma unroll
            for (int ni = 0; ni < 4; ++ni) {
                acc[mi][ni] = __builtin_amdgcn_mfma_f32_16x16x32_bf16(ah[mi], bh[ni], acc[mi][ni], 0, 0, 0);
                if (SPLIT) {
                    acc[mi][ni] = __builtin_amdgcn_mfma_f32_16x16x32_bf16(ah[mi], bl_[ni], acc[mi][ni], 0, 0, 0);
                    acc[mi][ni] = __builtin_amdgcn_mfma_f32_16x16x32_bf16(al_[mi], bh[ni], acc[mi][ni], 0, 0, 0);
                }
            }
        __syncthreads();
    }

    // epilogue: C/D layout col = lane&15, row = (lane>>4)*4 + r
    #pragma unroll
    for (int mi = 0; mi < 4; ++mi)
        #pragma unroll
        for (int ni = 0; ni < 4; ++ni)
            #pragma unroll
            for (int r = 0; r < 4; ++r) {
                int gm = m0 + wm + mi * 16 + kq * 4 + r;
                int gn = n0 + wn + ni * 16 + r16;
                if (gn >= N) continue;
                float v = acc[mi][ni][r];
                if (HASBIAS) v += bias[gn];
                if (ACT == 1) v = fmaxf(v, 0.f);
                else if (ACT == 2) v = tanhf(v);
                if (HASADD) v += bf2f(addsrc[(size_t)gm * ldc + gn]);
                if (OUTBF16) Cb[(size_t)gm * ldc + gn] = f2bf(v);
                else Cf[(size_t)gm * ldc + gn] = v;
            }
}

extern "C" void kernel_launch(void* const* d_in, const int* in_sizes, int n_in,
                              void* d_out, int out_size, void* d_ws, size_t ws_size,
                              hipStream_t stream) {
    const float* x1     = (const float*)d_in[0];
    const float* x2     = (const float*)d_in[1];
    const float* w7     = (const float*)d_in[2];
    const float* b7     = (const float*)d_in[3];
    const float* w5     = (const float*)d_in[4];
    const float* b5     = (const float*)d_in[5];
    const float* w3     = (const float*)d_in[6];
    const float* b3     = (const float*)d_in[7];
    const float* U      = (const float*)d_in[8];
    const float* bias_v = (const float*)d_in[9];
    const float* fc_w   = (const float*)d_in[10];
    const float* fc_b   = (const float*)d_in[11];
    const float* fcx_w  = (const float*)d_in[12];
    const float* fcx_b  = (const float*)d_in[13];
    float* out = (float*)d_out;

    const size_t MT = (size_t)BATCH * SEQ;      // 16384
    const size_t NE = MT * D_MODEL;             // 12.58M

    // ---- workspace layout (~216 MB) ----
    char* p = (char*)d_ws;
    auto alloc = [&](size_t bytes) -> char* {
        char* r = p;
        p += (bytes + 255) & ~(size_t)255;
        return r;
    };
    ushort_t* x1_hi  = (ushort_t*)alloc(NE * 2);
    ushort_t* x1_lo  = (ushort_t*)alloc(NE * 2);
    ushort_t* x2_hi  = (ushort_t*)alloc(NE * 2);
    ushort_t* x2_lo  = (ushort_t*)alloc(NE * 2);
    ushort_t* x2t    = (ushort_t*)alloc(NE * 2);
    ushort_t* y1_hi  = (ushort_t*)alloc(NE * 2);
    ushort_t* y1_lo  = (ushort_t*)alloc(NE * 2);
    ushort_t* xcnn   = (ushort_t*)alloc(NE * 2);
    ushort_t* feats  = (ushort_t*)alloc(MT * FC_PAD * 2);
    ushort_t* Wt     = (ushort_t*)alloc((size_t)FC_PAD * KCOMB * 2);
    ushort_t* fc_wt  = (ushort_t*)alloc((size_t)D_MODEL * FC_PAD * 2);
    ushort_t* fcx_wt = (ushort_t*)alloc((size_t)D_MODEL * 2 * D_MODEL * 2);
    ushort_t* Ut_hi  = (ushort_t*)alloc((size_t)D_MODEL * D_MODEL * 2);
    ushort_t* Ut_lo  = (ushort_t*)alloc((size_t)D_MODEL * D_MODEL * 2);
    ushort_t* attnb  = (ushort_t*)alloc((size_t)SEQ * SEQ * 2);
    float*    bcat   = (float*)alloc(128 * 4);
    float*    rbias  = (float*)alloc(MT * 4);
    // attn fp32 scores alias x1_lo's space (x1_lo is dead after the xU GEMM,
    // which completes before the first scores GEMM in stream order). 16.8MB <= 25.2MB.
    float*    attnf  = (float*)x1_lo;

    const int T = 256;
    auto blk = [](size_t n) { return dim3((unsigned)((n + 255) / 256)); };

    // ---- prep ----
    build_wcomb_kernel<<<blk((size_t)FC_PAD * KCOMB), T, 0, stream>>>(w7, b7, w5, b5, w3, b3, Wt, bcat);
    convert_fc_kernel<<<blk((size_t)D_MODEL * FC_PAD), T, 0, stream>>>(fc_w, fc_wt);
    convert_fcx_kernel<<<blk((size_t)D_MODEL * 2 * D_MODEL), T, 0, stream>>>(fcx_w, fcx_wt, (size_t)D_MODEL * 2 * D_MODEL);
    split_ut_kernel<<<blk((size_t)D_MODEL * D_MODEL), T, 0, stream>>>(U, Ut_hi, Ut_lo);
    split_f32_kernel<<<blk(NE), T, 0, stream>>>(x1, x1_hi, x1_lo, NE);
    split_f32_kernel<<<blk(NE), T, 0, stream>>>(x2, x2_hi, x2_lo, NE);
    transpose_bf16_kernel<<<dim3(SEQ / 32, D_MODEL / 32, BATCH), T, 0, stream>>>(x2_hi, x2t);
    rowbias_kernel<<<dim3((unsigned)MT), T, 0, stream>>>(x2, bias_v, rbias);

    // ---- conv (im2col GEMM): feats = relu(im2col(x2) @ Wcomb + bcat), bf16 out
    mfma_gemm<1, 0, 1, 1, 0, 1><<<dim3(MT / 128, 1), T, 0, stream>>>(
        x2_hi, nullptr, nullptr, Wt, nullptr, bcat, nullptr, nullptr, feats,
        (int)MT, FC_PAD, KCOMB, D_MODEL, KCOMB, FC_PAD);

    // ---- fc: xcnn = tanh(feats @ fc_w^T + fc_b), bf16 out
    mfma_gemm<0, 0, 2, 1, 0, 1><<<dim3(MT / 128, D_MODEL / 128), T, 0, stream>>>(
        feats, nullptr, nullptr, fc_wt, nullptr, fc_b, nullptr, nullptr, xcnn,
        (int)MT, D_MODEL, FC_PAD, FC_PAD, FC_PAD, D_MODEL);

    // ---- y1 = x1 @ U (split precision), fp32 into d_out
    mfma_gemm<0, 1, 0, 0, 0, 0><<<dim3(MT / 128, D_MODEL / 128), T, 0, stream>>>(
        x1_hi, nullptr, x1_lo, Ut_hi, Ut_lo, nullptr, nullptr, out, nullptr,
        (int)MT, D_MODEL, D_MODEL, D_MODEL, D_MODEL, D_MODEL);

    split_f32_kernel<<<blk(NE), T, 0, stream>>>(out, y1_hi, y1_lo, NE);

    // ---- attention per batch ----
    for (int b = 0; b < BATCH; ++b) {
        const size_t off = (size_t)b * SEQ * D_MODEL;
        // scores = y1b @ x2b^T + rowbias (split precision), fp32
        mfma_gemm<0, 1, 0, 1, 0, 0><<<dim3(SEQ / 128, SEQ / 128), T, 0, stream>>>(
            y1_hi + off, nullptr, y1_lo + off, x2_hi + off, x2_lo + off,
            rbias + (size_t)b * SEQ, nullptr, attnf, nullptr,
            SEQ, SEQ, D_MODEL, D_MODEL, D_MODEL, SEQ);

        softmax_kernel<<<dim3(SEQ), T, 0, stream>>>(attnf, attnb);

        // x = xcnn + tanh(attn @ x2b), bf16, in-place into xcnn
        mfma_gemm<0, 0, 2, 0, 1, 1><<<dim3(SEQ / 128, D_MODEL / 128), T, 0, stream>>>(
            attnb, nullptr, nullptr, x2t + off, nullptr, nullptr,
            xcnn + off, nullptr, xcnn + off,
            SEQ, D_MODEL, SEQ, SEQ, SEQ, D_MODEL);
    }

    // ---- final: out = concat(x1, x) @ fcx_w^T + fcx_b, fp32
    mfma_gemm<2, 0, 0, 1, 0, 0><<<dim3(MT / 128, D_MODEL / 128), T, 0, stream>>>(
        x1_hi, xcnn, nullptr, fcx_wt, nullptr, fcx_b, nullptr, out, nullptr,
        (int)MT, D_MODEL, 2 * D_MODEL, D_MODEL, 2 * D_MODEL, D_MODEL);
}

// Round 3
// 703.862 us; speedup vs baseline: 8.6322x; 2.3131x over previous
//
#include <hip/hip_runtime.h>
#include <cmath>

#define D_MODEL 768
#define SEQ 2048
#define BATCH 8
#define FC_PAD 96
#define KCOMB (7 * D_MODEL)   // 5376

typedef unsigned short ushort_t;
typedef __attribute__((ext_vector_type(8))) unsigned short u16x8;
typedef __attribute__((ext_vector_type(4))) unsigned short u16x4;
typedef __attribute__((ext_vector_type(8))) short bf16x8;
typedef __attribute__((ext_vector_type(4))) float f32x4;

__device__ __forceinline__ ushort_t f2bf(float x) {
    unsigned u = __builtin_bit_cast(unsigned, x);
    unsigned r = (u + 0x7FFFu + ((u >> 16) & 1u)) >> 16;
    return (ushort_t)r;
}
__device__ __forceinline__ float bf2f(ushort_t h) {
    return __builtin_bit_cast(float, (unsigned)h << 16);
}
__device__ __forceinline__ float fast_tanh(float x) {
    float a = fabsf(x);
    float t = __expf(-2.f * a);
    float r = (1.f - t) / (1.f + t);
    return copysignf(r, x);
}
// async global->LDS, 16B per lane; lbase must be wave-uniform, src is per-lane
__device__ __forceinline__ void gload16(const ushort_t* g, ushort_t* lbase) {
    __builtin_amdgcn_global_load_lds((const __attribute__((address_space(1))) void*)g,
                                     (__attribute__((address_space(3))) void*)lbase,
                                     16, 0, 0);
}

// ---------------- prep kernels ----------------
__global__ void split_f32_kernel(const float* __restrict__ src,
                                 ushort_t* __restrict__ hi, ushort_t* __restrict__ lo,
                                 size_t n4) {
    size_t i = (size_t)blockIdx.x * 256 + threadIdx.x;
    if (i >= n4) return;
    f32x4 x = *(const f32x4*)(src + i * 4);
    u16x4 h, l;
    #pragma unroll
    for (int j = 0; j < 4; ++j) {
        h[j] = f2bf(x[j]);
        l[j] = f2bf(x[j] - bf2f(h[j]));
    }
    *(u16x4*)(hi + i * 4) = h;
    *(u16x4*)(lo + i * 4) = l;
}

__global__ void convert_fcx_kernel(const float* __restrict__ src, ushort_t* __restrict__ dst, size_t n4) {
    size_t i = (size_t)blockIdx.x * 256 + threadIdx.x;
    if (i >= n4) return;
    f32x4 x = *(const f32x4*)(src + i * 4);
    u16x4 h;
    #pragma unroll
    for (int j = 0; j < 4; ++j) h[j] = f2bf(x[j]);
    *(u16x4*)(dst + i * 4) = h;
}

// fc_w [768][90] -> fc_wt bf16 [768][96] zero-padded
__global__ void convert_fc_kernel(const float* __restrict__ src, ushort_t* __restrict__ dst) {
    int i = blockIdx.x * 256 + threadIdx.x;
    if (i >= D_MODEL * FC_PAD) return;
    int o = i / FC_PAD, j = i - o * FC_PAD;
    dst[i] = (j < 90) ? f2bf(src[o * 90 + j]) : 0;
}

// U [768][768] -> Ut_hi/lo [n][k] = split(U[k][n])
__global__ void split_ut_kernel(const float* __restrict__ U,
                                ushort_t* __restrict__ hi, ushort_t* __restrict__ lo) {
    int i = blockIdx.x * 256 + threadIdx.x;
    if (i >= D_MODEL * D_MODEL) return;
    int n = i / D_MODEL, k = i - n * D_MODEL;
    float x = U[(size_t)k * D_MODEL + n];
    ushort_t h = f2bf(x);
    hi[i] = h;
    lo[i] = f2bf(x - bf2f(h));
}

// combined conv weight, bf16, [96][5376]; rows 90..95 zero
__global__ void build_wcomb_kernel(const float* __restrict__ w7, const float* __restrict__ b7,
                                   const float* __restrict__ w5, const float* __restrict__ b5,
                                   const float* __restrict__ w3, const float* __restrict__ b3,
                                   ushort_t* __restrict__ Wt, float* __restrict__ bcat) {
    int idx = blockIdx.x * 256 + threadIdx.x;
    const int total = FC_PAD * KCOMB;
    if (idx < total) {
        int o = idx / KCOMB, k = idx - o * KCOMB;
        int t = k / D_MODEL, d = k - t * D_MODEL;
        float v = 0.f;
        if (o < 40) {
            v = w7[(size_t)o * (D_MODEL * 7) + d * 7 + t];
        } else if (o < 70) {
            int t5 = t - 1;
            if (t5 >= 0 && t5 < 5) v = w5[(size_t)(o - 40) * (D_MODEL * 5) + d * 5 + t5];
        } else if (o < 90) {
            int t3 = t - 2;
            if (t3 >= 0 && t3 < 3) v = w3[(size_t)(o - 70) * (D_MODEL * 3) + d * 3 + t3];
        }
        Wt[idx] = f2bf(v);
    }
    if (idx < FC_PAD) {
        float bv = 0.f;
        if (idx < 40) bv = b7[idx];
        else if (idx < 70) bv = b5[idx - 40];
        else if (idx < 90) bv = b3[idx - 70];
        bcat[idx] = bv;
    }
}

// x2_hi [8][2048][768] -> x2t [8][768][2048]
__global__ void transpose_bf16_kernel(const ushort_t* __restrict__ in, ushort_t* __restrict__ out) {
    __shared__ ushort_t tile[32][40];
    int b = blockIdx.z;
    int s0 = blockIdx.x * 32, d0 = blockIdx.y * 32;
    int tx = threadIdx.x & 31, ty = threadIdx.x >> 5;   // 32 x 8
    const ushort_t* inb = in + (size_t)b * SEQ * D_MODEL;
    ushort_t* outb = out + (size_t)b * D_MODEL * SEQ;
    #pragma unroll
    for (int i = 0; i < 4; ++i)
        tile[ty + i * 8][tx] = inb[(size_t)(s0 + ty + i * 8) * D_MODEL + d0 + tx];
    __syncthreads();
    #pragma unroll
    for (int i = 0; i < 4; ++i)
        outb[(size_t)(d0 + ty + i * 8) * SEQ + s0 + tx] = tile[tx][ty + i * 8];
}

// rowbias[b,t] = x2[b,t,:] . bias_v   (fp32)
__global__ void rowbias_kernel(const float* __restrict__ x2, const float* __restrict__ bias_v,
                               float* __restrict__ rowbias) {
    int row = blockIdx.x;
    const float* xr = x2 + (size_t)row * D_MODEL;
    float s = 0.f;
    for (int c = threadIdx.x; c < D_MODEL; c += 256) s += xr[c] * bias_v[c];
    for (int off = 32; off > 0; off >>= 1) s += __shfl_down(s, off);
    __shared__ float red[4];
    int lane = threadIdx.x & 63, w = threadIdx.x >> 6;
    if (lane == 0) red[w] = s;
    __syncthreads();
    if (threadIdx.x == 0) rowbias[row] = red[0] + red[1] + red[2] + red[3];
}

// row softmax: fp32 in [2048], bf16 out
__global__ void softmax_kernel(const float* __restrict__ in, ushort_t* __restrict__ outb) {
    __shared__ float ls[SEQ];
    __shared__ float red[4];
    __shared__ float bc;
    int row = blockIdx.x;
    const float* p = in + (size_t)row * SEQ;
    ushort_t* q = outb + (size_t)row * SEQ;
    int lane = threadIdx.x & 63, w = threadIdx.x >> 6;

    float mx = -1e30f;
    for (int c = threadIdx.x; c < SEQ; c += 256) { float v = p[c]; ls[c] = v; mx = fmaxf(mx, v); }
    for (int off = 32; off > 0; off >>= 1) mx = fmaxf(mx, __shfl_down(mx, off));
    if (lane == 0) red[w] = mx;
    __syncthreads();
    if (threadIdx.x == 0) bc = fmaxf(fmaxf(red[0], red[1]), fmaxf(red[2], red[3]));
    __syncthreads();
    mx = bc;
    float s = 0.f;
    for (int c = threadIdx.x; c < SEQ; c += 256) { float e = __expf(ls[c] - mx); ls[c] = e; s += e; }
    for (int off = 32; off > 0; off >>= 1) s += __shfl_down(s, off);
    if (lane == 0) red[w] = s;
    __syncthreads();
    if (threadIdx.x == 0) bc = 1.f / (red[0] + red[1] + red[2] + red[3]);
    __syncthreads();
    float inv = bc;
    for (int c = threadIdx.x; c < SEQ; c += 256) q[c] = f2bf(ls[c] * inv);
}

// ---------------- bf16 MFMA GEMM (m97 structure: BK=32, linear LDS, global_load_lds) ----------------
// C[M,N] = epilogue( A' @ B'^T ); A' [M][K] bf16, B' [N][K] bf16 (N-major).
// TM/TN: block tile (waves 2x2, wave tile TM/2 x TN/2).
// AMODE: 0 plain, 1 im2col(x2_hi, VGPR-staged), 2 concat(A | A2)
// SPLIT: hi/lo pairs on A and B, 3 MFMA per fragment (drop lo*lo)
// ACT: 0 none, 1 relu, 2 tanh; HASBIAS: +bias[n] before ACT; HASADD: += bf16 addsrc after ACT
// OUTMODE: 0 fp32->Cf, 1 bf16->Cb, 2 split bf16 -> Cb(hi), Cl(lo)
// blockIdx.z batches with strides sA/sB/sBias/sC.
template<int TM, int TN, int AMODE, int SPLIT, int ACT, int HASBIAS, int HASADD, int OUTMODE>
__global__ __launch_bounds__(256, SPLIT ? 3 : 4)
void mfma_gemm(const ushort_t* __restrict__ A, const ushort_t* __restrict__ A2,
               const ushort_t* __restrict__ Al, const ushort_t* __restrict__ B,
               const ushort_t* __restrict__ Bl, const float* __restrict__ bias,
               const ushort_t* __restrict__ addsrc,
               float* __restrict__ Cf, ushort_t* __restrict__ Cb, ushort_t* __restrict__ Cl,
               int M, int N, int K, int lda, int ldb, int ldc,
               size_t sA, size_t sB, size_t sBias, size_t sC) {
    constexpr int WM = TM / 2, WN = TN / 2, FM = WM / 16, FN = WN / 16;
    __shared__ __align__(16) ushort_t As_[TM * 32];
    __shared__ __align__(16) ushort_t Bs_[TN * 32];
    __shared__ __align__(16) ushort_t Als_[SPLIT ? TM * 32 : 16];
    __shared__ __align__(16) ushort_t Bls_[SPLIT ? TN * 32 : 16];

    const int z = blockIdx.z;
    A += (size_t)z * sA;
    if (SPLIT) { Al += (size_t)z * sA; Bl += (size_t)z * sB; }
    B += (size_t)z * sB;
    if (HASBIAS) bias += (size_t)z * sBias;
    if (HASADD) addsrc += (size_t)z * sC;
    if (OUTMODE == 0) Cf += (size_t)z * sC;
    else { Cb += (size_t)z * sC; if (OUTMODE == 2) Cl += (size_t)z * sC; }

    const int m0 = blockIdx.x * TM;
    const int n0 = blockIdx.y * TN;
    const int tid = threadIdx.x;
    const int lane = tid & 63;
    const int wave = tid >> 6;
    const int wm = (wave >> 1) * WM, wn = (wave & 1) * WN;
    const int r16 = lane & 15, kq = lane >> 4;
    const int srow = tid >> 2;
    const int scol = (tid & 3) * 8;

    f32x4 acc[FM][FN];
    #pragma unroll
    for (int i = 0; i < FM; ++i)
        #pragma unroll
        for (int j = 0; j < FN; ++j) acc[i][j] = (f32x4){0.f, 0.f, 0.f, 0.f};

    const u16x8 zv = {0, 0, 0, 0, 0, 0, 0, 0};

    for (int k0 = 0; k0 < K; k0 += 32) {
        // ---- stage A ----
        if (AMODE == 1) {
            #pragma unroll
            for (int i = 0; i < TM / 64; ++i) {
                int m = srow + i * 64;
                int gm = m0 + m;
                int gk = k0 + scol;
                int t = gk / D_MODEL, d = gk - t * D_MODEL;
                int s = (gm & (SEQ - 1)) + t - 3;
                int bb = gm >> 11;
                u16x8 va = (s >= 0 && s < SEQ) ? *(const u16x8*)(A + ((size_t)(bb * SEQ + s)) * lda + d) : zv;
                *(u16x8*)&As_[m * 32 + scol] = va;
            }
        } else {
            #pragma unroll
            for (int i = 0; i < TM / 64; ++i) {
                int gm = m0 + srow + i * 64;
                int gk = k0 + scol;
                const ushort_t* src;
                if (AMODE == 2)
                    src = (gk < D_MODEL) ? A + (size_t)gm * lda + gk
                                         : A2 + (size_t)gm * lda + (gk - D_MODEL);
                else
                    src = A + (size_t)gm * lda + gk;
                gload16(src, &As_[(i * 64 + wave * 16) * 32]);
                if (SPLIT) gload16(Al + (size_t)gm * lda + gk, &Als_[(i * 64 + wave * 16) * 32]);
            }
        }
        // ---- stage B ----
        #pragma unroll
        for (int i = 0; i < TN / 64; ++i) {
            int gn = n0 + srow + i * 64;
            int gk = k0 + scol;
            gload16(B + (size_t)gn * ldb + gk, &Bs_[(i * 64 + wave * 16) * 32]);
            if (SPLIT) gload16(Bl + (size_t)gn * ldb + gk, &Bls_[(i * 64 + wave * 16) * 32]);
        }
        __syncthreads();

        bf16x8 ah[FM], bh[FN];
        #pragma unroll
        for (int mi = 0; mi < FM; ++mi)
            ah[mi] = *(const bf16x8*)&As_[(wm + mi * 16 + r16) * 32 + kq * 8];
        #pragma unroll
        for (int ni = 0; ni < FN; ++ni)
            bh[ni] = *(const bf16x8*)&Bs_[(wn + ni * 16 + r16) * 32 + kq * 8];
        if (SPLIT) {
            bf16x8 al2[FM], bl2[FN];
            #pragma unroll
            for (int mi = 0; mi < FM; ++mi)
                al2[mi] = *(const bf16x8*)&Als_[(wm + mi * 16 + r16) * 32 + kq * 8];
            #pragma unroll
            for (int ni = 0; ni < FN; ++ni)
                bl2[ni] = *(const bf16x8*)&Bls_[(wn + ni * 16 + r16) * 32 + kq * 8];
            #pragma unroll
            for (int mi = 0; mi < FM; ++mi)
                #pragma unroll
                for (int ni = 0; ni < FN; ++ni) {
                    acc[mi][ni] = __builtin_amdgcn_mfma_f32_16x16x32_bf16(ah[mi], bh[ni], acc[mi][ni], 0, 0, 0);
                    acc[mi][ni] = __builtin_amdgcn_mfma_f32_16x16x32_bf16(ah[mi], bl2[ni], acc[mi][ni], 0, 0, 0);
                    acc[mi][ni] = __builtin_amdgcn_mfma_f32_16x16x32_bf16(al2[mi], bh[ni], acc[mi][ni], 0, 0, 0);
                }
        } else {
            #pragma unroll
            for (int mi = 0; mi < FM; ++mi)
                #pragma unroll
                for (int ni = 0; ni < FN; ++ni)
                    acc[mi][ni] = __builtin_amdgcn_mfma_f32_16x16x32_bf16(ah[mi], bh[ni], acc[mi][ni], 0, 0, 0);
        }
        __syncthreads();
    }

    // epilogue: C/D layout col = lane&15, row = (lane>>4)*4 + r
    #pragma unroll
    for (int mi = 0; mi < FM; ++mi)
        #pragma unroll
        for (int ni = 0; ni < FN; ++ni)
            #pragma unroll
            for (int r = 0; r < 4; ++r) {
                int gm = m0 + wm + mi * 16 + kq * 4 + r;
                int gn = n0 + wn + ni * 16 + r16;
                if (gn >= N) continue;
                float v = acc[mi][ni][r];
                if (HASBIAS) v += bias[gn];
                if (ACT == 1) v = fmaxf(v, 0.f);
                else if (ACT == 2) v = fast_tanh(v);
                if (HASADD) v += bf2f(addsrc[(size_t)gm * ldc + gn]);
                size_t idx = (size_t)gm * ldc + gn;
                if (OUTMODE == 0) {
                    Cf[idx] = v;
                } else if (OUTMODE == 1) {
                    Cb[idx] = f2bf(v);
                } else {
                    ushort_t h = f2bf(v);
                    Cb[idx] = h;
                    Cl[idx] = f2bf(v - bf2f(h));
                }
            }
}

extern "C" void kernel_launch(void* const* d_in, const int* in_sizes, int n_in,
                              void* d_out, int out_size, void* d_ws, size_t ws_size,
                              hipStream_t stream) {
    const float* x1     = (const float*)d_in[0];
    const float* x2     = (const float*)d_in[1];
    const float* w7     = (const float*)d_in[2];
    const float* b7     = (const float*)d_in[3];
    const float* w5     = (const float*)d_in[4];
    const float* b5     = (const float*)d_in[5];
    const float* w3     = (const float*)d_in[6];
    const float* b3     = (const float*)d_in[7];
    const float* U      = (const float*)d_in[8];
    const float* bias_v = (const float*)d_in[9];
    const float* fc_w   = (const float*)d_in[10];
    const float* fc_b   = (const float*)d_in[11];
    const float* fcx_w  = (const float*)d_in[12];
    const float* fcx_b  = (const float*)d_in[13];
    float* out = (float*)d_out;

    const size_t MT = (size_t)BATCH * SEQ;      // 16384
    const size_t NE = MT * D_MODEL;             // 12.58M
    const size_t NEb = (size_t)SEQ * D_MODEL;   // per-batch elems

    char* p = (char*)d_ws;
    auto alloc = [&](size_t bytes) -> char* {
        char* r = p;
        p += (bytes + 255) & ~(size_t)255;
        return r;
    };
    ushort_t* x1_hi  = (ushort_t*)alloc(NE * 2);
    ushort_t* x1_lo  = (ushort_t*)alloc(NE * 2);   // dead after xU -> reused as attnb
    ushort_t* x2_hi  = (ushort_t*)alloc(NE * 2);
    ushort_t* x2_lo  = (ushort_t*)alloc(NE * 2);
    ushort_t* x2t    = (ushort_t*)alloc(NE * 2);
    ushort_t* y1_hi  = (ushort_t*)alloc(NE * 2);
    ushort_t* y1_lo  = (ushort_t*)alloc(NE * 2);
    ushort_t* xcnn   = (ushort_t*)alloc(NE * 2);
    ushort_t* feats  = (ushort_t*)alloc(MT * FC_PAD * 2);
    ushort_t* Wt     = (ushort_t*)alloc((size_t)FC_PAD * KCOMB * 2);  // OOB rows 96..127 read harmlessly into following allocs
    ushort_t* fc_wt  = (ushort_t*)alloc((size_t)D_MODEL * FC_PAD * 2);
    ushort_t* fcx_wt = (ushort_t*)alloc((size_t)D_MODEL * 2 * D_MODEL * 2);
    ushort_t* Ut_hi  = (ushort_t*)alloc((size_t)D_MODEL * D_MODEL * 2);
    ushort_t* Ut_lo  = (ushort_t*)alloc((size_t)D_MODEL * D_MODEL * 2);
    float*    bcat   = (float*)alloc(128 * 4);
    float*    rbias  = (float*)alloc(MT * 4);

    // aliases for attention scratch:
    // attnf (fp32 scores, <=3 batches = 50.33MB) lives in d_out (dead until final GEMM)
    // attnb (bf16 softmax, <=3 batches = 25.17MB) lives in x1_lo (dead after xU GEMM)
    float*    attnf = (float*)d_out;
    ushort_t* attnb = x1_lo;

    const int T = 256;
    auto blk = [](size_t n) { return dim3((unsigned)((n + 255) / 256)); };

    // ---- prep ----
    build_wcomb_kernel<<<blk((size_t)FC_PAD * KCOMB), T, 0, stream>>>(w7, b7, w5, b5, w3, b3, Wt, bcat);
    convert_fc_kernel<<<blk((size_t)D_MODEL * FC_PAD), T, 0, stream>>>(fc_w, fc_wt);
    convert_fcx_kernel<<<blk((size_t)D_MODEL * 2 * D_MODEL / 4), T, 0, stream>>>(fcx_w, fcx_wt, (size_t)D_MODEL * 2 * D_MODEL / 4);
    split_ut_kernel<<<blk((size_t)D_MODEL * D_MODEL), T, 0, stream>>>(U, Ut_hi, Ut_lo);
    split_f32_kernel<<<blk(NE / 4), T, 0, stream>>>(x1, x1_hi, x1_lo, NE / 4);
    split_f32_kernel<<<blk(NE / 4), T, 0, stream>>>(x2, x2_hi, x2_lo, NE / 4);
    transpose_bf16_kernel<<<dim3(SEQ / 32, D_MODEL / 32, BATCH), T, 0, stream>>>(x2_hi, x2t);
    rowbias_kernel<<<dim3((unsigned)MT), T, 0, stream>>>(x2, bias_v, rbias);

    // ---- conv (im2col GEMM): feats = relu(im2col(x2) @ Wcomb + bcat), bf16
    mfma_gemm<64, 128, 1, 0, 1, 1, 0, 1><<<dim3(MT / 64, 1, 1), T, 0, stream>>>(
        x2_hi, nullptr, nullptr, Wt, nullptr, bcat, nullptr,
        nullptr, feats, nullptr,
        (int)MT, FC_PAD, KCOMB, D_MODEL, KCOMB, FC_PAD, 0, 0, 0, 0);

    // ---- fc: xcnn = tanh(feats @ fc_w^T + fc_b), bf16
    mfma_gemm<128, 128, 0, 0, 2, 1, 0, 1><<<dim3(MT / 128, D_MODEL / 128, 1), T, 0, stream>>>(
        feats, nullptr, nullptr, fc_wt, nullptr, fc_b, nullptr,
        nullptr, xcnn, nullptr,
        (int)MT, D_MODEL, FC_PAD, FC_PAD, FC_PAD, D_MODEL, 0, 0, 0, 0);

    // ---- y1 = x1 @ U (split precision), split bf16 out (hi,lo)
    mfma_gemm<128, 128, 0, 1, 0, 0, 0, 2><<<dim3(MT / 128, D_MODEL / 128, 1), T, 0, stream>>>(
        x1_hi, nullptr, x1_lo, Ut_hi, Ut_lo, nullptr, nullptr,
        nullptr, y1_hi, y1_lo,
        (int)MT, D_MODEL, D_MODEL, D_MODEL, D_MODEL, D_MODEL, 0, 0, 0, 0);

    // ---- attention in chunks of {3,3,2} batches ----
    const int b0s[3] = {0, 3, 6};
    const int nbs[3] = {3, 3, 2};
    for (int c = 0; c < 3; ++c) {
        const int b0 = b0s[c], nb = nbs[c];
        const size_t off = (size_t)b0 * NEb;

        // scores = y1 @ x2^T + rowbias (split), fp32 into attnf (=d_out)
        mfma_gemm<128, 128, 0, 1, 0, 1, 0, 0><<<dim3(SEQ / 128, SEQ / 128, nb), T, 0, stream>>>(
            y1_hi + off, nullptr, y1_lo + off, x2_hi + off, x2_lo + off,
            rbias + (size_t)b0 * SEQ, nullptr,
            attnf, nullptr, nullptr,
            SEQ, SEQ, D_MODEL, D_MODEL, D_MODEL, SEQ,
            NEb, NEb, SEQ, (size_t)SEQ * SEQ);

        softmax_kernel<<<dim3((unsigned)(nb * SEQ)), T, 0, stream>>>(attnf, attnb);

        // x = xcnn + tanh(attn @ x2), bf16 in-place into xcnn
        mfma_gemm<64, 128, 0, 0, 2, 0, 1, 1><<<dim3(SEQ / 64, D_MODEL / 128, nb), T, 0, stream>>>(
            attnb, nullptr, nullptr, x2t + off, nullptr, nullptr,
            xcnn + off,
            nullptr, xcnn + off, nullptr,
            SEQ, D_MODEL, SEQ, SEQ, SEQ, D_MODEL,
            (size_t)SEQ * SEQ, NEb, 0, NEb);
    }

    // ---- final: out = concat(x1, x) @ fcx_w^T + fcx_b, fp32 into d_out
    mfma_gemm<128, 128, 2, 0, 0, 1, 0, 0><<<dim3(MT / 128, D_MODEL / 128, 1), T, 0, stream>>>(
        x1_hi, xcnn, nullptr, fcx_wt, nullptr, fcx_b, nullptr,
        out, nullptr, nullptr,
        (int)MT, D_MODEL, 2 * D_MODEL, D_MODEL, 2 * D_MODEL, D_MODEL, 0, 0, 0, 0);
}

// Round 4
// 539.204 us; speedup vs baseline: 11.2682x; 1.3054x over previous
//
#include <hip/hip_runtime.h>
#include <cmath>

#define D_MODEL 768
#define SEQ 2048
#define BATCH 8
#define FC_PAD 96
#define FC_PAD2 128
#define KCOMB (7 * D_MODEL)   // 5376
#define KCHUNK 1344           // KCOMB/4

typedef unsigned short ushort_t;
typedef __attribute__((ext_vector_type(8))) unsigned short u16x8;
typedef __attribute__((ext_vector_type(4))) unsigned short u16x4;
typedef __attribute__((ext_vector_type(8))) short bf16x8;
typedef __attribute__((ext_vector_type(4))) float f32x4;

struct Ptr8  { const ushort_t* p[8]; };
struct Ptr8w { ushort_t* p[8]; };

__device__ __forceinline__ ushort_t f2bf(float x) {
    unsigned u = __builtin_bit_cast(unsigned, x);
    unsigned r = (u + 0x7FFFu + ((u >> 16) & 1u)) >> 16;
    return (ushort_t)r;
}
__device__ __forceinline__ float bf2f(ushort_t h) {
    return __builtin_bit_cast(float, (unsigned)h << 16);
}
__device__ __forceinline__ float fast_tanh(float x) {
    float a = fabsf(x);
    float t = __expf(-2.f * a);
    float r = (1.f - t) / (1.f + t);
    return copysignf(r, x);
}
__device__ __forceinline__ void gload16(const ushort_t* g, ushort_t* lbase) {
    __builtin_amdgcn_global_load_lds((const __attribute__((address_space(1))) void*)g,
                                     (__attribute__((address_space(3))) void*)lbase,
                                     16, 0, 0);
}

// ---------------- prep kernels ----------------
__global__ void split_f32_kernel(const float* __restrict__ src,
                                 ushort_t* __restrict__ hi, ushort_t* __restrict__ lo,
                                 size_t n4) {
    size_t i = (size_t)blockIdx.x * 256 + threadIdx.x;
    if (i >= n4) return;
    f32x4 x = *(const f32x4*)(src + i * 4);
    u16x4 h, l;
    #pragma unroll
    for (int j = 0; j < 4; ++j) {
        h[j] = f2bf(x[j]);
        l[j] = f2bf(x[j] - bf2f(h[j]));
    }
    *(u16x4*)(hi + i * 4) = h;
    *(u16x4*)(lo + i * 4) = l;
}

__global__ void convert_fcx_kernel(const float* __restrict__ src, ushort_t* __restrict__ dst, size_t n4) {
    size_t i = (size_t)blockIdx.x * 256 + threadIdx.x;
    if (i >= n4) return;
    f32x4 x = *(const f32x4*)(src + i * 4);
    u16x4 h;
    #pragma unroll
    for (int j = 0; j < 4; ++j) h[j] = f2bf(x[j]);
    *(u16x4*)(dst + i * 4) = h;
}

// fc_w [768][90] -> fc_wt bf16 [768][128] zero-padded
__global__ void convert_fc_kernel(const float* __restrict__ src, ushort_t* __restrict__ dst) {
    int i = blockIdx.x * 256 + threadIdx.x;
    if (i >= D_MODEL * FC_PAD2) return;
    int o = i / FC_PAD2, j = i - o * FC_PAD2;
    dst[i] = (j < 90) ? f2bf(src[o * 90 + j]) : 0;
}

// U [768][768] -> Ut_hi/lo [n][k] = split(U[k][n])
__global__ void split_ut_kernel(const float* __restrict__ U,
                                ushort_t* __restrict__ hi, ushort_t* __restrict__ lo) {
    int i = blockIdx.x * 256 + threadIdx.x;
    if (i >= D_MODEL * D_MODEL) return;
    int n = i / D_MODEL, k = i - n * D_MODEL;
    float x = U[(size_t)k * D_MODEL + n];
    ushort_t h = f2bf(x);
    hi[i] = h;
    lo[i] = f2bf(x - bf2f(h));
}

// combined conv weight, bf16, [128][5376]; rows 90..127 zero
__global__ void build_wcomb_kernel(const float* __restrict__ w7, const float* __restrict__ b7,
                                   const float* __restrict__ w5, const float* __restrict__ b5,
                                   const float* __restrict__ w3, const float* __restrict__ b3,
                                   ushort_t* __restrict__ Wt, float* __restrict__ bcat) {
    int idx = blockIdx.x * 256 + threadIdx.x;
    const int total = FC_PAD2 * KCOMB;
    if (idx < total) {
        int o = idx / KCOMB, k = idx - o * KCOMB;
        int t = k / D_MODEL, d = k - t * D_MODEL;
        float v = 0.f;
        if (o < 40) {
            v = w7[(size_t)o * (D_MODEL * 7) + d * 7 + t];
        } else if (o < 70) {
            int t5 = t - 1;
            if (t5 >= 0 && t5 < 5) v = w5[(size_t)(o - 40) * (D_MODEL * 5) + d * 5 + t5];
        } else if (o < 90) {
            int t3 = t - 2;
            if (t3 >= 0 && t3 < 3) v = w3[(size_t)(o - 70) * (D_MODEL * 3) + d * 3 + t3];
        }
        Wt[idx] = f2bf(v);
    }
    if (idx < FC_PAD2) {
        float bv = 0.f;
        if (idx < 40) bv = b7[idx];
        else if (idx < 70) bv = b5[idx - 40];
        else if (idx < 90) bv = b3[idx - 70];
        bcat[idx] = bv;
    }
}

// sum 4 conv partials + bias + relu -> feats bf16 [16384][128] (cols 96.. zero)
__global__ void conv_reduce_kernel(const float* __restrict__ P, const float* __restrict__ bcat,
                                   ushort_t* __restrict__ feats) {
    const size_t MT = (size_t)BATCH * SEQ;
    size_t i = (size_t)blockIdx.x * 256 + threadIdx.x;
    if (i >= MT * FC_PAD2) return;
    int col = (int)(i & (FC_PAD2 - 1));
    size_t row = i >> 7;
    float v = 0.f;
    if (col < FC_PAD) {
        size_t idx = row * FC_PAD + col;
        const size_t st = MT * FC_PAD;
        v = P[idx] + P[idx + st] + P[idx + 2 * st] + P[idx + 3 * st] + bcat[col];
        v = fmaxf(v, 0.f);
    }
    feats[i] = f2bf(v);
}

// x2_hi [8][2048][768] -> x2t [8][768][2048]
__global__ void transpose_bf16_kernel(const ushort_t* __restrict__ in, ushort_t* __restrict__ out) {
    __shared__ ushort_t tile[32][40];
    int b = blockIdx.z;
    int s0 = blockIdx.x * 32, d0 = blockIdx.y * 32;
    int tx = threadIdx.x & 31, ty = threadIdx.x >> 5;   // 32 x 8
    const ushort_t* inb = in + (size_t)b * SEQ * D_MODEL;
    ushort_t* outb = out + (size_t)b * D_MODEL * SEQ;
    #pragma unroll
    for (int i = 0; i < 4; ++i)
        tile[ty + i * 8][tx] = inb[(size_t)(s0 + ty + i * 8) * D_MODEL + d0 + tx];
    __syncthreads();
    #pragma unroll
    for (int i = 0; i < 4; ++i)
        outb[(size_t)(d0 + ty + i * 8) * SEQ + s0 + tx] = tile[tx][ty + i * 8];
}

// rowbias[b,t] = x2[b,t,:] . bias_v   (fp32)
__global__ void rowbias_kernel(const float* __restrict__ x2, const float* __restrict__ bias_v,
                               float* __restrict__ rowbias) {
    int row = blockIdx.x;
    const float* xr = x2 + (size_t)row * D_MODEL;
    float s = 0.f;
    for (int c = threadIdx.x; c < D_MODEL; c += 256) s += xr[c] * bias_v[c];
    for (int off = 32; off > 0; off >>= 1) s += __shfl_down(s, off);
    __shared__ float red[4];
    int lane = threadIdx.x & 63, w = threadIdx.x >> 6;
    if (lane == 0) red[w] = s;
    __syncthreads();
    if (threadIdx.x == 0) rowbias[row] = red[0] + red[1] + red[2] + red[3];
}

// row softmax: fp32 in [2048], bf16 out via per-batch pointer table
__global__ void softmax_kernel(const float* __restrict__ in, Ptr8w ptrs, int b0) {
    __shared__ float ls[SEQ];
    __shared__ float red[4];
    __shared__ float bc;
    int row = blockIdx.x;
    const float* p = in + (size_t)row * SEQ;
    ushort_t* q = ptrs.p[b0 + (row >> 11)] + (size_t)(row & (SEQ - 1)) * SEQ;
    int lane = threadIdx.x & 63, w = threadIdx.x >> 6;

    float mx = -1e30f;
    for (int c = threadIdx.x; c < SEQ; c += 256) { float v = p[c]; ls[c] = v; mx = fmaxf(mx, v); }
    for (int off = 32; off > 0; off >>= 1) mx = fmaxf(mx, __shfl_down(mx, off));
    if (lane == 0) red[w] = mx;
    __syncthreads();
    if (threadIdx.x == 0) bc = fmaxf(fmaxf(red[0], red[1]), fmaxf(red[2], red[3]));
    __syncthreads();
    mx = bc;
    float s = 0.f;
    for (int c = threadIdx.x; c < SEQ; c += 256) { float e = __expf(ls[c] - mx); ls[c] = e; s += e; }
    for (int off = 32; off > 0; off >>= 1) s += __shfl_down(s, off);
    if (lane == 0) red[w] = s;
    __syncthreads();
    if (threadIdx.x == 0) bc = 1.f / (red[0] + red[1] + red[2] + red[3]);
    __syncthreads();
    float inv = bc;
    for (int c = threadIdx.x; c < SEQ; c += 256) q[c] = f2bf(ls[c] * inv);
}

// ---------------- bf16 MFMA GEMM, 128B LDS rows + XOR slot swizzle ----------------
// C[M,N] = epilogue( A' @ B'^T ); A' [M][K] bf16, B' [N][K] bf16 (N-major).
// LDS rows: 64 elems (8 x 16B slots), slot ^= (row&7) folded into the GLOBAL source
// address (linear global_load_lds dest, swizzled read — rule #21).
// SPLIT: row packs [hi 32k | lo 32k]; 32 real k per iter, 48 MFMA.
// non-SPLIT: 64 real k per iter, FM*FN*2 MFMA.
// AMODE: 0 plain, 1 im2col(x2_hi, VGPR-staged), 2 concat(A|A2, stride 768)
// KSPLIT: blockIdx.z = K-chunk (kbase = z*K), C offset z*sC, A/B not z-offset.
// APTR: A base = ap.p[blockIdx.z].
// OUTMODE: 0 fp32->Cf, 1 bf16->Cb, 2 split bf16 -> Cb,Cl
template<int TM, int TN, int AMODE, int SPLIT, int ACT, int HASBIAS, int HASADD,
         int OUTMODE, int KSPLIT, int APTR>
__global__ __launch_bounds__(256, 3)
void mfma_gemm(const ushort_t* __restrict__ A, const ushort_t* __restrict__ A2,
               const ushort_t* __restrict__ Al, const ushort_t* __restrict__ B,
               const ushort_t* __restrict__ Bl, const float* __restrict__ bias,
               const ushort_t* __restrict__ addsrc,
               float* __restrict__ Cf, ushort_t* __restrict__ Cb, ushort_t* __restrict__ Cl,
               Ptr8 ap,
               int M, int N, int K, int lda, int ldb, int ldc,
               size_t sA, size_t sB, size_t sBias, size_t sC) {
    constexpr int WM = TM / 2, WN = TN / 2, FM = WM / 16, FN = WN / 16;
    __shared__ __align__(16) ushort_t As_[TM * 64];
    __shared__ __align__(16) ushort_t Bs_[TN * 64];

    const int z = blockIdx.z;
    const int kb = KSPLIT ? z * K : 0;
    const ushort_t* Ab = APTR ? ap.p[z] : (A + (KSPLIT ? 0 : (size_t)z * sA));
    const ushort_t* Alb = Al;
    const ushort_t* Bb = B + (KSPLIT ? 0 : (size_t)z * sB);
    const ushort_t* Blb = Bl;
    if (SPLIT) { Alb += (size_t)z * sA; Blb += (size_t)z * sB; }
    if (HASBIAS) bias += (size_t)z * sBias;
    if (HASADD) addsrc += (size_t)z * sC;
    if (OUTMODE == 0) Cf += (size_t)z * sC;
    else { Cb += (size_t)z * sC; if (OUTMODE == 2) Cl += (size_t)z * sC; }

    const int m0 = blockIdx.x * TM;
    const int n0 = blockIdx.y * TN;
    const int tid = threadIdx.x;
    const int lane = tid & 63;
    const int wave = tid >> 6;
    const int wm = (wave >> 1) * WM, wn = (wave & 1) * WN;
    const int r16 = lane & 15, kq = lane >> 4;
    const int srow = tid >> 3;          // 0..31
    const int slot = tid & 7;           // 16B slot (LDS-linear)

    f32x4 acc[FM][FN];
    #pragma unroll
    for (int i = 0; i < FM; ++i)
        #pragma unroll
        for (int j = 0; j < FN; ++j) acc[i][j] = (f32x4){0.f, 0.f, 0.f, 0.f};

    const u16x8 zv = {0, 0, 0, 0, 0, 0, 0, 0};
    const int kstep = SPLIT ? 32 : 64;

    for (int k0 = 0; k0 < K; k0 += kstep) {
        // ---- stage A ----
        #pragma unroll
        for (int i = 0; i < TM / 32; ++i) {
            int row = i * 32 + srow;
            int gm = m0 + row;
            int xs = slot ^ (row & 7);
            if (AMODE == 1) {
                int gkk = kb + k0 + xs * 8;
                int t = gkk / D_MODEL, d = gkk - t * D_MODEL;
                int s = (gm & (SEQ - 1)) + t - 3;
                int bb = gm >> 11;
                u16x8 v = (s >= 0 && s < SEQ) ? *(const u16x8*)(Ab + ((size_t)(bb * SEQ + s)) * lda + d) : zv;
                *(u16x8*)&As_[(size_t)row * 64 + slot * 8] = v;
            } else {
                const ushort_t* src;
                if (SPLIT) {
                    int gk = k0 + (xs & 3) * 8;
                    src = ((xs < 4) ? Ab : Alb) + (size_t)gm * lda + gk;
                } else if (AMODE == 2) {
                    int gk = k0 + xs * 8;
                    src = (gk < D_MODEL) ? Ab + (size_t)gm * D_MODEL + gk
                                         : A2 + (size_t)gm * D_MODEL + (gk - D_MODEL);
                } else {
                    int gk = kb + k0 + xs * 8;
                    src = Ab + (size_t)gm * lda + gk;
                }
                gload16(src, &As_[(size_t)(i * 32 + wave * 8) * 64]);
            }
        }
        // ---- stage B ----
        #pragma unroll
        for (int i = 0; i < TN / 32; ++i) {
            int row = i * 32 + srow;
            int gn = n0 + row;
            int xs = slot ^ (row & 7);
            const ushort_t* src;
            if (SPLIT) {
                int gk = k0 + (xs & 3) * 8;
                src = ((xs < 4) ? Bb : Blb) + (size_t)gn * ldb + gk;
            } else {
                int gk = kb + k0 + xs * 8;
                src = Bb + (size_t)gn * ldb + gk;
            }
            gload16(src, &Bs_[(size_t)(i * 32 + wave * 8) * 64]);
        }
        __syncthreads();

        if (SPLIT) {
            bf16x8 ah[FM], alr[FM], bh[FN], blr[FN];
            #pragma unroll
            for (int mi = 0; mi < FM; ++mi) {
                int row = wm + mi * 16 + r16;
                int sh = (kq ^ (row & 7)) * 8;
                ah[mi]  = *(const bf16x8*)&As_[(size_t)row * 64 + sh];
                alr[mi] = *(const bf16x8*)&As_[(size_t)row * 64 + (sh ^ 32)];
            }
            #pragma unroll
            for (int ni = 0; ni < FN; ++ni) {
                int row = wn + ni * 16 + r16;
                int sh = (kq ^ (row & 7)) * 8;
                bh[ni]  = *(const bf16x8*)&Bs_[(size_t)row * 64 + sh];
                blr[ni] = *(const bf16x8*)&Bs_[(size_t)row * 64 + (sh ^ 32)];
            }
            #pragma unroll
            for (int mi = 0; mi < FM; ++mi)
                #pragma unroll
                for (int ni = 0; ni < FN; ++ni) {
                    acc[mi][ni] = __builtin_amdgcn_mfma_f32_16x16x32_bf16(ah[mi], bh[ni], acc[mi][ni], 0, 0, 0);
                    acc[mi][ni] = __builtin_amdgcn_mfma_f32_16x16x32_bf16(ah[mi], blr[ni], acc[mi][ni], 0, 0, 0);
                    acc[mi][ni] = __builtin_amdgcn_mfma_f32_16x16x32_bf16(alr[mi], bh[ni], acc[mi][ni], 0, 0, 0);
                }
        } else {
            bf16x8 ah[FM][2], bh[FN][2];
            #pragma unroll
            for (int mi = 0; mi < FM; ++mi) {
                int row = wm + mi * 16 + r16;
                #pragma unroll
                for (int kk = 0; kk < 2; ++kk)
                    ah[mi][kk] = *(const bf16x8*)&As_[(size_t)row * 64 + (((kk * 4 + kq) ^ (row & 7)) * 8)];
            }
            #pragma unroll
            for (int ni = 0; ni < FN; ++ni) {
                int row = wn + ni * 16 + r16;
                #pragma unroll
                for (int kk = 0; kk < 2; ++kk)
                    bh[ni][kk] = *(const bf16x8*)&Bs_[(size_t)row * 64 + (((kk * 4 + kq) ^ (row & 7)) * 8)];
            }
            #pragma unroll
            for (int kk = 0; kk < 2; ++kk)
                #pragma unroll
                for (int mi = 0; mi < FM; ++mi)
                    #pragma unroll
                    for (int ni = 0; ni < FN; ++ni)
                        acc[mi][ni] = __builtin_amdgcn_mfma_f32_16x16x32_bf16(ah[mi][kk], bh[ni][kk], acc[mi][ni], 0, 0, 0);
        }
        __syncthreads();
    }

    // epilogue: C/D layout col = lane&15, row = (lane>>4)*4 + r
    #pragma unroll
    for (int mi = 0; mi < FM; ++mi)
        #pragma unroll
        for (int ni = 0; ni < FN; ++ni)
            #pragma unroll
            for (int r = 0; r < 4; ++r) {
                int gm = m0 + wm + mi * 16 + kq * 4 + r;
                int gn = n0 + wn + ni * 16 + r16;
                if (gn >= N) continue;
                float v = acc[mi][ni][r];
                if (HASBIAS) v += bias[gn];
                if (ACT == 1) v = fmaxf(v, 0.f);
                else if (ACT == 2) v = fast_tanh(v);
                if (HASADD) v += bf2f(addsrc[(size_t)gm * ldc + gn]);
                size_t idx = (size_t)gm * ldc + gn;
                if (OUTMODE == 0) {
                    Cf[idx] = v;
                } else if (OUTMODE == 1) {
                    Cb[idx] = f2bf(v);
                } else {
                    ushort_t h = f2bf(v);
                    Cb[idx] = h;
                    Cl[idx] = f2bf(v - bf2f(h));
                }
            }
}

extern "C" void kernel_launch(void* const* d_in, const int* in_sizes, int n_in,
                              void* d_out, int out_size, void* d_ws, size_t ws_size,
                              hipStream_t stream) {
    const float* x1     = (const float*)d_in[0];
    const float* x2     = (const float*)d_in[1];
    const float* w7     = (const float*)d_in[2];
    const float* b7     = (const float*)d_in[3];
    const float* w5     = (const float*)d_in[4];
    const float* b5     = (const float*)d_in[5];
    const float* w3     = (const float*)d_in[6];
    const float* b3     = (const float*)d_in[7];
    const float* U      = (const float*)d_in[8];
    const float* bias_v = (const float*)d_in[9];
    const float* fc_w   = (const float*)d_in[10];
    const float* fc_b   = (const float*)d_in[11];
    const float* fcx_w  = (const float*)d_in[12];
    const float* fcx_b  = (const float*)d_in[13];
    float* out = (float*)d_out;

    const size_t MT = (size_t)BATCH * SEQ;      // 16384
    const size_t NE = MT * D_MODEL;             // 12.58M
    const size_t NEb = (size_t)SEQ * D_MODEL;   // 1.57M
    const size_t SEGSZ = (size_t)SEQ * SEQ;     // 4.19M elems (one attnb batch)

    char* p = (char*)d_ws;
    auto alloc = [&](size_t bytes) -> char* {
        char* r = p;
        p += (bytes + 255) & ~(size_t)255;
        return r;
    };
    ushort_t* x1_hi  = (ushort_t*)alloc(NE * 2);
    ushort_t* x1_lo  = (ushort_t*)alloc(NE * 2);   // dead after xU -> attnb b0..b2
    ushort_t* x2_hi  = (ushort_t*)alloc(NE * 2);   // [0:seg] dead after chunk1 -> attnb b5
    ushort_t* x2_lo  = (ushort_t*)alloc(NE * 2);   // [0:seg] dead after chunk2 -> attnb b6
    ushort_t* x2t    = (ushort_t*)alloc(NE * 2);
    ushort_t* y1_hi  = (ushort_t*)alloc(NE * 2);   // conv partials first; attnb b3,b7 later
    ushort_t* y1_lo  = (ushort_t*)alloc(NE * 2);   // attnb b4
    ushort_t* xcnn   = (ushort_t*)alloc(NE * 2);
    ushort_t* feats  = (ushort_t*)alloc(MT * FC_PAD2 * 2);
    ushort_t* Wt     = (ushort_t*)alloc((size_t)FC_PAD2 * KCOMB * 2);
    ushort_t* fc_wt  = (ushort_t*)alloc((size_t)D_MODEL * FC_PAD2 * 2);
    ushort_t* fcx_wt = (ushort_t*)alloc((size_t)D_MODEL * 2 * D_MODEL * 2);
    ushort_t* Ut_hi  = (ushort_t*)alloc((size_t)D_MODEL * D_MODEL * 2);
    ushort_t* Ut_lo  = (ushort_t*)alloc((size_t)D_MODEL * D_MODEL * 2);
    float*    bcat   = (float*)alloc(FC_PAD2 * 4);
    float*    rbias  = (float*)alloc(MT * 4);

    float*    attnf = (float*)d_out;               // fp32 scores, <=3 batches (50.3MB = d_out)
    float*    convp = (float*)y1_hi;               // 4 partials [MT][96] fp32 = 25.17MB (= y1_hi)

    // attnb segment pointers (each SEQ*SEQ bf16 = 8.39MB), placed in dead regions
    Ptr8w apw;
    apw.p[0] = x1_lo;
    apw.p[1] = x1_lo + SEGSZ;
    apw.p[2] = x1_lo + 2 * SEGSZ;                  // x1_lo = 3*SEGSZ exactly
    apw.p[3] = y1_hi;
    apw.p[4] = y1_lo;
    apw.p[5] = x2_hi;
    apw.p[6] = x2_lo;
    apw.p[7] = y1_hi + SEGSZ;
    Ptr8 ap;
    for (int i = 0; i < 8; ++i) ap.p[i] = apw.p[i];
    Ptr8 apz = {};

    const int T = 256;
    auto blk = [](size_t n) { return dim3((unsigned)((n + 255) / 256)); };

    // ---- prep ----
    build_wcomb_kernel<<<blk((size_t)FC_PAD2 * KCOMB), T, 0, stream>>>(w7, b7, w5, b5, w3, b3, Wt, bcat);
    convert_fc_kernel<<<blk((size_t)D_MODEL * FC_PAD2), T, 0, stream>>>(fc_w, fc_wt);
    convert_fcx_kernel<<<blk((size_t)D_MODEL * 2 * D_MODEL / 4), T, 0, stream>>>(fcx_w, fcx_wt, (size_t)D_MODEL * 2 * D_MODEL / 4);
    split_ut_kernel<<<blk((size_t)D_MODEL * D_MODEL), T, 0, stream>>>(U, Ut_hi, Ut_lo);
    split_f32_kernel<<<blk(NE / 4), T, 0, stream>>>(x1, x1_hi, x1_lo, NE / 4);
    split_f32_kernel<<<blk(NE / 4), T, 0, stream>>>(x2, x2_hi, x2_lo, NE / 4);
    transpose_bf16_kernel<<<dim3(SEQ / 32, D_MODEL / 32, BATCH), T, 0, stream>>>(x2_hi, x2t);
    rowbias_kernel<<<dim3((unsigned)MT), T, 0, stream>>>(x2, bias_v, rbias);

    // ---- conv: 4 K-chunks -> fp32 partials (in y1_hi region) ----
    mfma_gemm<64, 128, 1, 0, 0, 0, 0, 0, 1, 0><<<dim3(MT / 64, 1, 4), T, 0, stream>>>(
        x2_hi, nullptr, nullptr, Wt, nullptr, nullptr, nullptr,
        convp, nullptr, nullptr, apz,
        (int)MT, FC_PAD, KCHUNK, D_MODEL, KCOMB, FC_PAD,
        0, 0, 0, MT * FC_PAD);
    conv_reduce_kernel<<<blk(MT * FC_PAD2), T, 0, stream>>>(convp, bcat, feats);

    // ---- fc: xcnn = tanh(feats @ fc_w^T + fc_b), K padded to 128 ----
    mfma_gemm<128, 128, 0, 0, 2, 1, 0, 1, 0, 0><<<dim3(MT / 128, D_MODEL / 128, 1), T, 0, stream>>>(
        feats, nullptr, nullptr, fc_wt, nullptr, fc_b, nullptr,
        nullptr, xcnn, nullptr, apz,
        (int)MT, D_MODEL, FC_PAD2, FC_PAD2, FC_PAD2, D_MODEL, 0, 0, 0, 0);

    // ---- y1 = x1 @ U (split), split bf16 out ----
    mfma_gemm<128, 128, 0, 1, 0, 0, 0, 2, 0, 0><<<dim3(MT / 128, D_MODEL / 128, 1), T, 0, stream>>>(
        x1_hi, nullptr, x1_lo, Ut_hi, Ut_lo, nullptr, nullptr,
        nullptr, y1_hi, y1_lo, apz,
        (int)MT, D_MODEL, D_MODEL, D_MODEL, D_MODEL, D_MODEL, 0, 0, 0, 0);

    // ---- attention: scores+softmax in chunks {3,3,2}, then one 8-batch PV ----
    const int b0s[3] = {0, 3, 6};
    const int nbs[3] = {3, 3, 2};
    for (int c = 0; c < 3; ++c) {
        const int b0 = b0s[c], nb = nbs[c];
        const size_t off = (size_t)b0 * NEb;

        mfma_gemm<128, 128, 0, 1, 0, 1, 0, 0, 0, 0><<<dim3(SEQ / 128, SEQ / 128, nb), T, 0, stream>>>(
            y1_hi + off, nullptr, y1_lo + off, x2_hi + off, x2_lo + off,
            rbias + (size_t)b0 * SEQ, nullptr,
            attnf, nullptr, nullptr, apz,
            SEQ, SEQ, D_MODEL, D_MODEL, D_MODEL, SEQ,
            NEb, NEb, SEQ, SEGSZ);

        softmax_kernel<<<dim3((unsigned)(nb * SEQ)), T, 0, stream>>>(attnf, apw, b0);
    }

    // PV: x = xcnn + tanh(attn @ x2), all 8 batches, A via pointer table
    mfma_gemm<128, 128, 0, 0, 2, 0, 1, 1, 0, 1><<<dim3(SEQ / 128, D_MODEL / 128, BATCH), T, 0, stream>>>(
        nullptr, nullptr, nullptr, x2t, nullptr, nullptr,
        xcnn,
        nullptr, xcnn, nullptr, ap,
        SEQ, D_MODEL, SEQ, SEQ, SEQ, D_MODEL,
        0, NEb, 0, NEb);

    // ---- final: out = concat(x1, x) @ fcx_w^T + fcx_b ----
    mfma_gemm<128, 128, 2, 0, 0, 1, 0, 0, 0, 0><<<dim3(MT / 128, D_MODEL / 128, 1), T, 0, stream>>>(
        x1_hi, xcnn, nullptr, fcx_wt, nullptr, fcx_b, nullptr,
        out, nullptr, nullptr, apz,
        (int)MT, D_MODEL, 2 * D_MODEL, D_MODEL, 2 * D_MODEL, D_MODEL, 0, 0, 0, 0);
}

// Round 5
// 432.674 us; speedup vs baseline: 14.0426x; 1.2462x over previous
//
#include <hip/hip_runtime.h>
#include <cmath>

#define D_MODEL 768
#define SEQ 2048
#define BATCH 8
#define FC_PAD 96
#define FC_PAD2 128
#define KCOMB (7 * D_MODEL)   // 5376
#define KCHUNK 1344           // KCOMB/4

typedef unsigned short ushort_t;
typedef _Float16 half_t;
typedef __attribute__((ext_vector_type(8))) _Float16 f16x8;
typedef __attribute__((ext_vector_type(8))) unsigned short u16x8;
typedef __attribute__((ext_vector_type(4))) unsigned short u16x4;
typedef __attribute__((ext_vector_type(4))) float f32x4;

struct Ptr8  { const ushort_t* p[8]; };
struct Ptr8w { ushort_t* p[8]; };

__device__ __forceinline__ ushort_t f2h(float x) {
    half_t h = (half_t)x;
    return __builtin_bit_cast(ushort_t, h);
}
__device__ __forceinline__ float h2f(ushort_t u) {
    return (float)__builtin_bit_cast(half_t, u);
}
__device__ __forceinline__ float fast_tanh(float x) {
    float a = fabsf(x);
    float t = __expf(-2.f * a);
    float r = (1.f - t) / (1.f + t);
    return copysignf(r, x);
}
__device__ __forceinline__ void gload16(const ushort_t* g, ushort_t* lbase) {
    __builtin_amdgcn_global_load_lds((const __attribute__((address_space(1))) void*)g,
                                     (__attribute__((address_space(3))) void*)lbase,
                                     16, 0, 0);
}
// bijective XCD-aware remap of (bx,by) within a z-slice (m204 formula)
__device__ __forceinline__ void xcd_swizzle(int gx, int gy, int& bx, int& by) {
    int nwg = gx * gy;
    int lin = by * gx + bx;
    int q = nwg >> 3, r = nwg & 7;
    int xcd = lin & 7, off = lin >> 3;
    int lin2 = (xcd < r) ? (xcd * (q + 1) + off) : (r * (q + 1) + (xcd - r) * q + off);
    bx = lin2 % gx;
    by = lin2 / gx;
}

// ---------------- prep kernels ----------------
__global__ void convert_f16_kernel(const float* __restrict__ src, ushort_t* __restrict__ dst, size_t n4) {
    size_t i = (size_t)blockIdx.x * 256 + threadIdx.x;
    if (i >= n4) return;
    f32x4 x = *(const f32x4*)(src + i * 4);
    u16x4 h;
    #pragma unroll
    for (int j = 0; j < 4; ++j) h[j] = f2h(x[j]);
    *(u16x4*)(dst + i * 4) = h;
}

// fc_w [768][90] -> fc_wt fp16 [768][128] zero-padded
__global__ void convert_fc_kernel(const float* __restrict__ src, ushort_t* __restrict__ dst) {
    int i = blockIdx.x * 256 + threadIdx.x;
    if (i >= D_MODEL * FC_PAD2) return;
    int o = i / FC_PAD2, j = i - o * FC_PAD2;
    dst[i] = (j < 90) ? f2h(src[o * 90 + j]) : 0;
}

// U [768][768] -> Ut [n][k] = fp16(U[k][n])
__global__ void convert_ut_kernel(const float* __restrict__ U, ushort_t* __restrict__ dst) {
    int i = blockIdx.x * 256 + threadIdx.x;
    if (i >= D_MODEL * D_MODEL) return;
    int n = i / D_MODEL, k = i - n * D_MODEL;
    dst[i] = f2h(U[(size_t)k * D_MODEL + n]);
}

// combined conv weight, fp16, [128][5376]; rows 90..127 zero
__global__ void build_wcomb_kernel(const float* __restrict__ w7, const float* __restrict__ b7,
                                   const float* __restrict__ w5, const float* __restrict__ b5,
                                   const float* __restrict__ w3, const float* __restrict__ b3,
                                   ushort_t* __restrict__ Wt, float* __restrict__ bcat) {
    int idx = blockIdx.x * 256 + threadIdx.x;
    const int total = FC_PAD2 * KCOMB;
    if (idx < total) {
        int o = idx / KCOMB, k = idx - o * KCOMB;
        int t = k / D_MODEL, d = k - t * D_MODEL;
        float v = 0.f;
        if (o < 40) {
            v = w7[(size_t)o * (D_MODEL * 7) + d * 7 + t];
        } else if (o < 70) {
            int t5 = t - 1;
            if (t5 >= 0 && t5 < 5) v = w5[(size_t)(o - 40) * (D_MODEL * 5) + d * 5 + t5];
        } else if (o < 90) {
            int t3 = t - 2;
            if (t3 >= 0 && t3 < 3) v = w3[(size_t)(o - 70) * (D_MODEL * 3) + d * 3 + t3];
        }
        Wt[idx] = f2h(v);
    }
    if (idx < FC_PAD2) {
        float bv = 0.f;
        if (idx < 40) bv = b7[idx];
        else if (idx < 70) bv = b5[idx - 40];
        else if (idx < 90) bv = b3[idx - 70];
        bcat[idx] = bv;
    }
}

// sum 4 conv partials + bias + relu -> feats fp16 [16384][128] (cols 96.. zero)
__global__ void conv_reduce_kernel(const float* __restrict__ P, const float* __restrict__ bcat,
                                   ushort_t* __restrict__ feats) {
    const size_t MT = (size_t)BATCH * SEQ;
    size_t i = (size_t)blockIdx.x * 256 + threadIdx.x;
    if (i >= MT * FC_PAD2) return;
    int col = (int)(i & (FC_PAD2 - 1));
    size_t row = i >> 7;
    float v = 0.f;
    if (col < FC_PAD) {
        size_t idx = row * FC_PAD + col;
        const size_t st = MT * FC_PAD;
        v = P[idx] + P[idx + st] + P[idx + 2 * st] + P[idx + 3 * st] + bcat[col];
        v = fmaxf(v, 0.f);
    }
    feats[i] = f2h(v);
}

// x2_h [8][2048][768] -> x2t [8][768][2048]
__global__ void transpose_f16_kernel(const ushort_t* __restrict__ in, ushort_t* __restrict__ out) {
    __shared__ ushort_t tile[32][40];
    int b = blockIdx.z;
    int s0 = blockIdx.x * 32, d0 = blockIdx.y * 32;
    int tx = threadIdx.x & 31, ty = threadIdx.x >> 5;   // 32 x 8
    const ushort_t* inb = in + (size_t)b * SEQ * D_MODEL;
    ushort_t* outb = out + (size_t)b * D_MODEL * SEQ;
    #pragma unroll
    for (int i = 0; i < 4; ++i)
        tile[ty + i * 8][tx] = inb[(size_t)(s0 + ty + i * 8) * D_MODEL + d0 + tx];
    __syncthreads();
    #pragma unroll
    for (int i = 0; i < 4; ++i)
        outb[(size_t)(d0 + ty + i * 8) * SEQ + s0 + tx] = tile[tx][ty + i * 8];
}

// rowbias[b,t] = x2[b,t,:] . bias_v   (fp32)
__global__ void rowbias_kernel(const float* __restrict__ x2, const float* __restrict__ bias_v,
                               float* __restrict__ rowbias) {
    int row = blockIdx.x;
    const float* xr = x2 + (size_t)row * D_MODEL;
    float s = 0.f;
    for (int c = threadIdx.x; c < D_MODEL; c += 256) s += xr[c] * bias_v[c];
    for (int off = 32; off > 0; off >>= 1) s += __shfl_down(s, off);
    __shared__ float red[4];
    int lane = threadIdx.x & 63, w = threadIdx.x >> 6;
    if (lane == 0) red[w] = s;
    __syncthreads();
    if (threadIdx.x == 0) rowbias[row] = red[0] + red[1] + red[2] + red[3];
}

// row softmax: fp32 in [2048], fp16 out via per-batch pointer table
__global__ void softmax_kernel(const float* __restrict__ in, Ptr8w ptrs, int b0) {
    __shared__ float ls[SEQ];
    __shared__ float red[4];
    __shared__ float bc;
    int row = blockIdx.x;
    const float* p = in + (size_t)row * SEQ;
    ushort_t* q = ptrs.p[b0 + (row >> 11)] + (size_t)(row & (SEQ - 1)) * SEQ;
    int lane = threadIdx.x & 63, w = threadIdx.x >> 6;

    float mx = -1e30f;
    for (int c = threadIdx.x; c < SEQ; c += 256) { float v = p[c]; ls[c] = v; mx = fmaxf(mx, v); }
    for (int off = 32; off > 0; off >>= 1) mx = fmaxf(mx, __shfl_down(mx, off));
    if (lane == 0) red[w] = mx;
    __syncthreads();
    if (threadIdx.x == 0) bc = fmaxf(fmaxf(red[0], red[1]), fmaxf(red[2], red[3]));
    __syncthreads();
    mx = bc;
    float s = 0.f;
    for (int c = threadIdx.x; c < SEQ; c += 256) { float e = __expf(ls[c] - mx); ls[c] = e; s += e; }
    for (int off = 32; off > 0; off >>= 1) s += __shfl_down(s, off);
    if (lane == 0) red[w] = s;
    __syncthreads();
    if (threadIdx.x == 0) bc = 1.f / (red[0] + red[1] + red[2] + red[3]);
    __syncthreads();
    float inv = bc;
    for (int c = threadIdx.x; c < SEQ; c += 256) q[c] = f2h(ls[c] * inv);
}

// ---------------- fp16 MFMA GEMM, BK=64, 128B LDS rows + XOR slot swizzle ----------------
// C[M,N] = epilogue( A' @ B'^T ); A' [M][K] fp16, B' [N][K] fp16 (N-major).
// LDS rows: 64 elems (8 x 16B slots), slot ^= (row&7) folded into the GLOBAL source
// address (linear global_load_lds dest, swizzled read — rule #21).
// AMODE: 0 plain, 1 im2col(x2_h, VGPR-staged), 2 concat(A|A2, stride 768)
// KSPLIT: blockIdx.z = K-chunk (kbase = z*K), C offset z*sC. APTR: A base = ap.p[z].
// OUTMODE: 0 fp32->Cf, 1 fp16->Ch
template<int TM, int TN, int AMODE, int ACT, int HASBIAS, int HASADD,
         int OUTMODE, int KSPLIT, int APTR>
__global__ __launch_bounds__(256, 3)
void mfma_gemm(const ushort_t* __restrict__ A, const ushort_t* __restrict__ A2,
               const ushort_t* __restrict__ B, const float* __restrict__ bias,
               const ushort_t* __restrict__ addsrc,
               float* __restrict__ Cf, ushort_t* __restrict__ Ch,
               Ptr8 ap,
               int M, int N, int K, int lda, int ldb, int ldc,
               size_t sA, size_t sB, size_t sBias, size_t sC) {
    constexpr int WM = TM / 2, WN = TN / 2, FM = WM / 16, FN = WN / 16;
    __shared__ __align__(16) ushort_t As_[TM * 64];
    __shared__ __align__(16) ushort_t Bs_[TN * 64];

    const int z = blockIdx.z;
    const int kb = KSPLIT ? z * K : 0;
    const ushort_t* Ab = APTR ? ap.p[z] : (A + (KSPLIT ? 0 : (size_t)z * sA));
    const ushort_t* Bb = B + (KSPLIT ? 0 : (size_t)z * sB);
    if (HASBIAS) bias += (size_t)z * sBias;
    if (HASADD) addsrc += (size_t)z * sC;
    if (OUTMODE == 0) Cf += (size_t)z * sC;
    else Ch += (size_t)z * sC;

    int bx = blockIdx.x, by = blockIdx.y;
    xcd_swizzle(gridDim.x, gridDim.y, bx, by);
    const int m0 = bx * TM;
    const int n0 = by * TN;
    const int tid = threadIdx.x;
    const int lane = tid & 63;
    const int wave = tid >> 6;
    const int wm = (wave >> 1) * WM, wn = (wave & 1) * WN;
    const int r16 = lane & 15, kq = lane >> 4;
    const int srow = tid >> 3;          // 0..31
    const int slot = tid & 7;           // 16B slot (LDS-linear)

    f32x4 acc[FM][FN];
    #pragma unroll
    for (int i = 0; i < FM; ++i)
        #pragma unroll
        for (int j = 0; j < FN; ++j) acc[i][j] = (f32x4){0.f, 0.f, 0.f, 0.f};

    const u16x8 zv = {0, 0, 0, 0, 0, 0, 0, 0};

    for (int k0 = 0; k0 < K; k0 += 64) {
        // ---- stage A ----
        #pragma unroll
        for (int i = 0; i < TM / 32; ++i) {
            int row = i * 32 + srow;
            int gm = m0 + row;
            int xs = slot ^ (row & 7);
            if (AMODE == 1) {
                int gkk = kb + k0 + xs * 8;
                int t = gkk / D_MODEL, d = gkk - t * D_MODEL;
                int s = (gm & (SEQ - 1)) + t - 3;
                int bb = gm >> 11;
                u16x8 v = (s >= 0 && s < SEQ) ? *(const u16x8*)(Ab + ((size_t)(bb * SEQ + s)) * lda + d) : zv;
                *(u16x8*)&As_[(size_t)row * 64 + slot * 8] = v;
            } else {
                const ushort_t* src;
                if (AMODE == 2) {
                    int gk = k0 + xs * 8;
                    src = (gk < D_MODEL) ? Ab + (size_t)gm * D_MODEL + gk
                                         : A2 + (size_t)gm * D_MODEL + (gk - D_MODEL);
                } else {
                    int gk = kb + k0 + xs * 8;
                    src = Ab + (size_t)gm * lda + gk;
                }
                gload16(src, &As_[(size_t)(i * 32 + wave * 8) * 64]);
            }
        }
        // ---- stage B ----
        #pragma unroll
        for (int i = 0; i < TN / 32; ++i) {
            int row = i * 32 + srow;
            int gn = n0 + row;
            int xs = slot ^ (row & 7);
            int gk = kb + k0 + xs * 8;
            gload16(Bb + (size_t)gn * ldb + gk, &Bs_[(size_t)(i * 32 + wave * 8) * 64]);
        }
        __syncthreads();

        f16x8 ah[FM][2], bh[FN][2];
        #pragma unroll
        for (int mi = 0; mi < FM; ++mi) {
            int row = wm + mi * 16 + r16;
            #pragma unroll
            for (int kk = 0; kk < 2; ++kk)
                ah[mi][kk] = *(const f16x8*)&As_[(size_t)row * 64 + (((kk * 4 + kq) ^ (row & 7)) * 8)];
        }
        #pragma unroll
        for (int ni = 0; ni < FN; ++ni) {
            int row = wn + ni * 16 + r16;
            #pragma unroll
            for (int kk = 0; kk < 2; ++kk)
                bh[ni][kk] = *(const f16x8*)&Bs_[(size_t)row * 64 + (((kk * 4 + kq) ^ (row & 7)) * 8)];
        }
        #pragma unroll
        for (int kk = 0; kk < 2; ++kk)
            #pragma unroll
            for (int mi = 0; mi < FM; ++mi)
                #pragma unroll
                for (int ni = 0; ni < FN; ++ni)
                    acc[mi][ni] = __builtin_amdgcn_mfma_f32_16x16x32_f16(ah[mi][kk], bh[ni][kk], acc[mi][ni], 0, 0, 0);
        __syncthreads();
    }

    // epilogue: C/D layout col = lane&15, row = (lane>>4)*4 + r
    #pragma unroll
    for (int mi = 0; mi < FM; ++mi)
        #pragma unroll
        for (int ni = 0; ni < FN; ++ni)
            #pragma unroll
            for (int r = 0; r < 4; ++r) {
                int gm = m0 + wm + mi * 16 + kq * 4 + r;
                int gn = n0 + wn + ni * 16 + r16;
                if (gn >= N) continue;
                float v = acc[mi][ni][r];
                if (HASBIAS) v += bias[gn];
                if (ACT == 1) v = fmaxf(v, 0.f);
                else if (ACT == 2) v = fast_tanh(v);
                if (HASADD) v += h2f(addsrc[(size_t)gm * ldc + gn]);
                size_t idx = (size_t)gm * ldc + gn;
                if (OUTMODE == 0) Cf[idx] = v;
                else Ch[idx] = f2h(v);
            }
}

extern "C" void kernel_launch(void* const* d_in, const int* in_sizes, int n_in,
                              void* d_out, int out_size, void* d_ws, size_t ws_size,
                              hipStream_t stream) {
    const float* x1     = (const float*)d_in[0];
    const float* x2     = (const float*)d_in[1];
    const float* w7     = (const float*)d_in[2];
    const float* b7     = (const float*)d_in[3];
    const float* w5     = (const float*)d_in[4];
    const float* b5     = (const float*)d_in[5];
    const float* w3     = (const float*)d_in[6];
    const float* b3     = (const float*)d_in[7];
    const float* U      = (const float*)d_in[8];
    const float* bias_v = (const float*)d_in[9];
    const float* fc_w   = (const float*)d_in[10];
    const float* fc_b   = (const float*)d_in[11];
    const float* fcx_w  = (const float*)d_in[12];
    const float* fcx_b  = (const float*)d_in[13];
    float* out = (float*)d_out;

    const size_t MT = (size_t)BATCH * SEQ;      // 16384
    const size_t NE = MT * D_MODEL;             // 12.58M
    const size_t NEb = (size_t)SEQ * D_MODEL;   // 1.57M
    const size_t SEGSZ = (size_t)SEQ * SEQ;     // 4.19M elems (one attnb batch)

    char* p = (char*)d_ws;
    auto alloc = [&](size_t bytes) -> char* {
        char* r = p;
        p += (bytes + 255) & ~(size_t)255;
        return r;
    };
    ushort_t* x1_h   = (ushort_t*)alloc(NE * 2);   // live to the end (final concat)
    ushort_t* x2_h   = (ushort_t*)alloc(NE * 2);   // dead per-batch after its scores chunk
    ushort_t* x2t    = (ushort_t*)alloc(NE * 2);   // live until PV
    ushort_t* y1     = (ushort_t*)alloc(NE * 2);   // dead per-batch after its scores chunk
    ushort_t* xcnn   = (ushort_t*)alloc(NE * 2);   // live to the end
    float*    convp  = (float*)   alloc(MT * FC_PAD * 4 * 4); // 4 partials; dead after reduce
    ushort_t* feats  = (ushort_t*)alloc(MT * FC_PAD2 * 2);
    ushort_t* Wt     = (ushort_t*)alloc((size_t)FC_PAD2 * KCOMB * 2);
    ushort_t* fc_wt  = (ushort_t*)alloc((size_t)D_MODEL * FC_PAD2 * 2);
    ushort_t* fcx_wt = (ushort_t*)alloc((size_t)D_MODEL * 2 * D_MODEL * 2);
    ushort_t* Ut     = (ushort_t*)alloc((size_t)D_MODEL * D_MODEL * 2);
    float*    bcat   = (float*)alloc(FC_PAD2 * 4);
    float*    rbias  = (float*)alloc(MT * 4);

    float* attnf = (float*)d_out;   // fp32 scores, 3 segments = 50.33MB = exactly d_out

    // attnb segments (each SEQ*SEQ fp16 = 8.39MB) in dead regions:
    //  b0-b2: convp (dead after conv_reduce; holds exactly 3 segments)
    //  b3,b4: y1 batches 0..5 region (dead after chunks 0/1)
    //  b5-b7: x2_h batches 0..5 region (dead after chunks 0/1)
    Ptr8w apw;
    apw.p[0] = (ushort_t*)convp;
    apw.p[1] = (ushort_t*)convp + SEGSZ;
    apw.p[2] = (ushort_t*)convp + 2 * SEGSZ;
    apw.p[3] = y1;                       // [0, 4.19M) ⊂ y1 b0-2 (dead after chunk0)
    apw.p[4] = y1 + SEGSZ;               // [4.19M, 8.39M) ⊂ y1 b0-5 (dead after chunk1)
    apw.p[5] = x2_h;                     // [0, 4.19M) ⊂ x2_h b0-2 (dead after chunk0)
    apw.p[6] = x2_h + SEGSZ;             // written after chunk2; x2_h b0-5 dead
    apw.p[7] = x2_h + 2 * SEGSZ;         // written after chunk2's scores completes
    Ptr8 ap;
    for (int i = 0; i < 8; ++i) ap.p[i] = apw.p[i];
    Ptr8 apz = {};

    const int T = 256;
    auto blk = [](size_t n) { return dim3((unsigned)((n + 255) / 256)); };

    // ---- prep ----
    build_wcomb_kernel<<<blk((size_t)FC_PAD2 * KCOMB), T, 0, stream>>>(w7, b7, w5, b5, w3, b3, Wt, bcat);
    convert_fc_kernel<<<blk((size_t)D_MODEL * FC_PAD2), T, 0, stream>>>(fc_w, fc_wt);
    convert_f16_kernel<<<blk((size_t)D_MODEL * 2 * D_MODEL / 4), T, 0, stream>>>(fcx_w, fcx_wt, (size_t)D_MODEL * 2 * D_MODEL / 4);
    convert_ut_kernel<<<blk((size_t)D_MODEL * D_MODEL), T, 0, stream>>>(U, Ut);
    convert_f16_kernel<<<blk(NE / 4), T, 0, stream>>>(x1, x1_h, NE / 4);
    convert_f16_kernel<<<blk(NE / 4), T, 0, stream>>>(x2, x2_h, NE / 4);
    transpose_f16_kernel<<<dim3(SEQ / 32, D_MODEL / 32, BATCH), T, 0, stream>>>(x2_h, x2t);
    rowbias_kernel<<<dim3((unsigned)MT), T, 0, stream>>>(x2, bias_v, rbias);

    // ---- conv: 4 K-chunks -> fp32 partials, then reduce+bias+relu -> feats ----
    mfma_gemm<64, 128, 1, 0, 0, 0, 0, 1, 0><<<dim3(MT / 64, 1, 4), T, 0, stream>>>(
        x2_h, nullptr, Wt, nullptr, nullptr,
        convp, nullptr, apz,
        (int)MT, FC_PAD, KCHUNK, D_MODEL, KCOMB, FC_PAD,
        0, 0, 0, MT * FC_PAD);
    conv_reduce_kernel<<<blk(MT * FC_PAD2), T, 0, stream>>>(convp, bcat, feats);

    // ---- fc: xcnn = tanh(feats @ fc_w^T + fc_b), K padded to 128 ----
    mfma_gemm<128, 128, 0, 2, 1, 0, 1, 0, 0><<<dim3(MT / 128, D_MODEL / 128, 1), T, 0, stream>>>(
        feats, nullptr, fc_wt, fc_b, nullptr,
        nullptr, xcnn, apz,
        (int)MT, D_MODEL, FC_PAD2, FC_PAD2, FC_PAD2, D_MODEL, 0, 0, 0, 0);

    // ---- y1 = x1 @ U, fp16 out ----
    mfma_gemm<128, 128, 0, 0, 0, 0, 1, 0, 0><<<dim3(MT / 128, D_MODEL / 128, 1), T, 0, stream>>>(
        x1_h, nullptr, Ut, nullptr, nullptr,
        nullptr, y1, apz,
        (int)MT, D_MODEL, D_MODEL, D_MODEL, D_MODEL, D_MODEL, 0, 0, 0, 0);

    // ---- attention: scores+softmax in chunks {3,3,2}, then one 8-batch PV ----
    const int b0s[3] = {0, 3, 6};
    const int nbs[3] = {3, 3, 2};
    for (int c = 0; c < 3; ++c) {
        const int b0 = b0s[c], nb = nbs[c];
        const size_t off = (size_t)b0 * NEb;

        mfma_gemm<128, 128, 0, 0, 1, 0, 0, 0, 0><<<dim3(SEQ / 128, SEQ / 128, nb), T, 0, stream>>>(
            y1 + off, nullptr, x2_h + off,
            rbias + (size_t)b0 * SEQ, nullptr,
            attnf, nullptr, apz,
            SEQ, SEQ, D_MODEL, D_MODEL, D_MODEL, SEQ,
            NEb, NEb, SEQ, SEGSZ);

        softmax_kernel<<<dim3((unsigned)(nb * SEQ)), T, 0, stream>>>(attnf, apw, b0);
    }

    // PV: x = xcnn + tanh(attn @ x2), all 8 batches, A via pointer table
    mfma_gemm<128, 128, 0, 2, 0, 1, 1, 0, 1><<<dim3(SEQ / 128, D_MODEL / 128, BATCH), T, 0, stream>>>(
        nullptr, nullptr, x2t, nullptr,
        xcnn,
        nullptr, xcnn, ap,
        SEQ, D_MODEL, SEQ, SEQ, SEQ, D_MODEL,
        0, NEb, 0, NEb);

    // ---- final: out = concat(x1, x) @ fcx_w^T + fcx_b ----
    mfma_gemm<128, 128, 2, 0, 1, 0, 0, 0, 0><<<dim3(MT / 128, D_MODEL / 128, 1), T, 0, stream>>>(
        x1_h, xcnn, fcx_wt, fcx_b, nullptr,
        out, nullptr, apz,
        (int)MT, D_MODEL, 2 * D_MODEL, D_MODEL, 2 * D_MODEL, D_MODEL, 0, 0, 0, 0);
}

// Round 6
// 401.324 us; speedup vs baseline: 15.1396x; 1.0781x over previous
//
#include <hip/hip_runtime.h>
#include <cmath>

#define D_MODEL 768
#define SEQ 2048
#define BATCH 8
#define FC_PAD 96
#define FC_PAD2 128
#define KCOMB (7 * D_MODEL)   // 5376
#define KCHUNK 1344           // KCOMB/4

typedef unsigned short ushort_t;
typedef _Float16 half_t;
typedef __attribute__((ext_vector_type(8))) _Float16 f16x8;
typedef __attribute__((ext_vector_type(8))) unsigned short u16x8;
typedef __attribute__((ext_vector_type(4))) unsigned short u16x4;
typedef __attribute__((ext_vector_type(4))) float f32x4;

struct Ptr8  { const ushort_t* p[8]; };
struct Ptr8w { ushort_t* p[8]; };

__device__ __forceinline__ ushort_t f2h(float x) {
    half_t h = (half_t)x;
    return __builtin_bit_cast(ushort_t, h);
}
__device__ __forceinline__ float h2f(ushort_t u) {
    return (float)__builtin_bit_cast(half_t, u);
}
__device__ __forceinline__ float fast_tanh(float x) {
    float a = fabsf(x);
    float t = __expf(-2.f * a);
    float r = (1.f - t) / (1.f + t);
    return copysignf(r, x);
}
__device__ __forceinline__ void gload16(const ushort_t* g, ushort_t* lbase) {
    __builtin_amdgcn_global_load_lds((const __attribute__((address_space(1))) void*)g,
                                     (__attribute__((address_space(3))) void*)lbase,
                                     16, 0, 0);
}

// ---------------- prep kernels ----------------
__global__ void convert_f16_kernel(const float* __restrict__ src, ushort_t* __restrict__ dst, size_t n4) {
    size_t i = (size_t)blockIdx.x * 256 + threadIdx.x;
    if (i >= n4) return;
    f32x4 x = *(const f32x4*)(src + i * 4);
    u16x4 h;
    #pragma unroll
    for (int j = 0; j < 4; ++j) h[j] = f2h(x[j]);
    *(u16x4*)(dst + i * 4) = h;
}

// fc_w [768][90] -> fc_wt fp16 [768][128] zero-padded
__global__ void convert_fc_kernel(const float* __restrict__ src, ushort_t* __restrict__ dst) {
    int i = blockIdx.x * 256 + threadIdx.x;
    if (i >= D_MODEL * FC_PAD2) return;
    int o = i / FC_PAD2, j = i - o * FC_PAD2;
    dst[i] = (j < 90) ? f2h(src[o * 90 + j]) : 0;
}

// U [768][768] -> Ut [n][k] = fp16(U[k][n])
__global__ void convert_ut_kernel(const float* __restrict__ U, ushort_t* __restrict__ dst) {
    int i = blockIdx.x * 256 + threadIdx.x;
    if (i >= D_MODEL * D_MODEL) return;
    int n = i / D_MODEL, k = i - n * D_MODEL;
    dst[i] = f2h(U[(size_t)k * D_MODEL + n]);
}

// combined conv weight, fp16, [128][5376]; rows 90..127 zero
__global__ void build_wcomb_kernel(const float* __restrict__ w7, const float* __restrict__ b7,
                                   const float* __restrict__ w5, const float* __restrict__ b5,
                                   const float* __restrict__ w3, const float* __restrict__ b3,
                                   ushort_t* __restrict__ Wt, float* __restrict__ bcat) {
    int idx = blockIdx.x * 256 + threadIdx.x;
    const int total = FC_PAD2 * KCOMB;
    if (idx < total) {
        int o = idx / KCOMB, k = idx - o * KCOMB;
        int t = k / D_MODEL, d = k - t * D_MODEL;
        float v = 0.f;
        if (o < 40) {
            v = w7[(size_t)o * (D_MODEL * 7) + d * 7 + t];
        } else if (o < 70) {
            int t5 = t - 1;
            if (t5 >= 0 && t5 < 5) v = w5[(size_t)(o - 40) * (D_MODEL * 5) + d * 5 + t5];
        } else if (o < 90) {
            int t3 = t - 2;
            if (t3 >= 0 && t3 < 3) v = w3[(size_t)(o - 70) * (D_MODEL * 3) + d * 3 + t3];
        }
        Wt[idx] = f2h(v);
    }
    if (idx < FC_PAD2) {
        float bv = 0.f;
        if (idx < 40) bv = b7[idx];
        else if (idx < 70) bv = b5[idx - 40];
        else if (idx < 90) bv = b3[idx - 70];
        bcat[idx] = bv;
    }
}

// sum 4 conv partials + bias + relu -> feats fp16 [16384][128] (cols 96.. zero)
__global__ void conv_reduce_kernel(const float* __restrict__ P, const float* __restrict__ bcat,
                                   ushort_t* __restrict__ feats) {
    const size_t MT = (size_t)BATCH * SEQ;
    size_t i = (size_t)blockIdx.x * 256 + threadIdx.x;
    if (i >= MT * FC_PAD2) return;
    int col = (int)(i & (FC_PAD2 - 1));
    size_t row = i >> 7;
    float v = 0.f;
    if (col < FC_PAD) {
        size_t idx = row * FC_PAD + col;
        const size_t st = MT * FC_PAD;
        v = P[idx] + P[idx + st] + P[idx + 2 * st] + P[idx + 3 * st] + bcat[col];
        v = fmaxf(v, 0.f);
    }
    feats[i] = f2h(v);
}

// x2_h [8][2048][768] -> x2t [8][768][2048]
__global__ void transpose_f16_kernel(const ushort_t* __restrict__ in, ushort_t* __restrict__ out) {
    __shared__ ushort_t tile[32][40];
    int b = blockIdx.z;
    int s0 = blockIdx.x * 32, d0 = blockIdx.y * 32;
    int tx = threadIdx.x & 31, ty = threadIdx.x >> 5;   // 32 x 8
    const ushort_t* inb = in + (size_t)b * SEQ * D_MODEL;
    ushort_t* outb = out + (size_t)b * D_MODEL * SEQ;
    #pragma unroll
    for (int i = 0; i < 4; ++i)
        tile[ty + i * 8][tx] = inb[(size_t)(s0 + ty + i * 8) * D_MODEL + d0 + tx];
    __syncthreads();
    #pragma unroll
    for (int i = 0; i < 4; ++i)
        outb[(size_t)(d0 + ty + i * 8) * SEQ + s0 + tx] = tile[tx][ty + i * 8];
}

// rowbias[b,t] = x2[b,t,:] . bias_v   (fp32)
__global__ void rowbias_kernel(const float* __restrict__ x2, const float* __restrict__ bias_v,
                               float* __restrict__ rowbias) {
    int row = blockIdx.x;
    const float* xr = x2 + (size_t)row * D_MODEL;
    float s = 0.f;
    for (int c = threadIdx.x; c < D_MODEL; c += 256) s += xr[c] * bias_v[c];
    for (int off = 32; off > 0; off >>= 1) s += __shfl_down(s, off);
    __shared__ float red[4];
    int lane = threadIdx.x & 63, w = threadIdx.x >> 6;
    if (lane == 0) red[w] = s;
    __syncthreads();
    if (threadIdx.x == 0) rowbias[row] = red[0] + red[1] + red[2] + red[3];
}

// row softmax: fp32 in [2048], fp16 out via per-batch pointer table
__global__ void softmax_kernel(const float* __restrict__ in, Ptr8w ptrs, int b0) {
    __shared__ float ls[SEQ];
    __shared__ float red[4];
    __shared__ float bc;
    int row = blockIdx.x;
    const float* p = in + (size_t)row * SEQ;
    ushort_t* q = ptrs.p[b0 + (row >> 11)] + (size_t)(row & (SEQ - 1)) * SEQ;
    int lane = threadIdx.x & 63, w = threadIdx.x >> 6;

    float mx = -1e30f;
    for (int c = threadIdx.x; c < SEQ; c += 256) { float v = p[c]; ls[c] = v; mx = fmaxf(mx, v); }
    for (int off = 32; off > 0; off >>= 1) mx = fmaxf(mx, __shfl_down(mx, off));
    if (lane == 0) red[w] = mx;
    __syncthreads();
    if (threadIdx.x == 0) bc = fmaxf(fmaxf(red[0], red[1]), fmaxf(red[2], red[3]));
    __syncthreads();
    mx = bc;
    float s = 0.f;
    for (int c = threadIdx.x; c < SEQ; c += 256) { float e = __expf(ls[c] - mx); ls[c] = e; s += e; }
    for (int off = 32; off > 0; off >>= 1) s += __shfl_down(s, off);
    if (lane == 0) red[w] = s;
    __syncthreads();
    if (threadIdx.x == 0) bc = 1.f / (red[0] + red[1] + red[2] + red[3]);
    __syncthreads();
    float inv = bc;
    for (int c = threadIdx.x; c < SEQ; c += 256) q[c] = f2h(ls[c] * inv);
}

// ---------------- fp16 MFMA GEMM, BK=64, 128B LDS rows + XOR slot swizzle ----------------
// C[M,N] = epilogue( A' @ B'^T ); A' [M][K] fp16, B' [N][K] fp16 (N-major).
// WMC x WNC waves, each owning a (TM/WMC) x (TN/WNC) sub-tile (64x64 -> 64 acc VGPRs).
// LDS rows: 64 elems (8 x 16B slots), slot ^= (row&7) folded into the GLOBAL source
// address (linear global_load_lds dest, swizzled read — rule #21).
// AMODE: 0 plain, 1 im2col(x2_h, VGPR-staged), 2 concat(A|A2, stride 768)
// KSPLIT: blockIdx.z = K-chunk (kbase = z*K), C offset z*sC. APTR: A base = ap.p[z].
// OUTMODE: 0 fp32->Cf, 1 fp16->Ch
template<int TM, int TN, int WMC, int WNC, int AMODE, int ACT, int HASBIAS, int HASADD,
         int OUTMODE, int KSPLIT, int APTR>
__global__ __launch_bounds__(WMC * WNC * 64, 2)
void mfma_gemm(const ushort_t* __restrict__ A, const ushort_t* __restrict__ A2,
               const ushort_t* __restrict__ B, const float* __restrict__ bias,
               const ushort_t* __restrict__ addsrc,
               float* __restrict__ Cf, ushort_t* __restrict__ Ch,
               Ptr8 ap,
               int M, int N, int K, int lda, int ldb, int ldc,
               size_t sA, size_t sB, size_t sBias, size_t sC) {
    constexpr int NT = WMC * WNC * 64;
    constexpr int WM = TM / WMC, WN = TN / WNC, FM = WM / 16, FN = WN / 16;
    __shared__ __align__(16) ushort_t As_[TM * 64];
    __shared__ __align__(16) ushort_t Bs_[TN * 64];

    const int z = blockIdx.z;
    const int kb = KSPLIT ? z * K : 0;
    const ushort_t* Ab = APTR ? ap.p[z] : (A + (KSPLIT ? 0 : (size_t)z * sA));
    const ushort_t* Bb = B + (KSPLIT ? 0 : (size_t)z * sB);
    if (HASBIAS) bias += (size_t)z * sBias;
    if (HASADD) addsrc += (size_t)z * sC;
    if (OUTMODE == 0) Cf += (size_t)z * sC;
    else Ch += (size_t)z * sC;

    const int m0 = blockIdx.x * TM;
    const int n0 = blockIdx.y * TN;
    const int tid = threadIdx.x;
    const int lane = tid & 63;
    const int wave = tid >> 6;
    const int wm = (wave / WNC) * WM, wn = (wave % WNC) * WN;
    const int r16 = lane & 15, kq = lane >> 4;

    f32x4 acc[FM][FN];
    #pragma unroll
    for (int i = 0; i < FM; ++i)
        #pragma unroll
        for (int j = 0; j < FN; ++j) acc[i][j] = (f32x4){0.f, 0.f, 0.f, 0.f};

    const u16x8 zv = {0, 0, 0, 0, 0, 0, 0, 0};

    for (int k0 = 0; k0 < K; k0 += 64) {
        // ---- stage A: TM rows x 8 slots ----
        #pragma unroll
        for (int i = 0; i < TM * 8 / NT; ++i) {
            int idx = i * NT + tid;
            int row = idx >> 3, slot = idx & 7;
            int gm = m0 + row;
            int xs = slot ^ (row & 7);
            if (AMODE == 1) {
                int gkk = kb + k0 + xs * 8;
                int t = gkk / D_MODEL, d = gkk - t * D_MODEL;
                int s = (gm & (SEQ - 1)) + t - 3;
                int bb = gm >> 11;
                u16x8 v = (s >= 0 && s < SEQ) ? *(const u16x8*)(Ab + ((size_t)(bb * SEQ + s)) * lda + d) : zv;
                *(u16x8*)&As_[(size_t)idx * 8] = v;
            } else {
                const ushort_t* src;
                if (AMODE == 2) {
                    int gk = k0 + xs * 8;
                    src = (gk < D_MODEL) ? Ab + (size_t)gm * D_MODEL + gk
                                         : A2 + (size_t)gm * D_MODEL + (gk - D_MODEL);
                } else {
                    int gk = kb + k0 + xs * 8;
                    src = Ab + (size_t)gm * lda + gk;
                }
                gload16(src, &As_[(size_t)(i * NT + wave * 64) * 8]);
            }
        }
        // ---- stage B: TN rows x 8 slots ----
        #pragma unroll
        for (int i = 0; i < TN * 8 / NT; ++i) {
            int idx = i * NT + tid;
            int row = idx >> 3, slot = idx & 7;
            int gn = n0 + row;
            int xs = slot ^ (row & 7);
            int gk = kb + k0 + xs * 8;
            gload16(Bb + (size_t)gn * ldb + gk, &Bs_[(size_t)(i * NT + wave * 64) * 8]);
        }
        __syncthreads();

        f16x8 ah[FM][2], bh[FN][2];
        #pragma unroll
        for (int mi = 0; mi < FM; ++mi) {
            int row = wm + mi * 16 + r16;
            #pragma unroll
            for (int kk = 0; kk < 2; ++kk)
                ah[mi][kk] = *(const f16x8*)&As_[(size_t)row * 64 + (((kk * 4 + kq) ^ (row & 7)) * 8)];
        }
        #pragma unroll
        for (int ni = 0; ni < FN; ++ni) {
            int row = wn + ni * 16 + r16;
            #pragma unroll
            for (int kk = 0; kk < 2; ++kk)
                bh[ni][kk] = *(const f16x8*)&Bs_[(size_t)row * 64 + (((kk * 4 + kq) ^ (row & 7)) * 8)];
        }
        #pragma unroll
        for (int kk = 0; kk < 2; ++kk)
            #pragma unroll
            for (int mi = 0; mi < FM; ++mi)
                #pragma unroll
                for (int ni = 0; ni < FN; ++ni)
                    acc[mi][ni] = __builtin_amdgcn_mfma_f32_16x16x32_f16(ah[mi][kk], bh[ni][kk], acc[mi][ni], 0, 0, 0);
        __syncthreads();
    }

    // epilogue: C/D layout col = lane&15, row = (lane>>4)*4 + r
    #pragma unroll
    for (int mi = 0; mi < FM; ++mi)
        #pragma unroll
        for (int ni = 0; ni < FN; ++ni)
            #pragma unroll
            for (int r = 0; r < 4; ++r) {
                int gm = m0 + wm + mi * 16 + kq * 4 + r;
                int gn = n0 + wn + ni * 16 + r16;
                if (gn >= N) continue;
                float v = acc[mi][ni][r];
                if (HASBIAS) v += bias[gn];
                if (ACT == 1) v = fmaxf(v, 0.f);
                else if (ACT == 2) v = fast_tanh(v);
                if (HASADD) v += h2f(addsrc[(size_t)gm * ldc + gn]);
                size_t idx = (size_t)gm * ldc + gn;
                if (OUTMODE == 0) Cf[idx] = v;
                else Ch[idx] = f2h(v);
            }
}

extern "C" void kernel_launch(void* const* d_in, const int* in_sizes, int n_in,
                              void* d_out, int out_size, void* d_ws, size_t ws_size,
                              hipStream_t stream) {
    const float* x1     = (const float*)d_in[0];
    const float* x2     = (const float*)d_in[1];
    const float* w7     = (const float*)d_in[2];
    const float* b7     = (const float*)d_in[3];
    const float* w5     = (const float*)d_in[4];
    const float* b5     = (const float*)d_in[5];
    const float* w3     = (const float*)d_in[6];
    const float* b3     = (const float*)d_in[7];
    const float* U      = (const float*)d_in[8];
    const float* bias_v = (const float*)d_in[9];
    const float* fc_w   = (const float*)d_in[10];
    const float* fc_b   = (const float*)d_in[11];
    const float* fcx_w  = (const float*)d_in[12];
    const float* fcx_b  = (const float*)d_in[13];
    float* out = (float*)d_out;

    const size_t MT = (size_t)BATCH * SEQ;      // 16384
    const size_t NE = MT * D_MODEL;             // 12.58M
    const size_t NEb = (size_t)SEQ * D_MODEL;   // 1.57M
    const size_t SEGSZ = (size_t)SEQ * SEQ;     // 4.19M elems (one attnb batch)

    char* p = (char*)d_ws;
    auto alloc = [&](size_t bytes) -> char* {
        char* r = p;
        p += (bytes + 255) & ~(size_t)255;
        return r;
    };
    ushort_t* x1_h   = (ushort_t*)alloc(NE * 2);   // live to the end (final concat)
    ushort_t* x2_h   = (ushort_t*)alloc(NE * 2);   // dead per-batch after its scores chunk
    ushort_t* x2t    = (ushort_t*)alloc(NE * 2);   // live until PV
    ushort_t* y1     = (ushort_t*)alloc(NE * 2);   // dead per-batch after its scores chunk
    ushort_t* xcnn   = (ushort_t*)alloc(NE * 2);   // live to the end
    float*    convp  = (float*)   alloc(MT * FC_PAD * 4 * 4); // 4 partials; dead after reduce
    ushort_t* feats  = (ushort_t*)alloc(MT * FC_PAD2 * 2);
    ushort_t* Wt     = (ushort_t*)alloc((size_t)FC_PAD2 * KCOMB * 2);
    ushort_t* fc_wt  = (ushort_t*)alloc((size_t)D_MODEL * FC_PAD2 * 2);
    ushort_t* fcx_wt = (ushort_t*)alloc((size_t)D_MODEL * 2 * D_MODEL * 2);
    ushort_t* Ut     = (ushort_t*)alloc((size_t)D_MODEL * D_MODEL * 2);
    float*    bcat   = (float*)alloc(FC_PAD2 * 4);
    float*    rbias  = (float*)alloc(MT * 4);

    float* attnf = (float*)d_out;   // fp32 scores, 3 segments = 50.33MB = exactly d_out

    // attnb segments (each SEQ*SEQ fp16 = 8.39MB) in dead regions:
    //  b0-b2: convp (dead after conv_reduce; holds exactly 3 segments)
    //  b3,b4: y1 batches 0..5 region (dead after chunks 0/1)
    //  b5-b7: x2_h batches 0..5 region (dead after chunks 0/1)
    Ptr8w apw;
    apw.p[0] = (ushort_t*)convp;
    apw.p[1] = (ushort_t*)convp + SEGSZ;
    apw.p[2] = (ushort_t*)convp + 2 * SEGSZ;
    apw.p[3] = y1;                       // [0, 4.19M) ⊂ y1 b0-2 (dead after chunk0)
    apw.p[4] = y1 + SEGSZ;               // [4.19M, 8.39M) ⊂ y1 b0-5 (dead after chunk1)
    apw.p[5] = x2_h;                     // [0, 4.19M) ⊂ x2_h b0-2 (dead after chunk0)
    apw.p[6] = x2_h + SEGSZ;             // written after chunk2; x2_h b0-5 dead
    apw.p[7] = x2_h + 2 * SEGSZ;         // written after chunk2's scores completes
    Ptr8 ap;
    for (int i = 0; i < 8; ++i) ap.p[i] = apw.p[i];
    Ptr8 apz = {};

    const int T = 256;
    auto blk = [](size_t n) { return dim3((unsigned)((n + 255) / 256)); };

    // ---- prep ----
    build_wcomb_kernel<<<blk((size_t)FC_PAD2 * KCOMB), T, 0, stream>>>(w7, b7, w5, b5, w3, b3, Wt, bcat);
    convert_fc_kernel<<<blk((size_t)D_MODEL * FC_PAD2), T, 0, stream>>>(fc_w, fc_wt);
    convert_f16_kernel<<<blk((size_t)D_MODEL * 2 * D_MODEL / 4), T, 0, stream>>>(fcx_w, fcx_wt, (size_t)D_MODEL * 2 * D_MODEL / 4);
    convert_ut_kernel<<<blk((size_t)D_MODEL * D_MODEL), T, 0, stream>>>(U, Ut);
    convert_f16_kernel<<<blk(NE / 4), T, 0, stream>>>(x1, x1_h, NE / 4);
    convert_f16_kernel<<<blk(NE / 4), T, 0, stream>>>(x2, x2_h, NE / 4);
    transpose_f16_kernel<<<dim3(SEQ / 32, D_MODEL / 32, BATCH), T, 0, stream>>>(x2_h, x2t);
    rowbias_kernel<<<dim3((unsigned)MT), T, 0, stream>>>(x2, bias_v, rbias);

    // ---- conv: 4 K-chunks -> fp32 partials, then reduce+bias+relu -> feats ----
    mfma_gemm<64, 128, 2, 2, 1, 0, 0, 0, 0, 1, 0><<<dim3(MT / 64, 1, 4), 256, 0, stream>>>(
        x2_h, nullptr, Wt, nullptr, nullptr,
        convp, nullptr, apz,
        (int)MT, FC_PAD, KCHUNK, D_MODEL, KCOMB, FC_PAD,
        0, 0, 0, MT * FC_PAD);
    conv_reduce_kernel<<<blk(MT * FC_PAD2), T, 0, stream>>>(convp, bcat, feats);

    // ---- fc: xcnn = tanh(feats @ fc_w^T + fc_b), K padded to 128 ----
    mfma_gemm<128, 256, 2, 4, 0, 2, 1, 0, 1, 0, 0><<<dim3(MT / 128, 3, 1), 512, 0, stream>>>(
        feats, nullptr, fc_wt, fc_b, nullptr,
        nullptr, xcnn, apz,
        (int)MT, D_MODEL, FC_PAD2, FC_PAD2, FC_PAD2, D_MODEL, 0, 0, 0, 0);

    // ---- y1 = x1 @ U, fp16 out ----
    mfma_gemm<128, 256, 2, 4, 0, 0, 0, 0, 1, 0, 0><<<dim3(MT / 128, 3, 1), 512, 0, stream>>>(
        x1_h, nullptr, Ut, nullptr, nullptr,
        nullptr, y1, apz,
        (int)MT, D_MODEL, D_MODEL, D_MODEL, D_MODEL, D_MODEL, 0, 0, 0, 0);

    // ---- attention: scores+softmax in chunks {3,3,2}, then one 8-batch PV ----
    const int b0s[3] = {0, 3, 6};
    const int nbs[3] = {3, 3, 2};
    for (int c = 0; c < 3; ++c) {
        const int b0 = b0s[c], nb = nbs[c];
        const size_t off = (size_t)b0 * NEb;

        mfma_gemm<128, 256, 2, 4, 0, 0, 1, 0, 0, 0, 0><<<dim3(SEQ / 128, SEQ / 256, nb), 512, 0, stream>>>(
            y1 + off, nullptr, x2_h + off,
            rbias + (size_t)b0 * SEQ, nullptr,
            attnf, nullptr, apz,
            SEQ, SEQ, D_MODEL, D_MODEL, D_MODEL, SEQ,
            NEb, NEb, SEQ, SEGSZ);

        softmax_kernel<<<dim3((unsigned)(nb * SEQ)), T, 0, stream>>>(attnf, apw, b0);
    }

    // PV: x = xcnn + tanh(attn @ x2), all 8 batches, A via pointer table
    mfma_gemm<128, 256, 2, 4, 0, 2, 0, 1, 1, 0, 1><<<dim3(SEQ / 128, 3, BATCH), 512, 0, stream>>>(
        nullptr, nullptr, x2t, nullptr,
        xcnn,
        nullptr, xcnn, ap,
        SEQ, D_MODEL, SEQ, SEQ, SEQ, D_MODEL,
        0, NEb, 0, NEb);

    // ---- final: out = concat(x1, x) @ fcx_w^T + fcx_b ----
    mfma_gemm<128, 256, 2, 4, 2, 0, 1, 0, 0, 0, 0><<<dim3(MT / 128, 3, 1), 512, 0, stream>>>(
        x1_h, xcnn, fcx_wt, fcx_b, nullptr,
        out, nullptr, apz,
        (int)MT, D_MODEL, 2 * D_MODEL, D_MODEL, 2 * D_MODEL, D_MODEL, 0, 0, 0, 0);
}

// Round 7
// 399.056 us; speedup vs baseline: 15.2256x; 1.0057x over previous
//
#include <hip/hip_runtime.h>
#include <cmath>

#define D_MODEL 768
#define SEQ 2048
#define BATCH 8
#define FC_PAD 96
#define FC_PAD2 128
#define KCOMB (7 * D_MODEL)   // 5376
#define KCHUNK 1344           // KCOMB/4

typedef unsigned short ushort_t;
typedef _Float16 half_t;
typedef __attribute__((ext_vector_type(8))) _Float16 f16x8;
typedef __attribute__((ext_vector_type(8))) unsigned short u16x8;
typedef __attribute__((ext_vector_type(4))) unsigned short u16x4;
typedef __attribute__((ext_vector_type(4))) float f32x4;

struct Ptr8  { const ushort_t* p[8]; };
struct Ptr8w { ushort_t* p[8]; };

__device__ __forceinline__ ushort_t f2h(float x) {
    half_t h = (half_t)x;
    return __builtin_bit_cast(ushort_t, h);
}
__device__ __forceinline__ float h2f(ushort_t u) {
    return (float)__builtin_bit_cast(half_t, u);
}
__device__ __forceinline__ float fast_tanh(float x) {
    float a = fabsf(x);
    float t = __expf(-2.f * a);
    float r = (1.f - t) / (1.f + t);
    return copysignf(r, x);
}
__device__ __forceinline__ void gload16(const ushort_t* g, ushort_t* lbase) {
    __builtin_amdgcn_global_load_lds((const __attribute__((address_space(1))) void*)g,
                                     (__attribute__((address_space(3))) void*)lbase,
                                     16, 0, 0);
}

// ---------------- prep kernels ----------------
__global__ void convert_f16_kernel(const float* __restrict__ src, ushort_t* __restrict__ dst, size_t n4) {
    size_t i = (size_t)blockIdx.x * 256 + threadIdx.x;
    if (i >= n4) return;
    f32x4 x = *(const f32x4*)(src + i * 4);
    u16x4 h;
    #pragma unroll
    for (int j = 0; j < 4; ++j) h[j] = f2h(x[j]);
    *(u16x4*)(dst + i * 4) = h;
}

// fc_w [768][90] -> fc_wt fp16 [768][128] zero-padded
__global__ void convert_fc_kernel(const float* __restrict__ src, ushort_t* __restrict__ dst) {
    int i = blockIdx.x * 256 + threadIdx.x;
    if (i >= D_MODEL * FC_PAD2) return;
    int o = i / FC_PAD2, j = i - o * FC_PAD2;
    dst[i] = (j < 90) ? f2h(src[o * 90 + j]) : 0;
}

// U [768][768] -> Ut [n][k] = fp16(U[k][n])
__global__ void convert_ut_kernel(const float* __restrict__ U, ushort_t* __restrict__ dst) {
    int i = blockIdx.x * 256 + threadIdx.x;
    if (i >= D_MODEL * D_MODEL) return;
    int n = i / D_MODEL, k = i - n * D_MODEL;
    dst[i] = f2h(U[(size_t)k * D_MODEL + n]);
}

// combined conv weight, fp16, [128][5376]; rows 90..127 zero
__global__ void build_wcomb_kernel(const float* __restrict__ w7, const float* __restrict__ b7,
                                   const float* __restrict__ w5, const float* __restrict__ b5,
                                   const float* __restrict__ w3, const float* __restrict__ b3,
                                   ushort_t* __restrict__ Wt, float* __restrict__ bcat) {
    int idx = blockIdx.x * 256 + threadIdx.x;
    const int total = FC_PAD2 * KCOMB;
    if (idx < total) {
        int o = idx / KCOMB, k = idx - o * KCOMB;
        int t = k / D_MODEL, d = k - t * D_MODEL;
        float v = 0.f;
        if (o < 40) {
            v = w7[(size_t)o * (D_MODEL * 7) + d * 7 + t];
        } else if (o < 70) {
            int t5 = t - 1;
            if (t5 >= 0 && t5 < 5) v = w5[(size_t)(o - 40) * (D_MODEL * 5) + d * 5 + t5];
        } else if (o < 90) {
            int t3 = t - 2;
            if (t3 >= 0 && t3 < 3) v = w3[(size_t)(o - 70) * (D_MODEL * 3) + d * 3 + t3];
        }
        Wt[idx] = f2h(v);
    }
    if (idx < FC_PAD2) {
        float bv = 0.f;
        if (idx < 40) bv = b7[idx];
        else if (idx < 70) bv = b5[idx - 40];
        else if (idx < 90) bv = b3[idx - 70];
        bcat[idx] = bv;
    }
}

// sum 4 conv partials + bias + relu -> feats fp16 [16384][128] (cols 96.. zero)
__global__ void conv_reduce_kernel(const float* __restrict__ P, const float* __restrict__ bcat,
                                   ushort_t* __restrict__ feats) {
    const size_t MT = (size_t)BATCH * SEQ;
    size_t i = (size_t)blockIdx.x * 256 + threadIdx.x;
    if (i >= MT * FC_PAD2) return;
    int col = (int)(i & (FC_PAD2 - 1));
    size_t row = i >> 7;
    float v = 0.f;
    if (col < FC_PAD) {
        size_t idx = row * FC_PAD + col;
        const size_t st = MT * FC_PAD;
        v = P[idx] + P[idx + st] + P[idx + 2 * st] + P[idx + 3 * st] + bcat[col];
        v = fmaxf(v, 0.f);
    }
    feats[i] = f2h(v);
}

// x2_h [8][2048][768] -> x2t [8][768][2048]
__global__ void transpose_f16_kernel(const ushort_t* __restrict__ in, ushort_t* __restrict__ out) {
    __shared__ ushort_t tile[32][40];
    int b = blockIdx.z;
    int s0 = blockIdx.x * 32, d0 = blockIdx.y * 32;
    int tx = threadIdx.x & 31, ty = threadIdx.x >> 5;   // 32 x 8
    const ushort_t* inb = in + (size_t)b * SEQ * D_MODEL;
    ushort_t* outb = out + (size_t)b * D_MODEL * SEQ;
    #pragma unroll
    for (int i = 0; i < 4; ++i)
        tile[ty + i * 8][tx] = inb[(size_t)(s0 + ty + i * 8) * D_MODEL + d0 + tx];
    __syncthreads();
    #pragma unroll
    for (int i = 0; i < 4; ++i)
        outb[(size_t)(d0 + ty + i * 8) * SEQ + s0 + tx] = tile[tx][ty + i * 8];
}

// rowbias[b,t] = x2[b,t,:] . bias_v   (fp32)
__global__ void rowbias_kernel(const float* __restrict__ x2, const float* __restrict__ bias_v,
                               float* __restrict__ rowbias) {
    int row = blockIdx.x;
    const float* xr = x2 + (size_t)row * D_MODEL;
    float s = 0.f;
    for (int c = threadIdx.x; c < D_MODEL; c += 256) s += xr[c] * bias_v[c];
    for (int off = 32; off > 0; off >>= 1) s += __shfl_down(s, off);
    __shared__ float red[4];
    int lane = threadIdx.x & 63, w = threadIdx.x >> 6;
    if (lane == 0) red[w] = s;
    __syncthreads();
    if (threadIdx.x == 0) rowbias[row] = red[0] + red[1] + red[2] + red[3];
}

// row softmax: fp32 in [2048], fp16 out via per-batch pointer table
__global__ void softmax_kernel(const float* __restrict__ in, Ptr8w ptrs, int b0) {
    __shared__ float ls[SEQ];
    __shared__ float red[4];
    __shared__ float bc;
    int row = blockIdx.x;
    const float* p = in + (size_t)row * SEQ;
    ushort_t* q = ptrs.p[b0 + (row >> 11)] + (size_t)(row & (SEQ - 1)) * SEQ;
    int lane = threadIdx.x & 63, w = threadIdx.x >> 6;

    float mx = -1e30f;
    for (int c = threadIdx.x; c < SEQ; c += 256) { float v = p[c]; ls[c] = v; mx = fmaxf(mx, v); }
    for (int off = 32; off > 0; off >>= 1) mx = fmaxf(mx, __shfl_down(mx, off));
    if (lane == 0) red[w] = mx;
    __syncthreads();
    if (threadIdx.x == 0) bc = fmaxf(fmaxf(red[0], red[1]), fmaxf(red[2], red[3]));
    __syncthreads();
    mx = bc;
    float s = 0.f;
    for (int c = threadIdx.x; c < SEQ; c += 256) { float e = __expf(ls[c] - mx); ls[c] = e; s += e; }
    for (int off = 32; off > 0; off >>= 1) s += __shfl_down(s, off);
    if (lane == 0) red[w] = s;
    __syncthreads();
    if (threadIdx.x == 0) bc = 1.f / (red[0] + red[1] + red[2] + red[3]);
    __syncthreads();
    float inv = bc;
    for (int c = threadIdx.x; c < SEQ; c += 256) q[c] = f2h(ls[c] * inv);
}

// ---------------- fp16 MFMA GEMM, BK=64, 128B LDS rows + XOR slot swizzle ----------------
// C[M,N] = epilogue( A' @ B'^T ); A' [M][K] fp16, B' [N][K] fp16 (N-major).
// 4 waves (2x2), wave tile 64x64. LDS rows: 64 elems (8 x 16B slots),
// slot ^= (row&7) folded into the GLOBAL source address (rule #21).
// AMODE: 0 plain, 1 im2col(x2_h, VGPR-staged), 2 concat(A|A2, stride 768)
// KSPLIT: blockIdx.z = K-chunk (kbase = z*K), C offset z*sC. APTR: A base = ap.p[z].
// OUTMODE: 0 fp32->Cf, 1 fp16->Ch
// MAP (block->tile decode; XCD = linear_id % 8 empirically):
//  0: (blockIdx.x, blockIdx.y, blockIdx.z)
//  1: lin -> z = lin%ZM, t = lin/ZM, bx = t%GX, by = t/GX   (per-XCD batch pinning)
//  2: lin -> xcd = lin%8, t = lin/8, by = t%GY, bx = xcd*(GX/8) + t/GY  (A-panel slice per XCD)
template<int TM, int TN, int AMODE, int ACT, int HASBIAS, int HASADD,
         int OUTMODE, int KSPLIT, int APTR, int MAP, int ZM, int GX, int GY>
__global__ __launch_bounds__(256, 3)
void mfma_gemm(const ushort_t* __restrict__ A, const ushort_t* __restrict__ A2,
               const ushort_t* __restrict__ B, const float* __restrict__ bias,
               const ushort_t* __restrict__ addsrc,
               float* __restrict__ Cf, ushort_t* __restrict__ Ch,
               Ptr8 ap,
               int M, int N, int K, int lda, int ldb, int ldc,
               size_t sA, size_t sB, size_t sBias, size_t sC) {
    constexpr int WM = TM / 2, WN = TN / 2, FM = WM / 16, FN = WN / 16;
    __shared__ __align__(16) ushort_t As_[TM * 64];
    __shared__ __align__(16) ushort_t Bs_[TN * 64];

    int bx, by, z;
    if (MAP == 1) {
        int lin = blockIdx.x;
        z = lin % ZM;
        int t = lin / ZM;
        bx = t % GX;
        by = t / GX;
    } else if (MAP == 2) {
        int lin = blockIdx.x;
        int xcd = lin & 7;
        int t = lin >> 3;
        by = t % GY;
        bx = xcd * (GX / 8) + t / GY;
        z = 0;
    } else {
        bx = blockIdx.x; by = blockIdx.y; z = blockIdx.z;
    }

    const int kb = KSPLIT ? z * K : 0;
    const ushort_t* Ab = APTR ? ap.p[z] : (A + (KSPLIT ? 0 : (size_t)z * sA));
    const ushort_t* Bb = B + (KSPLIT ? 0 : (size_t)z * sB);
    if (HASBIAS) bias += (size_t)z * sBias;
    if (HASADD) addsrc += (size_t)z * sC;
    if (OUTMODE == 0) Cf += (size_t)z * sC;
    else Ch += (size_t)z * sC;

    const int m0 = bx * TM;
    const int n0 = by * TN;
    const int tid = threadIdx.x;
    const int lane = tid & 63;
    const int wave = tid >> 6;
    const int wm = (wave >> 1) * WM, wn = (wave & 1) * WN;
    const int r16 = lane & 15, kq = lane >> 4;
    const int srow = tid >> 3;          // 0..31
    const int slot = tid & 7;           // 16B slot (LDS-linear)

    f32x4 acc[FM][FN];
    #pragma unroll
    for (int i = 0; i < FM; ++i)
        #pragma unroll
        for (int j = 0; j < FN; ++j) acc[i][j] = (f32x4){0.f, 0.f, 0.f, 0.f};

    const u16x8 zv = {0, 0, 0, 0, 0, 0, 0, 0};

    for (int k0 = 0; k0 < K; k0 += 64) {
        // ---- stage A ----
        #pragma unroll
        for (int i = 0; i < TM / 32; ++i) {
            int row = i * 32 + srow;
            int gm = m0 + row;
            int xs = slot ^ (row & 7);
            if (AMODE == 1) {
                int gkk = kb + k0 + xs * 8;
                int t = gkk / D_MODEL, d = gkk - t * D_MODEL;
                int s = (gm & (SEQ - 1)) + t - 3;
                int bb = gm >> 11;
                u16x8 v = (s >= 0 && s < SEQ) ? *(const u16x8*)(Ab + ((size_t)(bb * SEQ + s)) * lda + d) : zv;
                *(u16x8*)&As_[(size_t)row * 64 + slot * 8] = v;
            } else {
                const ushort_t* src;
                if (AMODE == 2) {
                    int gk = k0 + xs * 8;
                    src = (gk < D_MODEL) ? Ab + (size_t)gm * D_MODEL + gk
                                         : A2 + (size_t)gm * D_MODEL + (gk - D_MODEL);
                } else {
                    int gk = kb + k0 + xs * 8;
                    src = Ab + (size_t)gm * lda + gk;
                }
                gload16(src, &As_[(size_t)(i * 32 + wave * 8) * 64]);
            }
        }
        // ---- stage B ----
        #pragma unroll
        for (int i = 0; i < TN / 32; ++i) {
            int row = i * 32 + srow;
            int gn = n0 + row;
            int xs = slot ^ (row & 7);
            int gk = kb + k0 + xs * 8;
            gload16(Bb + (size_t)gn * ldb + gk, &Bs_[(size_t)(i * 32 + wave * 8) * 64]);
        }
        __syncthreads();

        f16x8 ah[FM][2], bh[FN][2];
        #pragma unroll
        for (int mi = 0; mi < FM; ++mi) {
            int row = wm + mi * 16 + r16;
            #pragma unroll
            for (int kk = 0; kk < 2; ++kk)
                ah[mi][kk] = *(const f16x8*)&As_[(size_t)row * 64 + (((kk * 4 + kq) ^ (row & 7)) * 8)];
        }
        #pragma unroll
        for (int ni = 0; ni < FN; ++ni) {
            int row = wn + ni * 16 + r16;
            #pragma unroll
            for (int kk = 0; kk < 2; ++kk)
                bh[ni][kk] = *(const f16x8*)&Bs_[(size_t)row * 64 + (((kk * 4 + kq) ^ (row & 7)) * 8)];
        }
        #pragma unroll
        for (int kk = 0; kk < 2; ++kk)
            #pragma unroll
            for (int mi = 0; mi < FM; ++mi)
                #pragma unroll
                for (int ni = 0; ni < FN; ++ni)
                    acc[mi][ni] = __builtin_amdgcn_mfma_f32_16x16x32_f16(ah[mi][kk], bh[ni][kk], acc[mi][ni], 0, 0, 0);
        __syncthreads();
    }

    // epilogue: C/D layout col = lane&15, row = (lane>>4)*4 + r
    #pragma unroll
    for (int mi = 0; mi < FM; ++mi)
        #pragma unroll
        for (int ni = 0; ni < FN; ++ni)
            #pragma unroll
            for (int r = 0; r < 4; ++r) {
                int gm = m0 + wm + mi * 16 + kq * 4 + r;
                int gn = n0 + wn + ni * 16 + r16;
                if (gn >= N) continue;
                float v = acc[mi][ni][r];
                if (HASBIAS) v += bias[gn];
                if (ACT == 1) v = fmaxf(v, 0.f);
                else if (ACT == 2) v = fast_tanh(v);
                if (HASADD) v += h2f(addsrc[(size_t)gm * ldc + gn]);
                size_t idx = (size_t)gm * ldc + gn;
                if (OUTMODE == 0) Cf[idx] = v;
                else Ch[idx] = f2h(v);
            }
}

extern "C" void kernel_launch(void* const* d_in, const int* in_sizes, int n_in,
                              void* d_out, int out_size, void* d_ws, size_t ws_size,
                              hipStream_t stream) {
    const float* x1     = (const float*)d_in[0];
    const float* x2     = (const float*)d_in[1];
    const float* w7     = (const float*)d_in[2];
    const float* b7     = (const float*)d_in[3];
    const float* w5     = (const float*)d_in[4];
    const float* b5     = (const float*)d_in[5];
    const float* w3     = (const float*)d_in[6];
    const float* b3     = (const float*)d_in[7];
    const float* U      = (const float*)d_in[8];
    const float* bias_v = (const float*)d_in[9];
    const float* fc_w   = (const float*)d_in[10];
    const float* fc_b   = (const float*)d_in[11];
    const float* fcx_w  = (const float*)d_in[12];
    const float* fcx_b  = (const float*)d_in[13];
    float* out = (float*)d_out;

    const size_t MT = (size_t)BATCH * SEQ;      // 16384
    const size_t NE = MT * D_MODEL;             // 12.58M
    const size_t NEb = (size_t)SEQ * D_MODEL;   // 1.57M elems (3.15MB fp16 per batch)
    const size_t SEGSZ = (size_t)SEQ * SEQ;     // 4.19M elems (8.39MB fp16 per attnb batch)

    char* p = (char*)d_ws;
    auto alloc = [&](size_t bytes) -> char* {
        char* r = p;
        p += (bytes + 255) & ~(size_t)255;
        return r;
    };
    ushort_t* x1_h   = (ushort_t*)alloc(NE * 2);   // live to the end (final concat)
    ushort_t* x2_h   = (ushort_t*)alloc(NE * 2);   // dead per-batch after its scores chunk
    ushort_t* x2t    = (ushort_t*)alloc(NE * 2);   // live until PV
    ushort_t* y1     = (ushort_t*)alloc(NE * 2);   // dead per-batch after its scores chunk
    ushort_t* xcnn   = (ushort_t*)alloc(NE * 2);   // live to the end
    float*    convp  = (float*)   alloc(MT * FC_PAD * 4 * 4); // 4 partials; dead after reduce
    ushort_t* feats  = (ushort_t*)alloc(MT * FC_PAD2 * 2);
    ushort_t* Wt     = (ushort_t*)alloc((size_t)FC_PAD2 * KCOMB * 2);
    ushort_t* fc_wt  = (ushort_t*)alloc((size_t)D_MODEL * FC_PAD2 * 2);
    ushort_t* fcx_wt = (ushort_t*)alloc((size_t)D_MODEL * 2 * D_MODEL * 2);
    ushort_t* Ut     = (ushort_t*)alloc((size_t)D_MODEL * D_MODEL * 2);
    float*    bcat   = (float*)alloc(FC_PAD2 * 4);
    float*    rbias  = (float*)alloc(MT * 4);

    float* attnf = (float*)d_out;   // fp32 scores, 2 batches = 33.6MB <= d_out 50.3MB

    // attnb segments (each 8.39MB) in dead regions (2-batch chunk schedule):
    //  written after chunk c's scores complete; all reads happen in PV at the end.
    Ptr8w apw;
    apw.p[0] = (ushort_t*)convp;              // chunk0: convp dead after conv_reduce
    apw.p[1] = (ushort_t*)convp + SEGSZ;
    apw.p[2] = (ushort_t*)convp + 2 * SEGSZ;  // chunk1
    apw.p[3] = y1;                            // chunk1: y1 b0-b1 (+part b2, dead by then)
    apw.p[4] = x2_h;                          // chunk2: x2_h b0-b2 dead
    apw.p[5] = x2_h + SEGSZ;                  // chunk2: x2_h b1-b5 dead
    apw.p[6] = y1 + SEGSZ;                    // chunk3: y1 b2-b5 dead
    apw.p[7] = x2_h + 2 * SEGSZ;              // chunk3: x2_h b5-b7 dead
    Ptr8 ap;
    for (int i = 0; i < 8; ++i) ap.p[i] = apw.p[i];
    Ptr8 apz = {};

    const int T = 256;
    auto blk = [](size_t n) { return dim3((unsigned)((n + 255) / 256)); };

    // ---- prep ----
    build_wcomb_kernel<<<blk((size_t)FC_PAD2 * KCOMB), T, 0, stream>>>(w7, b7, w5, b5, w3, b3, Wt, bcat);
    convert_fc_kernel<<<blk((size_t)D_MODEL * FC_PAD2), T, 0, stream>>>(fc_w, fc_wt);
    convert_f16_kernel<<<blk((size_t)D_MODEL * 2 * D_MODEL / 4), T, 0, stream>>>(fcx_w, fcx_wt, (size_t)D_MODEL * 2 * D_MODEL / 4);
    convert_ut_kernel<<<blk((size_t)D_MODEL * D_MODEL), T, 0, stream>>>(U, Ut);
    convert_f16_kernel<<<blk(NE / 4), T, 0, stream>>>(x1, x1_h, NE / 4);
    convert_f16_kernel<<<blk(NE / 4), T, 0, stream>>>(x2, x2_h, NE / 4);
    transpose_f16_kernel<<<dim3(SEQ / 32, D_MODEL / 32, BATCH), T, 0, stream>>>(x2_h, x2t);
    rowbias_kernel<<<dim3((unsigned)MT), T, 0, stream>>>(x2, bias_v, rbias);

    // ---- conv: 4 K-chunks -> fp32 partials, then reduce+bias+relu -> feats ----
    mfma_gemm<64, 128, 1, 0, 0, 0, 0, 1, 0, 0, 1, 1, 1><<<dim3(MT / 64, 1, 4), T, 0, stream>>>(
        x2_h, nullptr, Wt, nullptr, nullptr,
        convp, nullptr, apz,
        (int)MT, FC_PAD, KCHUNK, D_MODEL, KCOMB, FC_PAD,
        0, 0, 0, MT * FC_PAD);
    conv_reduce_kernel<<<blk(MT * FC_PAD2), T, 0, stream>>>(convp, bcat, feats);

    // ---- fc: xcnn = tanh(feats @ fc_w^T + fc_b), K padded to 128; MAP2 panel-sliced ----
    mfma_gemm<128, 128, 0, 2, 1, 0, 1, 0, 0, 2, 1, 128, 6><<<dim3(768, 1, 1), T, 0, stream>>>(
        feats, nullptr, fc_wt, fc_b, nullptr,
        nullptr, xcnn, apz,
        (int)MT, D_MODEL, FC_PAD2, FC_PAD2, FC_PAD2, D_MODEL, 0, 0, 0, 0);

    // ---- y1 = x1 @ U, fp16 out; MAP2 panel-sliced ----
    mfma_gemm<128, 128, 0, 0, 0, 0, 1, 0, 0, 2, 1, 128, 6><<<dim3(768, 1, 1), T, 0, stream>>>(
        x1_h, nullptr, Ut, nullptr, nullptr,
        nullptr, y1, apz,
        (int)MT, D_MODEL, D_MODEL, D_MODEL, D_MODEL, D_MODEL, 0, 0, 0, 0);

    // ---- attention: scores+softmax in 4 chunks of 2 batches; MAP1 batch-per-XCD-pair ----
    for (int c = 0; c < 4; ++c) {
        const int b0 = c * 2;
        const size_t off = (size_t)b0 * NEb;

        mfma_gemm<128, 128, 0, 0, 1, 0, 0, 0, 0, 1, 2, 16, 16><<<dim3(512, 1, 1), T, 0, stream>>>(
            y1 + off, nullptr, x2_h + off,
            rbias + (size_t)b0 * SEQ, nullptr,
            attnf, nullptr, apz,
            SEQ, SEQ, D_MODEL, D_MODEL, D_MODEL, SEQ,
            NEb, NEb, SEQ, SEGSZ);

        softmax_kernel<<<dim3((unsigned)(2 * SEQ)), T, 0, stream>>>(attnf, apw, b0);
    }

    // ---- PV: x = xcnn + tanh(attn @ x2), all 8 batches; MAP1 batch-per-XCD ----
    mfma_gemm<128, 128, 0, 2, 0, 1, 1, 0, 1, 1, 8, 16, 6><<<dim3(768, 1, 1), T, 0, stream>>>(
        nullptr, nullptr, x2t, nullptr,
        xcnn,
        nullptr, xcnn, ap,
        SEQ, D_MODEL, SEQ, SEQ, SEQ, D_MODEL,
        0, NEb, 0, NEb);

    // ---- final: out = concat(x1, x) @ fcx_w^T + fcx_b; MAP2 panel-sliced ----
    mfma_gemm<128, 128, 2, 0, 1, 0, 0, 0, 0, 2, 1, 128, 6><<<dim3(768, 1, 1), T, 0, stream>>>(
        x1_h, xcnn, fcx_wt, fcx_b, nullptr,
        out, nullptr, apz,
        (int)MT, D_MODEL, 2 * D_MODEL, D_MODEL, 2 * D_MODEL, D_MODEL, 0, 0, 0, 0);
}

// Round 8
// 341.080 us; speedup vs baseline: 17.8136x; 1.1700x over previous
//
#include <hip/hip_runtime.h>
#include <cmath>

#define D_MODEL 768
#define SEQ 2048
#define BATCH 8
#define FC_PAD 96
#define FC_PAD2 128
#define KCOMB (7 * D_MODEL)   // 5376
#define KCHUNK 1344           // KCOMB/4

typedef unsigned short ushort_t;
typedef _Float16 half_t;
typedef __attribute__((ext_vector_type(8))) _Float16 f16x8;
typedef __attribute__((ext_vector_type(8))) unsigned short u16x8;
typedef __attribute__((ext_vector_type(4))) unsigned short u16x4;
typedef __attribute__((ext_vector_type(4))) float f32x4;

struct Ptr8 { const ushort_t* p[8]; };

__device__ __forceinline__ ushort_t f2h(float x) {
    half_t h = (half_t)x;
    return __builtin_bit_cast(ushort_t, h);
}
__device__ __forceinline__ float h2f(ushort_t u) {
    return (float)__builtin_bit_cast(half_t, u);
}
__device__ __forceinline__ float fast_tanh(float x) {
    float a = fabsf(x);
    float t = __expf(-2.f * a);
    float r = (1.f - t) / (1.f + t);
    return copysignf(r, x);
}
__device__ __forceinline__ void gload16(const ushort_t* g, ushort_t* lbase) {
    __builtin_amdgcn_global_load_lds((const __attribute__((address_space(1))) void*)g,
                                     (__attribute__((address_space(3))) void*)lbase,
                                     16, 0, 0);
}

// ---------------- prep kernels ----------------
__global__ void convert_f16_kernel(const float* __restrict__ src, ushort_t* __restrict__ dst, size_t n4) {
    size_t i = (size_t)blockIdx.x * 256 + threadIdx.x;
    if (i >= n4) return;
    f32x4 x = *(const f32x4*)(src + i * 4);
    u16x4 h;
    #pragma unroll
    for (int j = 0; j < 4; ++j) h[j] = f2h(x[j]);
    *(u16x4*)(dst + i * 4) = h;
}

// fc_w [768][90] -> fc_wt fp16 [768][128] zero-padded
__global__ void convert_fc_kernel(const float* __restrict__ src, ushort_t* __restrict__ dst) {
    int i = blockIdx.x * 256 + threadIdx.x;
    if (i >= D_MODEL * FC_PAD2) return;
    int o = i / FC_PAD2, j = i - o * FC_PAD2;
    dst[i] = (j < 90) ? f2h(src[o * 90 + j]) : 0;
}

// U [768][768] -> Ut [n][k] = fp16(U[k][n])
__global__ void convert_ut_kernel(const float* __restrict__ U, ushort_t* __restrict__ dst) {
    int i = blockIdx.x * 256 + threadIdx.x;
    if (i >= D_MODEL * D_MODEL) return;
    int n = i / D_MODEL, k = i - n * D_MODEL;
    dst[i] = f2h(U[(size_t)k * D_MODEL + n]);
}

// combined conv weight, fp16, [128][5376]; rows 90..127 zero
__global__ void build_wcomb_kernel(const float* __restrict__ w7, const float* __restrict__ b7,
                                   const float* __restrict__ w5, const float* __restrict__ b5,
                                   const float* __restrict__ w3, const float* __restrict__ b3,
                                   ushort_t* __restrict__ Wt, float* __restrict__ bcat) {
    int idx = blockIdx.x * 256 + threadIdx.x;
    const int total = FC_PAD2 * KCOMB;
    if (idx < total) {
        int o = idx / KCOMB, k = idx - o * KCOMB;
        int t = k / D_MODEL, d = k - t * D_MODEL;
        float v = 0.f;
        if (o < 40) {
            v = w7[(size_t)o * (D_MODEL * 7) + d * 7 + t];
        } else if (o < 70) {
            int t5 = t - 1;
            if (t5 >= 0 && t5 < 5) v = w5[(size_t)(o - 40) * (D_MODEL * 5) + d * 5 + t5];
        } else if (o < 90) {
            int t3 = t - 2;
            if (t3 >= 0 && t3 < 3) v = w3[(size_t)(o - 70) * (D_MODEL * 3) + d * 3 + t3];
        }
        Wt[idx] = f2h(v);
    }
    if (idx < FC_PAD2) {
        float bv = 0.f;
        if (idx < 40) bv = b7[idx];
        else if (idx < 70) bv = b5[idx - 40];
        else if (idx < 90) bv = b3[idx - 70];
        bcat[idx] = bv;
    }
}

// sum 4 conv partials + bias + relu -> feats fp16 [16384][128] (cols 96.. zero)
__global__ void conv_reduce_kernel(const float* __restrict__ P, const float* __restrict__ bcat,
                                   ushort_t* __restrict__ feats) {
    const size_t MT = (size_t)BATCH * SEQ;
    size_t i = (size_t)blockIdx.x * 256 + threadIdx.x;
    if (i >= MT * FC_PAD2) return;
    int col = (int)(i & (FC_PAD2 - 1));
    size_t row = i >> 7;
    float v = 0.f;
    if (col < FC_PAD) {
        size_t idx = row * FC_PAD + col;
        const size_t st = MT * FC_PAD;
        v = P[idx] + P[idx + st] + P[idx + 2 * st] + P[idx + 3 * st] + bcat[col];
        v = fmaxf(v, 0.f);
    }
    feats[i] = f2h(v);
}

// x2_h [8][2048][768] -> x2t [8][768][2048]
__global__ void transpose_f16_kernel(const ushort_t* __restrict__ in, ushort_t* __restrict__ out) {
    __shared__ ushort_t tile[32][40];
    int b = blockIdx.z;
    int s0 = blockIdx.x * 32, d0 = blockIdx.y * 32;
    int tx = threadIdx.x & 31, ty = threadIdx.x >> 5;   // 32 x 8
    const ushort_t* inb = in + (size_t)b * SEQ * D_MODEL;
    ushort_t* outb = out + (size_t)b * D_MODEL * SEQ;
    #pragma unroll
    for (int i = 0; i < 4; ++i)
        tile[ty + i * 8][tx] = inb[(size_t)(s0 + ty + i * 8) * D_MODEL + d0 + tx];
    __syncthreads();
    #pragma unroll
    for (int i = 0; i < 4; ++i)
        outb[(size_t)(d0 + ty + i * 8) * SEQ + s0 + tx] = tile[tx][ty + i * 8];
}

// rowbias[b,t] = x2[b,t,:] . bias_v   (fp32)
__global__ void rowbias_kernel(const float* __restrict__ x2, const float* __restrict__ bias_v,
                               float* __restrict__ rowbias) {
    int row = blockIdx.x;
    const float* xr = x2 + (size_t)row * D_MODEL;
    float s = 0.f;
    for (int c = threadIdx.x; c < D_MODEL; c += 256) s += xr[c] * bias_v[c];
    for (int off = 32; off > 0; off >>= 1) s += __shfl_down(s, off);
    __shared__ float red[4];
    int lane = threadIdx.x & 63, w = threadIdx.x >> 6;
    if (lane == 0) red[w] = s;
    __syncthreads();
    if (threadIdx.x == 0) rowbias[row] = red[0] + red[1] + red[2] + red[3];
}

// ---------------- fp16 MFMA GEMM, BK=64, 128B LDS rows + XOR slot swizzle ----------------
// C[M,N] = epilogue( A' @ B'^T ); A' [M][K] fp16, B' [N][K] fp16 (N-major).
// 4 waves (2x2), wave tile 64x64. LDS rows: 64 elems (8 x 16B slots),
// slot ^= (row&7) folded into the GLOBAL source address (rule #21).
// AMODE: 0 plain, 1 im2col(x2_h, VGPR-staged), 2 concat(A|A2, stride 768)
// KSPLIT: blockIdx.z = K-chunk; APTR: A base = ap.p[z]
// MAP: 0 3D grid; 1 lin->{z=lin%ZM (XCD pin), bx=t%GX, by=t/GX}; 2 lin->{xcd A-slice}
// SMEPI: tile-softmax epilogue — writes P'=exp(S+bias-m_tile) fp16 to ap.p[z],
//        and per-(row,tile) stats m,l to smw/slw. Requires TM=TN=128, full tiles.
// ASCALE: PV mode — prologue builds alpha[16][128] from stats; A-fragments scaled.
template<int TM, int TN, int AMODE, int ACT, int HASBIAS, int HASADD,
         int OUTMODE, int KSPLIT, int APTR, int MAP, int ZM, int GX, int GY,
         int SMEPI, int ASCALE>
__global__ __launch_bounds__(256, 3)
void mfma_gemm(const ushort_t* __restrict__ A, const ushort_t* __restrict__ A2,
               const ushort_t* __restrict__ B, const float* __restrict__ bias,
               const ushort_t* __restrict__ addsrc,
               float* __restrict__ Cf, ushort_t* __restrict__ Ch,
               Ptr8 ap, float* __restrict__ smw, float* __restrict__ slw,
               int M, int N, int K, int lda, int ldb, int ldc,
               size_t sA, size_t sB, size_t sBias, size_t sC) {
    constexpr int WM = TM / 2, WN = TN / 2, FM = WM / 16, FN = WN / 16;
    __shared__ __align__(16) ushort_t As_[TM * 64];
    __shared__ __align__(16) ushort_t Bs_[TN * 64];
    __shared__ float pmS[SMEPI ? 4 : 1][SMEPI ? 64 : 1];
    __shared__ float msS[SMEPI ? 128 : 1];
    __shared__ float plS[SMEPI ? 4 : 1][SMEPI ? 64 : 1];
    __shared__ float alS[ASCALE ? 16 : 1][ASCALE ? 128 : 1];

    int bx, by, z;
    if (MAP == 1) {
        int lin = blockIdx.x;
        z = lin % ZM;
        int t = lin / ZM;
        bx = t % GX;
        by = t / GX;
    } else if (MAP == 2) {
        int lin = blockIdx.x;
        int xcd = lin & 7;
        int t = lin >> 3;
        by = t % GY;
        bx = xcd * (GX / 8) + t / GY;
        z = 0;
    } else {
        bx = blockIdx.x; by = blockIdx.y; z = blockIdx.z;
    }

    const int kb = KSPLIT ? z * K : 0;
    const ushort_t* Ab = APTR ? ap.p[z] : (A + (KSPLIT ? 0 : (size_t)z * sA));
    const ushort_t* Bb = B + (KSPLIT ? 0 : (size_t)z * sB);
    if (HASBIAS) bias += (size_t)z * sBias;
    if (HASADD) addsrc += (size_t)z * sC;
    if (OUTMODE == 0) Cf += (size_t)z * sC;
    else if (!SMEPI) Ch += (size_t)z * sC;

    const int m0 = bx * TM;
    const int n0 = by * TN;
    const int tid = threadIdx.x;
    const int lane = tid & 63;
    const int wave = tid >> 6;
    const int wm = (wave >> 1) * WM, wn = (wave & 1) * WN;
    const int r16 = lane & 15, kq = lane >> 4;
    const int srow = tid >> 3;          // 0..31
    const int slot = tid & 7;           // 16B slot (LDS-linear)

    // ---- ASCALE prologue: alpha[tile][row] from stats ----
    if (ASCALE) {
        if (tid < 128) {
            int row = tid;
            int gm = m0 + row;
            float mt[16];
            float mg = -3.0e38f;
            #pragma unroll
            for (int t = 0; t < 16; ++t) {
                mt[t] = smw[((size_t)z * 16 + t) * SEQ + gm];
                mg = fmaxf(mg, mt[t]);
            }
            float lg = 0.f;
            #pragma unroll
            for (int t = 0; t < 16; ++t) {
                float e = __expf(mt[t] - mg);
                lg += slw[((size_t)z * 16 + t) * SEQ + gm] * e;
                alS[t][row] = e;
            }
            float inv = 1.f / lg;
            #pragma unroll
            for (int t = 0; t < 16; ++t) alS[t][row] *= inv;
        }
        __syncthreads();
    }

    f32x4 acc[FM][FN];
    #pragma unroll
    for (int i = 0; i < FM; ++i)
        #pragma unroll
        for (int j = 0; j < FN; ++j) acc[i][j] = (f32x4){0.f, 0.f, 0.f, 0.f};

    const u16x8 zv = {0, 0, 0, 0, 0, 0, 0, 0};

    for (int k0 = 0; k0 < K; k0 += 64) {
        // ---- stage A ----
        #pragma unroll
        for (int i = 0; i < TM / 32; ++i) {
            int row = i * 32 + srow;
            int gm = m0 + row;
            int xs = slot ^ (row & 7);
            if (AMODE == 1) {
                int gkk = kb + k0 + xs * 8;
                int t = gkk / D_MODEL, d = gkk - t * D_MODEL;
                int s = (gm & (SEQ - 1)) + t - 3;
                int bb = gm >> 11;
                u16x8 v = (s >= 0 && s < SEQ) ? *(const u16x8*)(Ab + ((size_t)(bb * SEQ + s)) * lda + d) : zv;
                *(u16x8*)&As_[(size_t)row * 64 + slot * 8] = v;
            } else {
                const ushort_t* src;
                if (AMODE == 2) {
                    int gk = k0 + xs * 8;
                    src = (gk < D_MODEL) ? Ab + (size_t)gm * D_MODEL + gk
                                         : A2 + (size_t)gm * D_MODEL + (gk - D_MODEL);
                } else {
                    int gk = kb + k0 + xs * 8;
                    src = Ab + (size_t)gm * lda + gk;
                }
                gload16(src, &As_[(size_t)(i * 32 + wave * 8) * 64]);
            }
        }
        // ---- stage B ----
        #pragma unroll
        for (int i = 0; i < TN / 32; ++i) {
            int row = i * 32 + srow;
            int gn = n0 + row;
            int xs = slot ^ (row & 7);
            int gk = kb + k0 + xs * 8;
            gload16(Bb + (size_t)gn * ldb + gk, &Bs_[(size_t)(i * 32 + wave * 8) * 64]);
        }
        __syncthreads();

        f16x8 ah[FM][2], bh[FN][2];
        #pragma unroll
        for (int mi = 0; mi < FM; ++mi) {
            int row = wm + mi * 16 + r16;
            #pragma unroll
            for (int kk = 0; kk < 2; ++kk)
                ah[mi][kk] = *(const f16x8*)&As_[(size_t)row * 64 + (((kk * 4 + kq) ^ (row & 7)) * 8)];
        }
        if (ASCALE) {
            const int kt = k0 >> 7;   // 128-col stats tile (kb==0 in PV)
            #pragma unroll
            for (int mi = 0; mi < FM; ++mi) {
                half_t s = (half_t)alS[kt][wm + mi * 16 + r16];
                ah[mi][0] = ah[mi][0] * s;
                ah[mi][1] = ah[mi][1] * s;
            }
        }
        #pragma unroll
        for (int ni = 0; ni < FN; ++ni) {
            int row = wn + ni * 16 + r16;
            #pragma unroll
            for (int kk = 0; kk < 2; ++kk)
                bh[ni][kk] = *(const f16x8*)&Bs_[(size_t)row * 64 + (((kk * 4 + kq) ^ (row & 7)) * 8)];
        }
        #pragma unroll
        for (int kk = 0; kk < 2; ++kk)
            #pragma unroll
            for (int mi = 0; mi < FM; ++mi)
                #pragma unroll
                for (int ni = 0; ni < FN; ++ni)
                    acc[mi][ni] = __builtin_amdgcn_mfma_f32_16x16x32_f16(ah[mi][kk], bh[ni][kk], acc[mi][ni], 0, 0, 0);
        __syncthreads();
    }

    if (SMEPI) {
        // ---- tile-softmax epilogue (TM=TN=128, full tiles) ----
        // 1) add column bias; per-lane row-max over ni
        float pmax[FM][4];
        #pragma unroll
        for (int mi = 0; mi < FM; ++mi)
            #pragma unroll
            for (int r = 0; r < 4; ++r) {
                float mx = -3.0e38f;
                #pragma unroll
                for (int ni = 0; ni < FN; ++ni) {
                    float v = acc[mi][ni][r] + bias[n0 + wn + ni * 16 + r16];
                    acc[mi][ni][r] = v;
                    mx = fmaxf(mx, v);
                }
                // butterfly max over the 16 column-lanes (low 4 lane bits)
                mx = fmaxf(mx, __shfl_xor(mx, 1));
                mx = fmaxf(mx, __shfl_xor(mx, 2));
                mx = fmaxf(mx, __shfl_xor(mx, 4));
                mx = fmaxf(mx, __shfl_xor(mx, 8));
                pmax[mi][r] = mx;
            }
        if (r16 == 0) {
            #pragma unroll
            for (int mi = 0; mi < FM; ++mi)
                #pragma unroll
                for (int r = 0; r < 4; ++r)
                    pmS[wave][mi * 16 + kq * 4 + r] = pmax[mi][r];
        }
        __syncthreads();
        if (tid < 128) {                      // combine wn-halves
            int rl = tid & 63, grp = tid >> 6;
            msS[grp * 64 + rl] = fmaxf(pmS[grp * 2][rl], pmS[grp * 2 + 1][rl]);
        }
        __syncthreads();
        // 2) exp(S - m_row), per-lane row-sum
        #pragma unroll
        for (int mi = 0; mi < FM; ++mi)
            #pragma unroll
            for (int r = 0; r < 4; ++r) {
                float mrow = msS[wm + mi * 16 + kq * 4 + r];
                float s = 0.f;
                #pragma unroll
                for (int ni = 0; ni < FN; ++ni) {
                    float e = __expf(acc[mi][ni][r] - mrow);
                    acc[mi][ni][r] = e;
                    s += e;
                }
                s += __shfl_xor(s, 1);
                s += __shfl_xor(s, 2);
                s += __shfl_xor(s, 4);
                s += __shfl_xor(s, 8);
                pmax[mi][r] = s;              // reuse reg
            }
        if (r16 == 0) {
            #pragma unroll
            for (int mi = 0; mi < FM; ++mi)
                #pragma unroll
                for (int r = 0; r < 4; ++r)
                    plS[wave][mi * 16 + kq * 4 + r] = pmax[mi][r];
        }
        __syncthreads();
        if (tid < 128) {                      // write stats
            int rl = tid & 63, grp = tid >> 6;
            int row = grp * 64 + rl;
            float l2 = plS[grp * 2][rl] + plS[grp * 2 + 1][rl];
            size_t si = ((size_t)z * 16 + by) * SEQ + (m0 + row);
            smw[si] = msS[row];
            slw[si] = l2;
        }
        // 3) write P' fp16 to this batch's segment
        ushort_t* Co = (ushort_t*)ap.p[z];
        #pragma unroll
        for (int mi = 0; mi < FM; ++mi)
            #pragma unroll
            for (int ni = 0; ni < FN; ++ni)
                #pragma unroll
                for (int r = 0; r < 4; ++r) {
                    int gm = m0 + wm + mi * 16 + kq * 4 + r;
                    int gn = n0 + wn + ni * 16 + r16;
                    Co[(size_t)gm * SEQ + gn] = f2h(acc[mi][ni][r]);
                }
        return;
    }

    // ---- standard epilogue: C/D layout col = lane&15, row = (lane>>4)*4 + r ----
    #pragma unroll
    for (int mi = 0; mi < FM; ++mi)
        #pragma unroll
        for (int ni = 0; ni < FN; ++ni)
            #pragma unroll
            for (int r = 0; r < 4; ++r) {
                int gm = m0 + wm + mi * 16 + kq * 4 + r;
                int gn = n0 + wn + ni * 16 + r16;
                if (gn >= N) continue;
                float v = acc[mi][ni][r];
                if (HASBIAS) v += bias[gn];
                if (ACT == 1) v = fmaxf(v, 0.f);
                else if (ACT == 2) v = fast_tanh(v);
                if (HASADD) v += h2f(addsrc[(size_t)gm * ldc + gn]);
                size_t idx = (size_t)gm * ldc + gn;
                if (OUTMODE == 0) Cf[idx] = v;
                else Ch[idx] = f2h(v);
            }
}

extern "C" void kernel_launch(void* const* d_in, const int* in_sizes, int n_in,
                              void* d_out, int out_size, void* d_ws, size_t ws_size,
                              hipStream_t stream) {
    const float* x1     = (const float*)d_in[0];
    const float* x2     = (const float*)d_in[1];
    const float* w7     = (const float*)d_in[2];
    const float* b7     = (const float*)d_in[3];
    const float* w5     = (const float*)d_in[4];
    const float* b5     = (const float*)d_in[5];
    const float* w3     = (const float*)d_in[6];
    const float* b3     = (const float*)d_in[7];
    const float* U      = (const float*)d_in[8];
    const float* bias_v = (const float*)d_in[9];
    const float* fc_w   = (const float*)d_in[10];
    const float* fc_b   = (const float*)d_in[11];
    const float* fcx_w  = (const float*)d_in[12];
    const float* fcx_b  = (const float*)d_in[13];
    float* out = (float*)d_out;

    const size_t MT = (size_t)BATCH * SEQ;      // 16384
    const size_t NE = MT * D_MODEL;             // 12.58M
    const size_t NEb = (size_t)SEQ * D_MODEL;   // 1.57M elems per batch
    const size_t SEGSZ = (size_t)SEQ * SEQ;     // 4.19M elems (8.39MB fp16 per P' batch)

    char* p = (char*)d_ws;
    auto alloc = [&](size_t bytes) -> char* {
        char* r = p;
        p += (bytes + 255) & ~(size_t)255;
        return r;
    };
    ushort_t* x1_h   = (ushort_t*)alloc(NE * 2);
    ushort_t* x2_h   = (ushort_t*)alloc(NE * 2);
    ushort_t* x2t    = (ushort_t*)alloc(NE * 2);
    ushort_t* y1     = (ushort_t*)alloc(NE * 2);
    ushort_t* xcnn   = (ushort_t*)alloc(NE * 2);
    float*    convp  = (float*)   alloc(MT * FC_PAD * 4 * 4); // 25.17MB; dead after reduce
    ushort_t* feats  = (ushort_t*)alloc(MT * FC_PAD2 * 2);
    ushort_t* Wt     = (ushort_t*)alloc((size_t)FC_PAD2 * KCOMB * 2);
    ushort_t* fc_wt  = (ushort_t*)alloc((size_t)D_MODEL * FC_PAD2 * 2);
    ushort_t* fcx_wt = (ushort_t*)alloc((size_t)D_MODEL * 2 * D_MODEL * 2);
    ushort_t* Ut     = (ushort_t*)alloc((size_t)D_MODEL * D_MODEL * 2);
    float*    bcat   = (float*)alloc(FC_PAD2 * 4);
    float*    rbias  = (float*)alloc(MT * 4);
    float*    smS    = (float*)alloc((size_t)BATCH * 16 * SEQ * 4);  // tile row-max
    float*    slS    = (float*)alloc((size_t)BATCH * 16 * SEQ * 4);  // tile row-sum

    // P' segments (8 x 8.39MB): 3 in convp (exactly 25.17MB, dead after conv_reduce),
    // 5 in d_out (41.9MB <= 50.3MB, dead until the final GEMM overwrites it).
    ushort_t* dob = (ushort_t*)d_out;
    Ptr8 ap;
    ap.p[0] = (ushort_t*)convp;
    ap.p[1] = (ushort_t*)convp + SEGSZ;
    ap.p[2] = (ushort_t*)convp + 2 * SEGSZ;
    ap.p[3] = dob;
    ap.p[4] = dob + SEGSZ;
    ap.p[5] = dob + 2 * SEGSZ;
    ap.p[6] = dob + 3 * SEGSZ;
    ap.p[7] = dob + 4 * SEGSZ;
    Ptr8 apz = {};

    const int T = 256;
    auto blk = [](size_t n) { return dim3((unsigned)((n + 255) / 256)); };

    // ---- prep ----
    build_wcomb_kernel<<<blk((size_t)FC_PAD2 * KCOMB), T, 0, stream>>>(w7, b7, w5, b5, w3, b3, Wt, bcat);
    convert_fc_kernel<<<blk((size_t)D_MODEL * FC_PAD2), T, 0, stream>>>(fc_w, fc_wt);
    convert_f16_kernel<<<blk((size_t)D_MODEL * 2 * D_MODEL / 4), T, 0, stream>>>(fcx_w, fcx_wt, (size_t)D_MODEL * 2 * D_MODEL / 4);
    convert_ut_kernel<<<blk((size_t)D_MODEL * D_MODEL), T, 0, stream>>>(U, Ut);
    convert_f16_kernel<<<blk(NE / 4), T, 0, stream>>>(x1, x1_h, NE / 4);
    convert_f16_kernel<<<blk(NE / 4), T, 0, stream>>>(x2, x2_h, NE / 4);
    transpose_f16_kernel<<<dim3(SEQ / 32, D_MODEL / 32, BATCH), T, 0, stream>>>(x2_h, x2t);
    rowbias_kernel<<<dim3((unsigned)MT), T, 0, stream>>>(x2, bias_v, rbias);

    // ---- conv: 4 K-chunks -> fp32 partials, then reduce+bias+relu -> feats ----
    mfma_gemm<64, 128, 1, 0, 0, 0, 0, 1, 0, 0, 1, 1, 1, 0, 0><<<dim3(MT / 64, 1, 4), T, 0, stream>>>(
        x2_h, nullptr, Wt, nullptr, nullptr,
        convp, nullptr, apz, nullptr, nullptr,
        (int)MT, FC_PAD, KCHUNK, D_MODEL, KCOMB, FC_PAD,
        0, 0, 0, MT * FC_PAD);
    conv_reduce_kernel<<<blk(MT * FC_PAD2), T, 0, stream>>>(convp, bcat, feats);

    // ---- fc: xcnn = tanh(feats @ fc_w^T + fc_b); MAP2 panel-sliced ----
    mfma_gemm<128, 128, 0, 2, 1, 0, 1, 0, 0, 2, 1, 128, 6, 0, 0><<<dim3(768, 1, 1), T, 0, stream>>>(
        feats, nullptr, fc_wt, fc_b, nullptr,
        nullptr, xcnn, apz, nullptr, nullptr,
        (int)MT, D_MODEL, FC_PAD2, FC_PAD2, FC_PAD2, D_MODEL, 0, 0, 0, 0);

    // ---- y1 = x1 @ U, fp16 out; MAP2 panel-sliced ----
    mfma_gemm<128, 128, 0, 0, 0, 0, 1, 0, 0, 2, 1, 128, 6, 0, 0><<<dim3(768, 1, 1), T, 0, stream>>>(
        x1_h, nullptr, Ut, nullptr, nullptr,
        nullptr, y1, apz, nullptr, nullptr,
        (int)MT, D_MODEL, D_MODEL, D_MODEL, D_MODEL, D_MODEL, 0, 0, 0, 0);

    // ---- scores + tile-softmax, ALL 8 batches, one dispatch; batch = XCD (lin%8) ----
    // P' = exp(S + rowbias - m_tile) fp16 -> segments; (m,l) stats -> smS/slS
    mfma_gemm<128, 128, 0, 0, 1, 0, 1, 0, 0, 1, 8, 16, 16, 1, 0><<<dim3(2048, 1, 1), T, 0, stream>>>(
        y1, nullptr, x2_h, rbias, nullptr,
        nullptr, nullptr, ap, smS, slS,
        SEQ, SEQ, D_MODEL, D_MODEL, D_MODEL, SEQ,
        NEb, NEb, SEQ, 0);

    // ---- PV with softmax fix-up: x = xcnn + tanh(sum_t alpha_t P'_t @ V_t) ----
    mfma_gemm<128, 128, 0, 2, 0, 1, 1, 0, 1, 1, 8, 16, 6, 0, 1><<<dim3(768, 1, 1), T, 0, stream>>>(
        nullptr, nullptr, x2t, nullptr,
        xcnn,
        nullptr, xcnn, ap, smS, slS,
        SEQ, D_MODEL, SEQ, SEQ, SEQ, D_MODEL,
        0, NEb, 0, NEb);

    // ---- final: out = concat(x1, x) @ fcx_w^T + fcx_b; MAP2 panel-sliced ----
    mfma_gemm<128, 128, 2, 0, 1, 0, 0, 0, 0, 2, 1, 128, 6, 0, 0><<<dim3(768, 1, 1), T, 0, stream>>>(
        x1_h, xcnn, fcx_wt, fcx_b, nullptr,
        out, nullptr, apz, nullptr, nullptr,
        (int)MT, D_MODEL, 2 * D_MODEL, D_MODEL, 2 * D_MODEL, D_MODEL, 0, 0, 0, 0);
}

// Round 9
// 339.975 us; speedup vs baseline: 17.8715x; 1.0032x over previous
//
#include <hip/hip_runtime.h>
#include <cmath>

#define D_MODEL 768
#define SEQ 2048
#define BATCH 8
#define FC_PAD 96
#define FC_PAD2 128
#define KCOMB (7 * D_MODEL)   // 5376
#define KCHUNK 2688           // KCOMB/2

typedef unsigned short ushort_t;
typedef _Float16 half_t;
typedef __attribute__((ext_vector_type(8))) _Float16 f16x8;
typedef __attribute__((ext_vector_type(8))) unsigned short u16x8;
typedef __attribute__((ext_vector_type(4))) unsigned short u16x4;
typedef __attribute__((ext_vector_type(4))) float f32x4;

struct Ptr8 { const ushort_t* p[8]; };

__device__ __forceinline__ ushort_t f2h(float x) {
    half_t h = (half_t)x;
    return __builtin_bit_cast(ushort_t, h);
}
__device__ __forceinline__ float h2f(ushort_t u) {
    return (float)__builtin_bit_cast(half_t, u);
}
__device__ __forceinline__ float fast_tanh(float x) {
    float a = fabsf(x);
    float t = __expf(-2.f * a);
    float r = (1.f - t) / (1.f + t);
    return copysignf(r, x);
}
__device__ __forceinline__ void gload16(const ushort_t* g, ushort_t* lbase) {
    __builtin_amdgcn_global_load_lds((const __attribute__((address_space(1))) void*)g,
                                     (__attribute__((address_space(3))) void*)lbase,
                                     16, 0, 0);
}

// ---------------- prep kernels ----------------
__global__ void convert_f16_kernel(const float* __restrict__ src, ushort_t* __restrict__ dst, size_t n4) {
    size_t i = (size_t)blockIdx.x * 256 + threadIdx.x;
    if (i >= n4) return;
    f32x4 x = *(const f32x4*)(src + i * 4);
    u16x4 h;
    #pragma unroll
    for (int j = 0; j < 4; ++j) h[j] = f2h(x[j]);
    *(u16x4*)(dst + i * 4) = h;
}

// fc_w [768][90] -> fc_wt fp16 [768][128] zero-padded
__global__ void convert_fc_kernel(const float* __restrict__ src, ushort_t* __restrict__ dst) {
    int i = blockIdx.x * 256 + threadIdx.x;
    if (i >= D_MODEL * FC_PAD2) return;
    int o = i / FC_PAD2, j = i - o * FC_PAD2;
    dst[i] = (j < 90) ? f2h(src[o * 90 + j]) : 0;
}

// U [768][768] -> Ut [n][k] = fp16(U[k][n])
__global__ void convert_ut_kernel(const float* __restrict__ U, ushort_t* __restrict__ dst) {
    int i = blockIdx.x * 256 + threadIdx.x;
    if (i >= D_MODEL * D_MODEL) return;
    int n = i / D_MODEL, k = i - n * D_MODEL;
    dst[i] = f2h(U[(size_t)k * D_MODEL + n]);
}

// combined conv weight, fp16, [128][5376]; rows 90..127 zero
__global__ void build_wcomb_kernel(const float* __restrict__ w7, const float* __restrict__ b7,
                                   const float* __restrict__ w5, const float* __restrict__ b5,
                                   const float* __restrict__ w3, const float* __restrict__ b3,
                                   ushort_t* __restrict__ Wt, float* __restrict__ bcat) {
    int idx = blockIdx.x * 256 + threadIdx.x;
    const int total = FC_PAD2 * KCOMB;
    if (idx < total) {
        int o = idx / KCOMB, k = idx - o * KCOMB;
        int t = k / D_MODEL, d = k - t * D_MODEL;
        float v = 0.f;
        if (o < 40) {
            v = w7[(size_t)o * (D_MODEL * 7) + d * 7 + t];
        } else if (o < 70) {
            int t5 = t - 1;
            if (t5 >= 0 && t5 < 5) v = w5[(size_t)(o - 40) * (D_MODEL * 5) + d * 5 + t5];
        } else if (o < 90) {
            int t3 = t - 2;
            if (t3 >= 0 && t3 < 3) v = w3[(size_t)(o - 70) * (D_MODEL * 3) + d * 3 + t3];
        }
        Wt[idx] = f2h(v);
    }
    if (idx < FC_PAD2) {
        float bv = 0.f;
        if (idx < 40) bv = b7[idx];
        else if (idx < 70) bv = b5[idx - 40];
        else if (idx < 90) bv = b3[idx - 70];
        bcat[idx] = bv;
    }
}

// sum 2 conv partials + bias + relu -> feats fp16 [16384][128] (cols 96.. zero)
__global__ void conv_reduce_kernel(const float* __restrict__ P, const float* __restrict__ bcat,
                                   ushort_t* __restrict__ feats) {
    const size_t MT = (size_t)BATCH * SEQ;
    size_t i = (size_t)blockIdx.x * 256 + threadIdx.x;
    if (i >= MT * FC_PAD2) return;
    int col = (int)(i & (FC_PAD2 - 1));
    size_t row = i >> 7;
    float v = 0.f;
    if (col < FC_PAD) {
        size_t idx = row * FC_PAD + col;
        const size_t st = MT * FC_PAD;
        v = P[idx] + P[idx + st] + bcat[col];
        v = fmaxf(v, 0.f);
    }
    feats[i] = f2h(v);
}

// x2_h [8][2048][768] -> x2t [8][768][2048]
__global__ void transpose_f16_kernel(const ushort_t* __restrict__ in, ushort_t* __restrict__ out) {
    __shared__ ushort_t tile[32][40];
    int b = blockIdx.z;
    int s0 = blockIdx.x * 32, d0 = blockIdx.y * 32;
    int tx = threadIdx.x & 31, ty = threadIdx.x >> 5;   // 32 x 8
    const ushort_t* inb = in + (size_t)b * SEQ * D_MODEL;
    ushort_t* outb = out + (size_t)b * D_MODEL * SEQ;
    #pragma unroll
    for (int i = 0; i < 4; ++i)
        tile[ty + i * 8][tx] = inb[(size_t)(s0 + ty + i * 8) * D_MODEL + d0 + tx];
    __syncthreads();
    #pragma unroll
    for (int i = 0; i < 4; ++i)
        outb[(size_t)(d0 + ty + i * 8) * SEQ + s0 + tx] = tile[tx][ty + i * 8];
}

// ---------------- fp16 MFMA GEMM, BK=64, 128B LDS rows + XOR slot swizzle ----------------
// C[M,N] = epilogue( A' @ B'^T ); A' [M][K] fp16, B' [N][K] fp16 (N-major).
// 4 waves (2x2), wave tile 64x64. LDS rows: 64 elems (8 x 16B slots),
// slot ^= (row&7) folded into the GLOBAL source address (rule #21).
// AMODE: 0 plain, 1 im2col(x2_h, VGPR-staged), 2 concat(A|A2, stride 768)
// KSPLIT: blockIdx.z = K-chunk; APTR: A base = ap.p[z]
// MAP: 0 3D grid; 1 lin->{z=lin%ZM, bx=t%GX, by=t/GX}; 2 lin->{xcd A-slice, by fast};
//      3 lin->{z=lin%ZM, by=t%GY, bx=t/GY}  (by fastest: A-panel L2-hot)
// SMEPI: tile-softmax epilogue — writes P'=exp(S[+bias]-m_tile) fp16 to ap.p[z],
//        per-(row,tile) stats m,l -> smw/slw. Requires TM=TN=128, full tiles.
// ASCALE: PV mode — prologue builds fp16 alpha[16][128] from stats; A-frags scaled.
template<int TM, int TN, int AMODE, int ACT, int HASBIAS, int HASADD,
         int OUTMODE, int KSPLIT, int APTR, int MAP, int ZM, int GX, int GY,
         int SMEPI, int ASCALE>
__global__ __launch_bounds__(256, 3)
void mfma_gemm(const ushort_t* __restrict__ A, const ushort_t* __restrict__ A2,
               const ushort_t* __restrict__ B, const float* __restrict__ bias,
               const ushort_t* __restrict__ addsrc,
               float* __restrict__ Cf, ushort_t* __restrict__ Ch,
               Ptr8 ap, float* __restrict__ smw, float* __restrict__ slw,
               int M, int N, int K, int lda, int ldb, int ldc,
               size_t sA, size_t sB, size_t sBias, size_t sC) {
    constexpr int WM = TM / 2, WN = TN / 2, FM = WM / 16, FN = WN / 16;
    __shared__ __align__(16) ushort_t As_[TM * 64];
    __shared__ __align__(16) ushort_t Bs_[TN * 64];
    __shared__ float pmS[SMEPI ? 4 : 1][SMEPI ? 64 : 1];
    __shared__ float msS[SMEPI ? 128 : 1];
    __shared__ float plS[SMEPI ? 4 : 1][SMEPI ? 64 : 1];
    __shared__ ushort_t alS[ASCALE ? 16 : 1][ASCALE ? 128 : 1];   // fp16 alpha

    int bx, by, z;
    if (MAP == 1) {
        int lin = blockIdx.x;
        z = lin % ZM;
        int t = lin / ZM;
        bx = t % GX;
        by = t / GX;
    } else if (MAP == 2) {
        int lin = blockIdx.x;
        int xcd = lin & 7;
        int t = lin >> 3;
        by = t % GY;
        bx = xcd * (GX / 8) + t / GY;
        z = 0;
    } else if (MAP == 3) {
        int lin = blockIdx.x;
        z = lin % ZM;
        int t = lin / ZM;
        by = t % GY;
        bx = t / GY;
    } else {
        bx = blockIdx.x; by = blockIdx.y; z = blockIdx.z;
    }

    const int kb = KSPLIT ? z * K : 0;
    const ushort_t* Ab = APTR ? ap.p[z] : (A + (KSPLIT ? 0 : (size_t)z * sA));
    const ushort_t* Bb = B + (KSPLIT ? 0 : (size_t)z * sB);
    if (HASBIAS) bias += (size_t)z * sBias;
    if (HASADD) addsrc += (size_t)z * sC;
    if (OUTMODE == 0) Cf += (size_t)z * sC;
    else if (!SMEPI) Ch += (size_t)z * sC;

    const int m0 = bx * TM;
    const int n0 = by * TN;
    const int tid = threadIdx.x;
    const int lane = tid & 63;
    const int wave = tid >> 6;
    const int wm = (wave >> 1) * WM, wn = (wave & 1) * WN;
    const int r16 = lane & 15, kq = lane >> 4;
    const int srow = tid >> 3;          // 0..31
    const int slot = tid & 7;           // 16B slot (LDS-linear)

    // ---- ASCALE prologue: fp16 alpha[tile][row] from stats ----
    if (ASCALE) {
        if (tid < 128) {
            int row = tid;
            int gm = m0 + row;
            float mt[16], al[16];
            float mg = -3.0e38f;
            #pragma unroll
            for (int t = 0; t < 16; ++t) {
                mt[t] = smw[((size_t)z * 16 + t) * SEQ + gm];
                mg = fmaxf(mg, mt[t]);
            }
            float lg = 0.f;
            #pragma unroll
            for (int t = 0; t < 16; ++t) {
                float e = __expf(mt[t] - mg);
                lg += slw[((size_t)z * 16 + t) * SEQ + gm] * e;
                al[t] = e;
            }
            float inv = 1.f / lg;
            #pragma unroll
            for (int t = 0; t < 16; ++t) alS[t][row] = f2h(al[t] * inv);
        }
        __syncthreads();
    }

    f32x4 acc[FM][FN];
    #pragma unroll
    for (int i = 0; i < FM; ++i)
        #pragma unroll
        for (int j = 0; j < FN; ++j) acc[i][j] = (f32x4){0.f, 0.f, 0.f, 0.f};

    const u16x8 zv = {0, 0, 0, 0, 0, 0, 0, 0};

    for (int k0 = 0; k0 < K; k0 += 64) {
        // ---- stage A ----
        #pragma unroll
        for (int i = 0; i < TM / 32; ++i) {
            int row = i * 32 + srow;
            int gm = m0 + row;
            int xs = slot ^ (row & 7);
            if (AMODE == 1) {
                int gkk = kb + k0 + xs * 8;
                int t = gkk / D_MODEL, d = gkk - t * D_MODEL;
                int s = (gm & (SEQ - 1)) + t - 3;
                int bb = gm >> 11;
                u16x8 v = (s >= 0 && s < SEQ) ? *(const u16x8*)(Ab + ((size_t)(bb * SEQ + s)) * lda + d) : zv;
                *(u16x8*)&As_[(size_t)row * 64 + slot * 8] = v;
            } else {
                const ushort_t* src;
                if (AMODE == 2) {
                    int gk = k0 + xs * 8;
                    src = (gk < D_MODEL) ? Ab + (size_t)gm * D_MODEL + gk
                                         : A2 + (size_t)gm * D_MODEL + (gk - D_MODEL);
                } else {
                    int gk = kb + k0 + xs * 8;
                    src = Ab + (size_t)gm * lda + gk;
                }
                gload16(src, &As_[(size_t)(i * 32 + wave * 8) * 64]);
            }
        }
        // ---- stage B ----
        #pragma unroll
        for (int i = 0; i < TN / 32; ++i) {
            int row = i * 32 + srow;
            int gn = n0 + row;
            int xs = slot ^ (row & 7);
            int gk = kb + k0 + xs * 8;
            gload16(Bb + (size_t)gn * ldb + gk, &Bs_[(size_t)(i * 32 + wave * 8) * 64]);
        }
        __syncthreads();

        f16x8 ah[FM][2], bh[FN][2];
        #pragma unroll
        for (int mi = 0; mi < FM; ++mi) {
            int row = wm + mi * 16 + r16;
            #pragma unroll
            for (int kk = 0; kk < 2; ++kk)
                ah[mi][kk] = *(const f16x8*)&As_[(size_t)row * 64 + (((kk * 4 + kq) ^ (row & 7)) * 8)];
        }
        if (ASCALE) {
            const int kt = k0 >> 7;   // 128-col stats tile (kb==0 in PV)
            #pragma unroll
            for (int mi = 0; mi < FM; ++mi) {
                half_t s = __builtin_bit_cast(half_t, alS[kt][wm + mi * 16 + r16]);
                ah[mi][0] = ah[mi][0] * s;
                ah[mi][1] = ah[mi][1] * s;
            }
        }
        #pragma unroll
        for (int ni = 0; ni < FN; ++ni) {
            int row = wn + ni * 16 + r16;
            #pragma unroll
            for (int kk = 0; kk < 2; ++kk)
                bh[ni][kk] = *(const f16x8*)&Bs_[(size_t)row * 64 + (((kk * 4 + kq) ^ (row & 7)) * 8)];
        }
        #pragma unroll
        for (int kk = 0; kk < 2; ++kk)
            #pragma unroll
            for (int mi = 0; mi < FM; ++mi)
                #pragma unroll
                for (int ni = 0; ni < FN; ++ni)
                    acc[mi][ni] = __builtin_amdgcn_mfma_f32_16x16x32_f16(ah[mi][kk], bh[ni][kk], acc[mi][ni], 0, 0, 0);
        __syncthreads();
    }

    if (SMEPI) {
        // ---- tile-softmax epilogue (TM=TN=128, full tiles) ----
        float pmax[FM][4];
        #pragma unroll
        for (int mi = 0; mi < FM; ++mi)
            #pragma unroll
            for (int r = 0; r < 4; ++r) {
                float mx = -3.0e38f;
                #pragma unroll
                for (int ni = 0; ni < FN; ++ni) {
                    float v = acc[mi][ni][r];
                    if (HASBIAS) { v += bias[n0 + wn + ni * 16 + r16]; acc[mi][ni][r] = v; }
                    mx = fmaxf(mx, v);
                }
                mx = fmaxf(mx, __shfl_xor(mx, 1));
                mx = fmaxf(mx, __shfl_xor(mx, 2));
                mx = fmaxf(mx, __shfl_xor(mx, 4));
                mx = fmaxf(mx, __shfl_xor(mx, 8));
                pmax[mi][r] = mx;
            }
        if (r16 == 0) {
            #pragma unroll
            for (int mi = 0; mi < FM; ++mi)
                #pragma unroll
                for (int r = 0; r < 4; ++r)
                    pmS[wave][mi * 16 + kq * 4 + r] = pmax[mi][r];
        }
        __syncthreads();
        if (tid < 128) {                      // combine wn-halves
            int rl = tid & 63, grp = tid >> 6;
            msS[grp * 64 + rl] = fmaxf(pmS[grp * 2][rl], pmS[grp * 2 + 1][rl]);
        }
        __syncthreads();
        #pragma unroll
        for (int mi = 0; mi < FM; ++mi)
            #pragma unroll
            for (int r = 0; r < 4; ++r) {
                float mrow = msS[wm + mi * 16 + kq * 4 + r];
                float s = 0.f;
                #pragma unroll
                for (int ni = 0; ni < FN; ++ni) {
                    float e = __expf(acc[mi][ni][r] - mrow);
                    acc[mi][ni][r] = e;
                    s += e;
                }
                s += __shfl_xor(s, 1);
                s += __shfl_xor(s, 2);
                s += __shfl_xor(s, 4);
                s += __shfl_xor(s, 8);
                pmax[mi][r] = s;
            }
        if (r16 == 0) {
            #pragma unroll
            for (int mi = 0; mi < FM; ++mi)
                #pragma unroll
                for (int r = 0; r < 4; ++r)
                    plS[wave][mi * 16 + kq * 4 + r] = pmax[mi][r];
        }
        __syncthreads();
        if (tid < 128) {                      // write stats
            int rl = tid & 63, grp = tid >> 6;
            int row = grp * 64 + rl;
            float l2 = plS[grp * 2][rl] + plS[grp * 2 + 1][rl];
            size_t si = ((size_t)z * 16 + by) * SEQ + (m0 + row);
            smw[si] = msS[row];
            slw[si] = l2;
        }
        ushort_t* Co = (ushort_t*)ap.p[z];
        #pragma unroll
        for (int mi = 0; mi < FM; ++mi)
            #pragma unroll
            for (int ni = 0; ni < FN; ++ni)
                #pragma unroll
                for (int r = 0; r < 4; ++r) {
                    int gm = m0 + wm + mi * 16 + kq * 4 + r;
                    int gn = n0 + wn + ni * 16 + r16;
                    Co[(size_t)gm * SEQ + gn] = f2h(acc[mi][ni][r]);
                }
        return;
    }

    // ---- standard epilogue ----
    #pragma unroll
    for (int mi = 0; mi < FM; ++mi)
        #pragma unroll
        for (int ni = 0; ni < FN; ++ni)
            #pragma unroll
            for (int r = 0; r < 4; ++r) {
                int gm = m0 + wm + mi * 16 + kq * 4 + r;
                int gn = n0 + wn + ni * 16 + r16;
                if (gn >= N) continue;
                float v = acc[mi][ni][r];
                if (HASBIAS) v += bias[gn];
                if (ACT == 1) v = fmaxf(v, 0.f);
                else if (ACT == 2) v = fast_tanh(v);
                if (HASADD) v += h2f(addsrc[(size_t)gm * ldc + gn]);
                size_t idx = (size_t)gm * ldc + gn;
                if (OUTMODE == 0) Cf[idx] = v;
                else Ch[idx] = f2h(v);
            }
}

extern "C" void kernel_launch(void* const* d_in, const int* in_sizes, int n_in,
                              void* d_out, int out_size, void* d_ws, size_t ws_size,
                              hipStream_t stream) {
    const float* x1     = (const float*)d_in[0];
    const float* x2     = (const float*)d_in[1];
    const float* w7     = (const float*)d_in[2];
    const float* b7     = (const float*)d_in[3];
    const float* w5     = (const float*)d_in[4];
    const float* b5     = (const float*)d_in[5];
    const float* w3     = (const float*)d_in[6];
    const float* b3     = (const float*)d_in[7];
    const float* U      = (const float*)d_in[8];
    const float* bias_v = (const float*)d_in[9];
    const float* fc_w   = (const float*)d_in[10];
    const float* fc_b   = (const float*)d_in[11];
    const float* fcx_w  = (const float*)d_in[12];
    const float* fcx_b  = (const float*)d_in[13];
    float* out = (float*)d_out;

    const size_t MT = (size_t)BATCH * SEQ;      // 16384
    const size_t NE = MT * D_MODEL;             // 12.58M
    const size_t NEb = (size_t)SEQ * D_MODEL;   // per-batch elems
    const size_t SEGSZ = (size_t)SEQ * SEQ;     // P' batch elems (8.39MB fp16)

    char* p = (char*)d_ws;
    auto alloc = [&](size_t bytes) -> char* {
        char* r = p;
        p += (bytes + 255) & ~(size_t)255;
        return r;
    };
    ushort_t* x1_h   = (ushort_t*)alloc(NE * 2);
    ushort_t* x2_h   = (ushort_t*)alloc(NE * 2);
    ushort_t* x2t    = (ushort_t*)alloc(NE * 2);
    ushort_t* y1     = (ushort_t*)alloc(NE * 2);
    ushort_t* xcnn   = (ushort_t*)alloc(NE * 2);
    float*    convp  = (float*)   alloc(MT * FC_PAD * 4 * 4); // holds 2 partials + 3 P' segs
    ushort_t* feats  = (ushort_t*)alloc(MT * FC_PAD2 * 2);
    ushort_t* Wt     = (ushort_t*)alloc((size_t)FC_PAD2 * KCOMB * 2);
    ushort_t* fc_wt  = (ushort_t*)alloc((size_t)D_MODEL * FC_PAD2 * 2);
    ushort_t* fcx_wt = (ushort_t*)alloc((size_t)D_MODEL * 2 * D_MODEL * 2);
    ushort_t* Ut     = (ushort_t*)alloc((size_t)D_MODEL * D_MODEL * 2);
    float*    bcat   = (float*)alloc(FC_PAD2 * 4);
    float*    smS    = (float*)alloc((size_t)BATCH * 16 * SEQ * 4);  // tile row-max
    float*    slS    = (float*)alloc((size_t)BATCH * 16 * SEQ * 4);  // tile row-sum

    // P' segments (8 x 8.39MB): 3 in convp (25.17MB, dead after conv_reduce),
    // 5 in d_out (41.9MB <= 50.3MB, dead until the final GEMM overwrites it).
    ushort_t* dob = (ushort_t*)d_out;
    Ptr8 ap;
    ap.p[0] = (ushort_t*)convp;
    ap.p[1] = (ushort_t*)convp + SEGSZ;
    ap.p[2] = (ushort_t*)convp + 2 * SEGSZ;
    ap.p[3] = dob;
    ap.p[4] = dob + SEGSZ;
    ap.p[5] = dob + 2 * SEGSZ;
    ap.p[6] = dob + 3 * SEGSZ;
    ap.p[7] = dob + 4 * SEGSZ;
    Ptr8 apz = {};

    const int T = 256;
    auto blk = [](size_t n) { return dim3((unsigned)((n + 255) / 256)); };

    // ---- prep ----
    build_wcomb_kernel<<<blk((size_t)FC_PAD2 * KCOMB), T, 0, stream>>>(w7, b7, w5, b5, w3, b3, Wt, bcat);
    convert_fc_kernel<<<blk((size_t)D_MODEL * FC_PAD2), T, 0, stream>>>(fc_w, fc_wt);
    convert_f16_kernel<<<blk((size_t)D_MODEL * 2 * D_MODEL / 4), T, 0, stream>>>(fcx_w, fcx_wt, (size_t)D_MODEL * 2 * D_MODEL / 4);
    convert_ut_kernel<<<blk((size_t)D_MODEL * D_MODEL), T, 0, stream>>>(U, Ut);
    convert_f16_kernel<<<blk(NE / 4), T, 0, stream>>>(x1, x1_h, NE / 4);
    convert_f16_kernel<<<blk(NE / 4), T, 0, stream>>>(x2, x2_h, NE / 4);
    transpose_f16_kernel<<<dim3(SEQ / 32, D_MODEL / 32, BATCH), T, 0, stream>>>(x2_h, x2t);

    // ---- conv: 2 K-chunks -> fp32 partials, then reduce+bias+relu -> feats ----
    mfma_gemm<64, 128, 1, 0, 0, 0, 0, 1, 0, 0, 1, 1, 1, 0, 0><<<dim3(MT / 64, 1, 2), T, 0, stream>>>(
        x2_h, nullptr, Wt, nullptr, nullptr,
        convp, nullptr, apz, nullptr, nullptr,
        (int)MT, FC_PAD, KCHUNK, D_MODEL, KCOMB, FC_PAD,
        0, 0, 0, MT * FC_PAD);
    conv_reduce_kernel<<<blk(MT * FC_PAD2), T, 0, stream>>>(convp, bcat, feats);

    // ---- fc: xcnn = tanh(feats @ fc_w^T + fc_b); MAP2 panel-sliced ----
    mfma_gemm<128, 128, 0, 2, 1, 0, 1, 0, 0, 2, 1, 128, 6, 0, 0><<<dim3(768, 1, 1), T, 0, stream>>>(
        feats, nullptr, fc_wt, fc_b, nullptr,
        nullptr, xcnn, apz, nullptr, nullptr,
        (int)MT, D_MODEL, FC_PAD2, FC_PAD2, FC_PAD2, D_MODEL, 0, 0, 0, 0);

    // ---- y1 = x1 @ U + bias_v (rowbias folded in exactly); fp16 out; MAP2 ----
    mfma_gemm<128, 128, 0, 0, 1, 0, 1, 0, 0, 2, 1, 128, 6, 0, 0><<<dim3(768, 1, 1), T, 0, stream>>>(
        x1_h, nullptr, Ut, bias_v, nullptr,
        nullptr, y1, apz, nullptr, nullptr,
        (int)MT, D_MODEL, D_MODEL, D_MODEL, D_MODEL, D_MODEL, 0, 0, 0, 0);

    // ---- scores + tile-softmax, all 8 batches; batch = XCD (lin%8) ----
    mfma_gemm<128, 128, 0, 0, 0, 0, 1, 0, 0, 1, 8, 16, 16, 1, 0><<<dim3(2048, 1, 1), T, 0, stream>>>(
        y1, nullptr, x2_h, nullptr, nullptr,
        nullptr, nullptr, ap, smS, slS,
        SEQ, SEQ, D_MODEL, D_MODEL, D_MODEL, SEQ,
        NEb, NEb, 0, 0);

    // ---- PV with softmax fix-up: MAP3 (d-tile fastest -> P' panel L2-hot) ----
    mfma_gemm<128, 128, 0, 2, 0, 1, 1, 0, 1, 3, 8, 16, 6, 0, 1><<<dim3(768, 1, 1), T, 0, stream>>>(
        nullptr, nullptr, x2t, nullptr,
        xcnn,
        nullptr, xcnn, ap, smS, slS,
        SEQ, D_MODEL, SEQ, SEQ, SEQ, D_MODEL,
        0, NEb, 0, NEb);

    // ---- final: out = concat(x1, x) @ fcx_w^T + fcx_b; MAP2 ----
    mfma_gemm<128, 128, 2, 0, 1, 0, 0, 0, 0, 2, 1, 128, 6, 0, 0><<<dim3(768, 1, 1), T, 0, stream>>>(
        x1_h, xcnn, fcx_wt, fcx_b, nullptr,
        out, nullptr, apz, nullptr, nullptr,
        (int)MT, D_MODEL, 2 * D_MODEL, D_MODEL, 2 * D_MODEL, D_MODEL, 0, 0, 0, 0);
}